// Round 1
// baseline (878.202 us; speedup 1.0000x reference)
//
#include <hip/hip_runtime.h>
#include <hip/hip_cooperative_groups.h>
#include <math.h>

namespace cg = cooperative_groups;

#define NN 8192
#define DD 14
#define DP 16
#define FF 2048
#define HID 256
#define LN_EPS 1e-5f
#define NCH 16      // attention key chunks (512 keys each)
#define NFCH 8      // ffn neuron chunks in legacy path (256 each)
#define QSCALE (1.4426950408889634f / 3.7416573867739413f)  // log2(e)/sqrt(14)

typedef short bf16x8 __attribute__((ext_vector_type(8)));
typedef float f32x4 __attribute__((ext_vector_type(4)));

#define LOAD16(dst, srcp) { \
  const float4* _p = (const float4*)(srcp); \
  float4 _a = _p[0], _b = _p[1], _c = _p[2], _d = _p[3]; \
  dst[0]=_a.x; dst[1]=_a.y; dst[2]=_a.z; dst[3]=_a.w; \
  dst[4]=_b.x; dst[5]=_b.y; dst[6]=_b.z; dst[7]=_b.w; \
  dst[8]=_c.x; dst[9]=_c.y; dst[10]=_c.z; dst[11]=_c.w; \
  dst[12]=_d.x; dst[13]=_d.y; dst[14]=_d.z; dst[15]=_d.w; }

#define STORE16(dstp, src) { \
  float4* _p = (float4*)(dstp); \
  _p[0] = make_float4(src[0], src[1], src[2], src[3]); \
  _p[1] = make_float4(src[4], src[5], src[6], src[7]); \
  _p[2] = make_float4(src[8], src[9], src[10], src[11]); \
  _p[3] = make_float4(src[12], src[13], src[14], src[15]); }

static __device__ __forceinline__ float fast_exp2(float x) {
#if __has_builtin(__builtin_amdgcn_exp2f)
  return __builtin_amdgcn_exp2f(x);
#else
  return exp2f(x);
#endif
}

static __device__ __forceinline__ unsigned short bf_hi(float x) {
  return (unsigned short)(__float_as_uint(x) >> 16);
}
static __device__ __forceinline__ float bf_hi_f(float x) {
  return __uint_as_float(__float_as_uint(x) & 0xffff0000u);
}

// ---- repack 8 floats -> bf16 hi/lo fragments ----
static __device__ __forceinline__ void split8(const float* pv, bf16x8* ph, bf16x8* pl) {
  #pragma unroll
  for (int i = 0; i < 8; i++) {
    unsigned int u = __float_as_uint(pv[i]);
    (*ph)[i] = (short)(u >> 16);
    float rr = pv[i] - __uint_as_float(u & 0xffff0000u);
    (*pl)[i] = (short)(__float_as_uint(rr) >> 16);
  }
}

// ---- shared helper: compute qkv for row r from hr[16], store packed operands ----
static __device__ __forceinline__ void qkv_compute_store(
    int r, const float* hr, const float* __restrict__ wqkv,
    const float* __restrict__ bqkv, unsigned int* __restrict__ Qpack,
    unsigned int* __restrict__ KB1, unsigned int* __restrict__ KB2,
    unsigned short* __restrict__ VhiT, unsigned short* __restrict__ VloT) {
  float q[14], k[14], v[14];
  #pragma unroll 6
  for (int c = 0; c < 42; c++) {
    const float* w = wqkv + c * 14;
    float s = bqkv[c];
    #pragma unroll
    for (int d = 0; d < 14; d++) s = fmaf(hr[d], w[d], s);
    if (c < 14)       q[c] = s * QSCALE;
    else if (c < 28)  k[c - 14] = s;
    else              v[c - 28] = s;
  }
  unsigned int qp[16], k1[16], k2[16];
  unsigned short qh[14], ql[14], kh[14], kl[14];
  #pragma unroll
  for (int d = 0; d < 14; d++) {
    qh[d] = bf_hi(q[d]);
    ql[d] = bf_hi(q[d] - bf_hi_f(q[d]));
    kh[d] = bf_hi(k[d]);
    kl[d] = bf_hi(k[d] - bf_hi_f(k[d]));
  }
  #pragma unroll
  for (int i = 0; i < 7; i++) {
    qp[i]     = (unsigned int)qh[2*i] | ((unsigned int)qh[2*i+1] << 16);
    qp[8 + i] = (unsigned int)ql[2*i] | ((unsigned int)ql[2*i+1] << 16);
    k1[i]     = (unsigned int)kh[2*i] | ((unsigned int)kh[2*i+1] << 16);
    k1[8 + i] = k1[i];
    k2[i]     = (unsigned int)kl[2*i] | ((unsigned int)kl[2*i+1] << 16);
    k2[8 + i] = k2[i];
  }
  qp[7] = 0; qp[15] = 0; k1[7] = 0; k1[15] = 0; k2[7] = 0; k2[15] = 0;
  uint4* Qp4 = (uint4*)(Qpack + (size_t)r * 16);
  uint4* K14 = (uint4*)(KB1 + (size_t)r * 16);
  uint4* K24 = (uint4*)(KB2 + (size_t)r * 16);
  #pragma unroll
  for (int i = 0; i < 4; i++) {
    Qp4[i] = make_uint4(qp[4*i], qp[4*i+1], qp[4*i+2], qp[4*i+3]);
    K14[i] = make_uint4(k1[4*i], k1[4*i+1], k1[4*i+2], k1[4*i+3]);
    K24[i] = make_uint4(k2[4*i], k2[4*i+1], k2[4*i+2], k2[4*i+3]);
  }
  #pragma unroll
  for (int d = 0; d < 14; d++) {
    VhiT[(size_t)d * NN + r] = bf_hi(v[d]);
    VloT[(size_t)d * NN + r] = bf_hi(v[d] - bf_hi_f(v[d]));
  }
  VhiT[(size_t)14 * NN + r] = 0x3F80;  // ones column = softmax denom
  VhiT[(size_t)15 * NN + r] = 0;
  VloT[(size_t)14 * NN + r] = 0;
  VloT[(size_t)15 * NN + r] = 0;
}

// ---- shared helper: A-operand pack of 14-dim vector (hi|lo) ----
static __device__ __forceinline__ void store_apack(unsigned int* dst, const float* o) {
  unsigned int qp[16];
  unsigned short hh[14], ll[14];
  #pragma unroll
  for (int d = 0; d < 14; d++) {
    hh[d] = bf_hi(o[d]);
    ll[d] = bf_hi(o[d] - bf_hi_f(o[d]));
  }
  #pragma unroll
  for (int i = 0; i < 7; i++) {
    qp[i]     = (unsigned int)hh[2*i] | ((unsigned int)hh[2*i+1] << 16);
    qp[8 + i] = (unsigned int)ll[2*i] | ((unsigned int)ll[2*i+1] << 16);
  }
  qp[7] = 0; qp[15] = 0;
  uint4* d4 = (uint4*)dst;
  #pragma unroll
  for (int i = 0; i < 4; i++)
    d4[i] = make_uint4(qp[4*i], qp[4*i+1], qp[4*i+2], qp[4*i+3]);
}

// ======================================================================
// Legacy 9-kernel path (fallback if cooperative launch is unavailable)
// ======================================================================

__global__ void pack_all(const float* __restrict__ w3, const float* __restrict__ w4,
                         const float* __restrict__ ffw1, const float* __restrict__ ffw2,
                         const float* __restrict__ x, const float* __restrict__ wqkv,
                         const float* __restrict__ bqkv, float* __restrict__ h,
                         unsigned int* __restrict__ Qpack,
                         unsigned int* __restrict__ KB1, unsigned int* __restrict__ KB2,
                         unsigned short* __restrict__ VhiT, unsigned short* __restrict__ VloT,
                         unsigned short* __restrict__ B3h, unsigned short* __restrict__ B3l,
                         unsigned short* __restrict__ B4h, unsigned short* __restrict__ B4l,
                         unsigned int* __restrict__ W1B1, unsigned int* __restrict__ W1B2,
                         unsigned short* __restrict__ W2h, unsigned short* __restrict__ W2l) {
  const int blk = blockIdx.x, tid = threadIdx.x;
  if (blk < 32) {
    int t = blk * 256 + tid;
    int lane = t & 63, ks = (t >> 6) & 7, nt = t >> 9;
    int n = nt * 16 + (lane & 15);
    int k0 = ks * 32 + (lane >> 4) * 8;
    unsigned int h4[4], l4[4];
    #pragma unroll
    for (int jj = 0; jj < 4; jj++) {
      unsigned short h2[2], l2[2];
      #pragma unroll
      for (int e = 0; e < 2; e++) {
        float v = w4[(size_t)n * 256 + k0 + jj * 2 + e];
        h2[e] = bf_hi(v);
        l2[e] = bf_hi(v - bf_hi_f(v));
      }
      h4[jj] = (unsigned int)h2[0] | ((unsigned int)h2[1] << 16);
      l4[jj] = (unsigned int)l2[0] | ((unsigned int)l2[1] << 16);
    }
    ((uint4*)B4h)[t] = make_uint4(h4[0], h4[1], h4[2], h4[3]);
    ((uint4*)B4l)[t] = make_uint4(l4[0], l4[1], l4[2], l4[3]);
    if (ks < 2) {
      int fi = (nt * 2 + ks) * 64 + lane;
      #pragma unroll
      for (int jj = 0; jj < 4; jj++) {
        unsigned short h2[2], l2[2];
        #pragma unroll
        for (int e = 0; e < 2; e++) {
          int k = k0 + jj * 2 + e;
          float v = (k < 51) ? w3[(size_t)n * 51 + k] : 0.f;
          h2[e] = bf_hi(v);
          l2[e] = bf_hi(v - bf_hi_f(v));
        }
        h4[jj] = (unsigned int)h2[0] | ((unsigned int)h2[1] << 16);
        l4[jj] = (unsigned int)l2[0] | ((unsigned int)l2[1] << 16);
      }
      ((uint4*)B3h)[fi] = make_uint4(h4[0], h4[1], h4[2], h4[3]);
      ((uint4*)B3l)[fi] = make_uint4(l4[0], l4[1], l4[2], l4[3]);
    }
  } else if (blk < 48) {
    int t = (blk - 32) * 256 + tid;
    int l = t >> 11, j = t & 2047;
    const float* wrow = ffw1 + ((size_t)l * FF + j) * 14;
    unsigned int k1[16], k2[16];
    unsigned short kh[14], kl[14];
    #pragma unroll
    for (int d = 0; d < 14; d++) {
      float v = wrow[d];
      kh[d] = bf_hi(v);
      kl[d] = bf_hi(v - bf_hi_f(v));
    }
    #pragma unroll
    for (int i = 0; i < 7; i++) {
      k1[i] = (unsigned int)kh[2*i] | ((unsigned int)kh[2*i+1] << 16);
      k1[8 + i] = k1[i];
      k2[i] = (unsigned int)kl[2*i] | ((unsigned int)kl[2*i+1] << 16);
      k2[8 + i] = k2[i];
    }
    k1[7] = 0; k1[15] = 0; k2[7] = 0; k2[15] = 0;
    uint4* d1 = (uint4*)(W1B1 + (size_t)t * 16);
    uint4* d2 = (uint4*)(W1B2 + (size_t)t * 16);
    #pragma unroll
    for (int i = 0; i < 4; i++) {
      d1[i] = make_uint4(k1[4*i], k1[4*i+1], k1[4*i+2], k1[4*i+3]);
      d2[i] = make_uint4(k2[4*i], k2[4*i+1], k2[4*i+2], k2[4*i+3]);
    }
  } else if (blk < 64) {
    int t = (blk - 48) * 256 + tid;
    int l = t >> 11, j = t & 2047;
    #pragma unroll
    for (int d = 0; d < 16; d++) {
      float v = (d < 14) ? ffw2[((size_t)l * 14 + d) * FF + j] : 0.f;
      W2h[((size_t)l * 16 + d) * FF + j] = bf_hi(v);
      W2l[((size_t)l * 16 + d) * FF + j] = bf_hi(v - bf_hi_f(v));
    }
  } else {
    int r = (blk - 64) * 256 + tid;
    float hr[16];
    #pragma unroll
    for (int d = 0; d < 14; d++) hr[d] = x[(size_t)r * 14 + d];
    hr[14] = 0.f; hr[15] = 0.f;
    STORE16(h + (size_t)r * DP, hr);
    qkv_compute_store(r, hr, wqkv, bqkv, Qpack, KB1, KB2, VhiT, VloT);
  }
}

__global__ __launch_bounds__(256, 4) void attn_mfma(
    const unsigned int* __restrict__ Qpack, const unsigned int* __restrict__ KB1,
    const unsigned int* __restrict__ KB2, const unsigned short* __restrict__ VhiT,
    const unsigned short* __restrict__ VloT, float* __restrict__ part) {
  __shared__ float Plds[4][32][36];
  const int tid = threadIdx.x;
  const int wave = tid >> 6;
  const int lane = tid & 63;
  const int lo4 = lane & 15;
  const int hi4 = lane >> 4;
  const int qbase = blockIdx.x * 128 + wave * 32;
  const int kbase0 = blockIdx.y * 512;

  const bf16x8* Qp = (const bf16x8*)Qpack;
  const bf16x8* B1 = (const bf16x8*)KB1;
  const bf16x8* B2 = (const bf16x8*)KB2;
  const bf16x8* Vh = (const bf16x8*)VhiT;
  const bf16x8* Vl = (const bf16x8*)VloT;

  bf16x8 aQ0 = Qp[(size_t)(qbase + lo4) * 4 + hi4];
  bf16x8 aQ1 = Qp[(size_t)(qbase + 16 + lo4) * 4 + hi4];
  f32x4 acc0 = {0.f, 0.f, 0.f, 0.f};
  f32x4 acc1 = {0.f, 0.f, 0.f, 0.f};
  const f32x4 zero = {0.f, 0.f, 0.f, 0.f};

  for (int c = 0; c < 16; c++) {
    const int kb = kbase0 + c * 32;
    bf16x8 b1g0 = B1[(size_t)(kb + lo4) * 4 + hi4];
    bf16x8 b2g0 = B2[(size_t)(kb + lo4) * 4 + hi4];
    bf16x8 b1g1 = B1[(size_t)(kb + 16 + lo4) * 4 + hi4];
    bf16x8 b2g1 = B2[(size_t)(kb + 16 + lo4) * 4 + hi4];
    bf16x8 vh = Vh[(size_t)lo4 * 1024 + (kb >> 3) + hi4];
    bf16x8 vl = Vl[(size_t)lo4 * 1024 + (kb >> 3) + hi4];

    f32x4 s00 = __builtin_amdgcn_mfma_f32_16x16x32_bf16(aQ0, b1g0, zero, 0, 0, 0);
    f32x4 s01 = __builtin_amdgcn_mfma_f32_16x16x32_bf16(aQ0, b1g1, zero, 0, 0, 0);
    f32x4 s10 = __builtin_amdgcn_mfma_f32_16x16x32_bf16(aQ1, b1g0, zero, 0, 0, 0);
    f32x4 s11 = __builtin_amdgcn_mfma_f32_16x16x32_bf16(aQ1, b1g1, zero, 0, 0, 0);
    s00 = __builtin_amdgcn_mfma_f32_16x16x32_bf16(aQ0, b2g0, s00, 0, 0, 0);
    s01 = __builtin_amdgcn_mfma_f32_16x16x32_bf16(aQ0, b2g1, s01, 0, 0, 0);
    s10 = __builtin_amdgcn_mfma_f32_16x16x32_bf16(aQ1, b2g0, s10, 0, 0, 0);
    s11 = __builtin_amdgcn_mfma_f32_16x16x32_bf16(aQ1, b2g1, s11, 0, 0, 0);
    #pragma unroll
    for (int reg = 0; reg < 4; reg++) {
      Plds[wave][hi4 * 4 + reg][lo4]           = fast_exp2(s00[reg]);
      Plds[wave][hi4 * 4 + reg][16 + lo4]      = fast_exp2(s01[reg]);
      Plds[wave][16 + hi4 * 4 + reg][lo4]      = fast_exp2(s10[reg]);
      Plds[wave][16 + hi4 * 4 + reg][16 + lo4] = fast_exp2(s11[reg]);
    }
    __asm__ volatile("s_waitcnt lgkmcnt(0)" ::: "memory");
    const float4* p0 = (const float4*)&Plds[wave][lo4][hi4 * 8];
    const float4* p1 = (const float4*)&Plds[wave][16 + lo4][hi4 * 8];
    float4 a0 = p0[0], a1 = p0[1], c0 = p1[0], c1 = p1[1];
    float pv0[8] = {a0.x, a0.y, a0.z, a0.w, a1.x, a1.y, a1.z, a1.w};
    float pv1[8] = {c0.x, c0.y, c0.z, c0.w, c1.x, c1.y, c1.z, c1.w};
    bf16x8 ph0, pl0, ph1, pl1;
    split8(pv0, &ph0, &pl0);
    split8(pv1, &ph1, &pl1);
    acc0 = __builtin_amdgcn_mfma_f32_16x16x32_bf16(ph0, vh, acc0, 0, 0, 0);
    acc1 = __builtin_amdgcn_mfma_f32_16x16x32_bf16(ph1, vh, acc1, 0, 0, 0);
    acc0 = __builtin_amdgcn_mfma_f32_16x16x32_bf16(pl0, vh, acc0, 0, 0, 0);
    acc1 = __builtin_amdgcn_mfma_f32_16x16x32_bf16(pl1, vh, acc1, 0, 0, 0);
    acc0 = __builtin_amdgcn_mfma_f32_16x16x32_bf16(ph0, vl, acc0, 0, 0, 0);
    acc1 = __builtin_amdgcn_mfma_f32_16x16x32_bf16(ph1, vl, acc1, 0, 0, 0);
    __asm__ volatile("s_waitcnt lgkmcnt(0)" ::: "memory");
  }
  float* pbase = part + (size_t)blockIdx.y * NN * 16;
  #pragma unroll
  for (int reg = 0; reg < 4; reg++) {
    int row0 = qbase + hi4 * 4 + reg;
    pbase[(size_t)row0 * 16 + lo4] = acc0[reg];
    pbase[(size_t)(row0 + 16) * 16 + lo4] = acc1[reg];
  }
}

__global__ void attn_comb_ln1(float* __restrict__ h, const float* __restrict__ part,
                              const float* __restrict__ wo, const float* __restrict__ bo,
                              const float* __restrict__ g, const float* __restrict__ b,
                              unsigned int* __restrict__ Hpack) {
  int t = blockIdx.x * 128 + threadIdx.x;
  int r = t >> 2, q = t & 3;
  float L = 0.f;
  float A[14];
  #pragma unroll
  for (int d = 0; d < 14; d++) A[d] = 0.f;
  #pragma unroll
  for (int c = q; c < NCH; c += 4) {
    float p[16];
    LOAD16(p, part + ((size_t)c * NN + r) * 16);
    L += p[14];
    #pragma unroll
    for (int d = 0; d < 14; d++) A[d] += p[d];
  }
  #pragma unroll
  for (int off = 1; off < 4; off <<= 1) {
    L += __shfl_xor(L, off, 64);
    #pragma unroll
    for (int d = 0; d < 14; d++) A[d] += __shfl_xor(A[d], off, 64);
  }
  if (q == 0) {
    float inv = 1.f / L;
    float a[14];
    #pragma unroll
    for (int d = 0; d < 14; d++) a[d] = A[d] * inv;
    float hr[16];
    LOAD16(hr, h + (size_t)r * DP);
    float xx[14];
    #pragma unroll
    for (int i = 0; i < 14; i++) {
      float s = bo[i];
      #pragma unroll
      for (int d = 0; d < 14; d++) s = fmaf(wo[i * 14 + d], a[d], s);
      xx[i] = hr[i] + s;
    }
    float mu = 0.f;
    #pragma unroll
    for (int i = 0; i < 14; i++) mu += xx[i];
    mu *= (1.f / 14.f);
    float var = 0.f;
    #pragma unroll
    for (int i = 0; i < 14; i++) { float tt = xx[i] - mu; var = fmaf(tt, tt, var); }
    var *= (1.f / 14.f);
    float rs = rsqrtf(var + LN_EPS);
    float o[16];
    #pragma unroll
    for (int i = 0; i < 14; i++) o[i] = fmaf((xx[i] - mu) * rs, g[i], b[i]);
    o[14] = 0.f; o[15] = 0.f;
    STORE16(h + (size_t)r * DP, o);
    store_apack(Hpack + (size_t)r * 16, o);
  }
}

__global__ __launch_bounds__(256, 4) void ffn_mfma(
    const unsigned int* __restrict__ Hpack, const unsigned int* __restrict__ W1B1,
    const unsigned int* __restrict__ W1B2, const unsigned short* __restrict__ W2h,
    const unsigned short* __restrict__ W2l, const float* __restrict__ b1,
    float* __restrict__ part) {
  __shared__ float Plds[4][32][36];
  const int tid = threadIdx.x;
  const int wave = tid >> 6;
  const int lane = tid & 63;
  const int lo4 = lane & 15;
  const int hi4 = lane >> 4;
  const int qbase = blockIdx.x * 128 + wave * 32;
  const int jbase0 = blockIdx.y * 256;

  const bf16x8* Hp = (const bf16x8*)Hpack;
  const bf16x8* B1 = (const bf16x8*)W1B1;
  const bf16x8* B2 = (const bf16x8*)W1B2;
  const bf16x8* Vh = (const bf16x8*)W2h;
  const bf16x8* Vl = (const bf16x8*)W2l;

  bf16x8 aH0 = Hp[(size_t)(qbase + lo4) * 4 + hi4];
  bf16x8 aH1 = Hp[(size_t)(qbase + 16 + lo4) * 4 + hi4];
  f32x4 acc0 = {0.f, 0.f, 0.f, 0.f};
  f32x4 acc1 = {0.f, 0.f, 0.f, 0.f};
  const f32x4 zero = {0.f, 0.f, 0.f, 0.f};

  for (int c = 0; c < 8; c++) {
    const int jb = jbase0 + c * 32;
    bf16x8 b1g0 = B1[(size_t)(jb + lo4) * 4 + hi4];
    bf16x8 b2g0 = B2[(size_t)(jb + lo4) * 4 + hi4];
    bf16x8 b1g1 = B1[(size_t)(jb + 16 + lo4) * 4 + hi4];
    bf16x8 b2g1 = B2[(size_t)(jb + 16 + lo4) * 4 + hi4];
    bf16x8 vh = Vh[(size_t)lo4 * 256 + (jb >> 3) + hi4];
    bf16x8 vl = Vl[(size_t)lo4 * 256 + (jb >> 3) + hi4];
    float bb0 = b1[jb + lo4];
    float bb1 = b1[jb + 16 + lo4];

    f32x4 s00 = __builtin_amdgcn_mfma_f32_16x16x32_bf16(aH0, b1g0, zero, 0, 0, 0);
    f32x4 s01 = __builtin_amdgcn_mfma_f32_16x16x32_bf16(aH0, b1g1, zero, 0, 0, 0);
    f32x4 s10 = __builtin_amdgcn_mfma_f32_16x16x32_bf16(aH1, b1g0, zero, 0, 0, 0);
    f32x4 s11 = __builtin_amdgcn_mfma_f32_16x16x32_bf16(aH1, b1g1, zero, 0, 0, 0);
    s00 = __builtin_amdgcn_mfma_f32_16x16x32_bf16(aH0, b2g0, s00, 0, 0, 0);
    s01 = __builtin_amdgcn_mfma_f32_16x16x32_bf16(aH0, b2g1, s01, 0, 0, 0);
    s10 = __builtin_amdgcn_mfma_f32_16x16x32_bf16(aH1, b2g0, s10, 0, 0, 0);
    s11 = __builtin_amdgcn_mfma_f32_16x16x32_bf16(aH1, b2g1, s11, 0, 0, 0);
    #pragma unroll
    for (int reg = 0; reg < 4; reg++) {
      Plds[wave][hi4 * 4 + reg][lo4]           = fmaxf(s00[reg] + bb0, 0.f);
      Plds[wave][hi4 * 4 + reg][16 + lo4]      = fmaxf(s01[reg] + bb1, 0.f);
      Plds[wave][16 + hi4 * 4 + reg][lo4]      = fmaxf(s10[reg] + bb0, 0.f);
      Plds[wave][16 + hi4 * 4 + reg][16 + lo4] = fmaxf(s11[reg] + bb1, 0.f);
    }
    __asm__ volatile("s_waitcnt lgkmcnt(0)" ::: "memory");
    const float4* p0 = (const float4*)&Plds[wave][lo4][hi4 * 8];
    const float4* p1 = (const float4*)&Plds[wave][16 + lo4][hi4 * 8];
    float4 a0 = p0[0], a1 = p0[1], c0 = p1[0], c1 = p1[1];
    float pv0[8] = {a0.x, a0.y, a0.z, a0.w, a1.x, a1.y, a1.z, a1.w};
    float pv1[8] = {c0.x, c0.y, c0.z, c0.w, c1.x, c1.y, c1.z, c1.w};
    bf16x8 th0, tl0, th1, tl1;
    split8(pv0, &th0, &tl0);
    split8(pv1, &th1, &tl1);
    acc0 = __builtin_amdgcn_mfma_f32_16x16x32_bf16(th0, vh, acc0, 0, 0, 0);
    acc1 = __builtin_amdgcn_mfma_f32_16x16x32_bf16(th1, vh, acc1, 0, 0, 0);
    acc0 = __builtin_amdgcn_mfma_f32_16x16x32_bf16(tl0, vh, acc0, 0, 0, 0);
    acc1 = __builtin_amdgcn_mfma_f32_16x16x32_bf16(tl1, vh, acc1, 0, 0, 0);
    acc0 = __builtin_amdgcn_mfma_f32_16x16x32_bf16(th0, vl, acc0, 0, 0, 0);
    acc1 = __builtin_amdgcn_mfma_f32_16x16x32_bf16(th1, vl, acc1, 0, 0, 0);
    __asm__ volatile("s_waitcnt lgkmcnt(0)" ::: "memory");
  }
  float* pbase = part + (size_t)blockIdx.y * NN * 16;
  #pragma unroll
  for (int reg = 0; reg < 4; reg++) {
    int row0 = qbase + hi4 * 4 + reg;
    pbase[(size_t)row0 * 16 + lo4] = acc0[reg];
    pbase[(size_t)(row0 + 16) * 16 + lo4] = acc1[reg];
  }
}

__global__ void ffn_ln2_qkv(float* __restrict__ h, const float* __restrict__ part,
                            const float* __restrict__ b2, const float* __restrict__ g,
                            const float* __restrict__ b,
                            const float* __restrict__ wqkv, const float* __restrict__ bqkv,
                            unsigned int* __restrict__ Qpack,
                            unsigned int* __restrict__ KB1, unsigned int* __restrict__ KB2,
                            unsigned short* __restrict__ VhiT,
                            unsigned short* __restrict__ VloT) {
  int t = blockIdx.x * 128 + threadIdx.x;
  int r = t >> 2, q = t & 3;
  float f[14];
  #pragma unroll
  for (int d = 0; d < 14; d++) f[d] = 0.f;
  #pragma unroll
  for (int c = q; c < NFCH; c += 4) {
    float p[16];
    LOAD16(p, part + ((size_t)c * NN + r) * 16);
    #pragma unroll
    for (int d = 0; d < 14; d++) f[d] += p[d];
  }
  #pragma unroll
  for (int off = 1; off < 4; off <<= 1) {
    #pragma unroll
    for (int d = 0; d < 14; d++) f[d] += __shfl_xor(f[d], off, 64);
  }
  if (q == 0) {
    float hr[16];
    LOAD16(hr, h + (size_t)r * DP);
    float xx[14];
    #pragma unroll
    for (int i = 0; i < 14; i++) xx[i] = hr[i] + f[i] + b2[i];
    float mu = 0.f;
    #pragma unroll
    for (int i = 0; i < 14; i++) mu += xx[i];
    mu *= (1.f / 14.f);
    float var = 0.f;
    #pragma unroll
    for (int i = 0; i < 14; i++) { float tt = xx[i] - mu; var = fmaf(tt, tt, var); }
    var *= (1.f / 14.f);
    float rs = rsqrtf(var + LN_EPS);
    float o[16];
    #pragma unroll
    for (int i = 0; i < 14; i++) o[i] = fmaf((xx[i] - mu) * rs, g[i], b[i]);
    o[14] = 0.f; o[15] = 0.f;
    STORE16(h + (size_t)r * DP, o);
    qkv_compute_store(r, o, wqkv, bqkv, Qpack, KB1, KB2, VhiT, VloT);
  }
}

__global__ __launch_bounds__(256, 4) void tail_fused(
    const float* __restrict__ h, const float* __restrict__ part,
    const float* __restrict__ b2, const float* __restrict__ g, const float* __restrict__ b,
    const float* __restrict__ fc1w, const float* __restrict__ fc1b,
    const float* __restrict__ fc2w, const float* __restrict__ fc2b,
    const float* __restrict__ x, const float* __restrict__ y,
    const unsigned short* __restrict__ B3h, const unsigned short* __restrict__ B3l,
    const float* __restrict__ b3,
    const unsigned short* __restrict__ B4h, const unsigned short* __restrict__ B4l,
    const float* __restrict__ b4,
    const float* __restrict__ w5, const float* __restrict__ b5,
    float* __restrict__ out, float* __restrict__ outr) {
  __shared__ alignas(16) unsigned short Ah[16][72], Al[16][72];
  __shared__ alignas(16) unsigned short R1h[16][264], R1l[16][264];
  __shared__ float sred[4][16][16];
  __shared__ float szf[16];
  const int tid = threadIdx.x;
  const int wave = tid >> 6;
  const int lane = tid & 63;
  const int lo4 = lane & 15;
  const int hi4 = lane >> 4;
  const int rbase = blockIdx.x * 16;

  if (tid < 128) {
    int m = tid >> 3, c = tid & 7;
    int r = rbase + m;
    float p[16];
    LOAD16(p, part + ((size_t)c * NN + r) * 16);
    float f[14];
    #pragma unroll
    for (int d = 0; d < 14; d++) f[d] = p[d];
    #pragma unroll
    for (int off = 1; off < 8; off <<= 1) {
      #pragma unroll
      for (int d = 0; d < 14; d++) f[d] += __shfl_xor(f[d], off, 64);
    }
    if (c == 0) {
      float hr[16];
      LOAD16(hr, h + (size_t)r * DP);
      float xx[14];
      #pragma unroll
      for (int i = 0; i < 14; i++) xx[i] = hr[i] + f[i] + b2[i];
      float mu = 0.f;
      #pragma unroll
      for (int i = 0; i < 14; i++) mu += xx[i];
      mu *= (1.f / 14.f);
      float var = 0.f;
      #pragma unroll
      for (int i = 0; i < 14; i++) { float tt = xx[i] - mu; var = fmaf(tt, tt, var); }
      var *= (1.f / 14.f);
      float rs = rsqrtf(var + LN_EPS);
      float o[14];
      #pragma unroll
      for (int i = 0; i < 14; i++) o[i] = fmaf((xx[i] - mu) * rs, g[i], b[i]);
      float s = fc2b[0];
      #pragma unroll
      for (int i = 0; i < 14; i++) {
        float tt = fc1b[i];
        #pragma unroll
        for (int d = 0; d < 14; d++) tt = fmaf(fc1w[i * 14 + d], o[d], tt);
        s = fmaf(tt, fc2w[i], s);
      }
      out[r] = s;
      int si = (int)s;
      szf[m] = (float)si;
    }
  }
  __syncthreads();

  for (int idx = tid; idx < 16 * 64; idx += 256) {
    int m = idx >> 6, k = idx & 63;
    int r = rbase + m;
    float v = 0.f;
    if (k == 0)       v = szf[m];
    else if (k < 15)  v = x[(size_t)r * 14 + (k - 1)];
    else if (k < 51)  v = y[(size_t)r * 36 + (k - 15)];
    Ah[m][k] = bf_hi(v);
    Al[m][k] = bf_hi(v - bf_hi_f(v));
  }
  __syncthreads();

  const f32x4 zero = {0.f, 0.f, 0.f, 0.f};
  f32x4 acc[4];
  #pragma unroll
  for (int nt = 0; nt < 4; nt++) acc[nt] = zero;

  #pragma unroll
  for (int ks = 0; ks < 2; ks++) {
    bf16x8 ah = *(const bf16x8*)&Ah[lo4][ks * 32 + hi4 * 8];
    bf16x8 al = *(const bf16x8*)&Al[lo4][ks * 32 + hi4 * 8];
    #pragma unroll
    for (int nt = 0; nt < 4; nt++) {
      int fi = ((wave * 4 + nt) * 2 + ks) * 64 + lane;
      bf16x8 bh = ((const bf16x8*)B3h)[fi];
      bf16x8 bl = ((const bf16x8*)B3l)[fi];
      acc[nt] = __builtin_amdgcn_mfma_f32_16x16x32_bf16(ah, bh, acc[nt], 0, 0, 0);
      acc[nt] = __builtin_amdgcn_mfma_f32_16x16x32_bf16(al, bh, acc[nt], 0, 0, 0);
      acc[nt] = __builtin_amdgcn_mfma_f32_16x16x32_bf16(ah, bl, acc[nt], 0, 0, 0);
    }
  }
  #pragma unroll
  for (int nt = 0; nt < 4; nt++) {
    int n = (wave * 4 + nt) * 16 + lo4;
    float bb = b3[n];
    #pragma unroll
    for (int reg = 0; reg < 4; reg++) {
      int m = hi4 * 4 + reg;
      float v = fmaxf(acc[nt][reg] + bb, 0.f);
      R1h[m][n] = bf_hi(v);
      R1l[m][n] = bf_hi(v - bf_hi_f(v));
    }
  }
  __syncthreads();

  #pragma unroll
  for (int nt = 0; nt < 4; nt++) acc[nt] = zero;
  #pragma unroll
  for (int ks = 0; ks < 8; ks++) {
    bf16x8 ah = *(const bf16x8*)&R1h[lo4][ks * 32 + hi4 * 8];
    bf16x8 al = *(const bf16x8*)&R1l[lo4][ks * 32 + hi4 * 8];
    #pragma unroll
    for (int nt = 0; nt < 4; nt++) {
      int fi = ((wave * 4 + nt) * 8 + ks) * 64 + lane;
      bf16x8 bh = ((const bf16x8*)B4h)[fi];
      bf16x8 bl = ((const bf16x8*)B4l)[fi];
      acc[nt] = __builtin_amdgcn_mfma_f32_16x16x32_bf16(ah, bh, acc[nt], 0, 0, 0);
      acc[nt] = __builtin_amdgcn_mfma_f32_16x16x32_bf16(al, bh, acc[nt], 0, 0, 0);
      acc[nt] = __builtin_amdgcn_mfma_f32_16x16x32_bf16(ah, bl, acc[nt], 0, 0, 0);
    }
  }
  float s[4] = {0.f, 0.f, 0.f, 0.f};
  #pragma unroll
  for (int nt = 0; nt < 4; nt++) {
    int n = (wave * 4 + nt) * 16 + lo4;
    float bb = b4[n], ww = w5[n];
    #pragma unroll
    for (int reg = 0; reg < 4; reg++)
      s[reg] = fmaf(fmaxf(acc[nt][reg] + bb, 0.f), ww, s[reg]);
  }
  #pragma unroll
  for (int reg = 0; reg < 4; reg++) sred[wave][hi4 * 4 + reg][lo4] = s[reg];
  __syncthreads();

  if (tid < 16) {
    float t = b5[0];
    #pragma unroll
    for (int w = 0; w < 4; w++) {
      const float4* p = (const float4*)&sred[w][tid][0];
      float4 a0 = p[0], a1 = p[1], a2 = p[2], a3 = p[3];
      t += ((a0.x + a0.y) + (a0.z + a0.w)) + ((a1.x + a1.y) + (a1.z + a1.w)) +
           ((a2.x + a2.y) + (a2.z + a2.w)) + ((a3.x + a3.y) + (a3.z + a3.w));
    }
    float sz = szf[tid];
    outr[rbase + tid] = (sz != 0.f) ? t : 0.f;
  }
}

// ======================================================================
// Fused cooperative pipeline: one launch, 8 grid syncs instead of 8
// kernel-boundary drains.  1024 virtual blocks x 256 threads; 4 blk/CU.
// ======================================================================

struct P26 {
  const float *x, *y, *wqkv, *bqkv, *wo, *bo, *ln1g, *ln1b;
  const float *ffw1, *ffb1, *ffw2, *ffb2, *ln2g, *ln2b;
  const float *fc1w, *fc1b, *fc2w, *fc2b, *fc3w, *fc3b, *fc4w, *fc4b, *fc5w, *fc5b;
  float* ws;
  float* out;
};

__global__ __launch_bounds__(256, 4) void fused_pipeline(P26 p) {
  cg::grid_group grid = cg::this_grid();
  // LDS union: attn/ffn use [4][32][36] f32 (18432B); tail uses 25664B layout.
  __shared__ __attribute__((aligned(16))) char smem[25664];
  const int tid = threadIdx.x;
  const int wave = tid >> 6;
  const int lane = tid & 63;
  const int lo4 = lane & 15;
  const int hi4 = lane >> 4;

  float* ws = p.ws;
  float*          h     = ws;
  unsigned int*   Qpack = (unsigned int*)(ws + 131072);
  unsigned int*   KB1   = (unsigned int*)(ws + 262144);
  unsigned int*   KB2   = (unsigned int*)(ws + 393216);
  unsigned short* VhiT  = (unsigned short*)(ws + 524288);
  unsigned short* VloT  = (unsigned short*)(ws + 589824);
  unsigned int*   Hpack = (unsigned int*)(ws + 655360);
  float*          part  = ws + 786432;            // 16*8192*16 floats
  unsigned short* B3h   = (unsigned short*)(ws + 2891776);
  unsigned short* B3l   = (unsigned short*)(ws + 2899968);
  unsigned short* B4h   = (unsigned short*)(ws + 2908160);
  unsigned short* B4l   = (unsigned short*)(ws + 2940928);
  unsigned int*   W1B1  = (unsigned int*)(ws + 2973696);
  unsigned int*   W1B2  = (unsigned int*)(ws + 3039232);
  unsigned short* W2h   = (unsigned short*)(ws + 3104768);
  unsigned short* W2l   = (unsigned short*)(ws + 3137536);
  float* out  = p.out;
  float* outr = p.out + NN;

  // ---------------- P0: weight packs + layer-0 qkv ----------------
  for (int vb = blockIdx.x; vb < 96; vb += gridDim.x) {
    if (vb < 32) {
      int t = vb * 256 + tid;
      int ln = t & 63, ks = (t >> 6) & 7, nt = t >> 9;
      int n = nt * 16 + (ln & 15);
      int k0 = ks * 32 + (ln >> 4) * 8;
      unsigned int h4[4], l4[4];
      #pragma unroll
      for (int jj = 0; jj < 4; jj++) {
        unsigned short h2[2], l2[2];
        #pragma unroll
        for (int e = 0; e < 2; e++) {
          float v = p.fc4w[(size_t)n * 256 + k0 + jj * 2 + e];
          h2[e] = bf_hi(v);
          l2[e] = bf_hi(v - bf_hi_f(v));
        }
        h4[jj] = (unsigned int)h2[0] | ((unsigned int)h2[1] << 16);
        l4[jj] = (unsigned int)l2[0] | ((unsigned int)l2[1] << 16);
      }
      ((uint4*)B4h)[t] = make_uint4(h4[0], h4[1], h4[2], h4[3]);
      ((uint4*)B4l)[t] = make_uint4(l4[0], l4[1], l4[2], l4[3]);
      if (ks < 2) {
        int fi = (nt * 2 + ks) * 64 + ln;
        #pragma unroll
        for (int jj = 0; jj < 4; jj++) {
          unsigned short h2[2], l2[2];
          #pragma unroll
          for (int e = 0; e < 2; e++) {
            int k = k0 + jj * 2 + e;
            float v = (k < 51) ? p.fc3w[(size_t)n * 51 + k] : 0.f;
            h2[e] = bf_hi(v);
            l2[e] = bf_hi(v - bf_hi_f(v));
          }
          h4[jj] = (unsigned int)h2[0] | ((unsigned int)h2[1] << 16);
          l4[jj] = (unsigned int)l2[0] | ((unsigned int)l2[1] << 16);
        }
        ((uint4*)B3h)[fi] = make_uint4(h4[0], h4[1], h4[2], h4[3]);
        ((uint4*)B3l)[fi] = make_uint4(l4[0], l4[1], l4[2], l4[3]);
      }
    } else if (vb < 48) {
      int t = (vb - 32) * 256 + tid;
      int lw = t >> 11, j = t & 2047;
      const float* wrow = p.ffw1 + ((size_t)lw * FF + j) * 14;
      unsigned int k1[16], k2[16];
      unsigned short kh[14], kl[14];
      #pragma unroll
      for (int d = 0; d < 14; d++) {
        float v = wrow[d];
        kh[d] = bf_hi(v);
        kl[d] = bf_hi(v - bf_hi_f(v));
      }
      #pragma unroll
      for (int i = 0; i < 7; i++) {
        k1[i] = (unsigned int)kh[2*i] | ((unsigned int)kh[2*i+1] << 16);
        k1[8 + i] = k1[i];
        k2[i] = (unsigned int)kl[2*i] | ((unsigned int)kl[2*i+1] << 16);
        k2[8 + i] = k2[i];
      }
      k1[7] = 0; k1[15] = 0; k2[7] = 0; k2[15] = 0;
      uint4* d1 = (uint4*)(W1B1 + (size_t)t * 16);
      uint4* d2 = (uint4*)(W1B2 + (size_t)t * 16);
      #pragma unroll
      for (int i = 0; i < 4; i++) {
        d1[i] = make_uint4(k1[4*i], k1[4*i+1], k1[4*i+2], k1[4*i+3]);
        d2[i] = make_uint4(k2[4*i], k2[4*i+1], k2[4*i+2], k2[4*i+3]);
      }
    } else if (vb < 64) {
      int t = (vb - 48) * 256 + tid;
      int lw = t >> 11, j = t & 2047;
      #pragma unroll
      for (int d = 0; d < 16; d++) {
        float v = (d < 14) ? p.ffw2[((size_t)lw * 14 + d) * FF + j] : 0.f;
        W2h[((size_t)lw * 16 + d) * FF + j] = bf_hi(v);
        W2l[((size_t)lw * 16 + d) * FF + j] = bf_hi(v - bf_hi_f(v));
      }
    } else {
      int r = (vb - 64) * 256 + tid;
      float hr[16];
      #pragma unroll
      for (int d = 0; d < 14; d++) hr[d] = p.x[(size_t)r * 14 + d];
      hr[14] = 0.f; hr[15] = 0.f;
      STORE16(h + (size_t)r * DP, hr);
      qkv_compute_store(r, hr, p.wqkv, p.bqkv, Qpack, KB1, KB2, VhiT, VloT);
    }
  }
  grid.sync();

  const bf16x8* Qp  = (const bf16x8*)Qpack;
  const bf16x8* Kb1 = (const bf16x8*)KB1;
  const bf16x8* Kb2 = (const bf16x8*)KB2;
  const bf16x8* Vh  = (const bf16x8*)VhiT;
  const bf16x8* Vl  = (const bf16x8*)VloT;
  const bf16x8* Hp  = (const bf16x8*)Hpack;
  const f32x4 zero = {0.f, 0.f, 0.f, 0.f};

  for (int l = 0; l < 2; l++) {
    // ---------------- attention phase 1 (1024 vblocks) ----------------
    for (int vb = blockIdx.x; vb < 1024; vb += gridDim.x) {
      float (*Pl)[36] = reinterpret_cast<float(*)[36]>(smem + wave * 4608);
      const int qbase = (vb & 63) * 128 + wave * 32;
      const int kbase0 = (vb >> 6) * 512;
      bf16x8 aQ0 = Qp[(size_t)(qbase + lo4) * 4 + hi4];
      bf16x8 aQ1 = Qp[(size_t)(qbase + 16 + lo4) * 4 + hi4];
      f32x4 acc0 = zero, acc1 = zero;
      for (int c = 0; c < 16; c++) {
        const int kb = kbase0 + c * 32;
        bf16x8 b1g0 = Kb1[(size_t)(kb + lo4) * 4 + hi4];
        bf16x8 b2g0 = Kb2[(size_t)(kb + lo4) * 4 + hi4];
        bf16x8 b1g1 = Kb1[(size_t)(kb + 16 + lo4) * 4 + hi4];
        bf16x8 b2g1 = Kb2[(size_t)(kb + 16 + lo4) * 4 + hi4];
        bf16x8 vh = Vh[(size_t)lo4 * 1024 + (kb >> 3) + hi4];
        bf16x8 vl = Vl[(size_t)lo4 * 1024 + (kb >> 3) + hi4];

        f32x4 s00 = __builtin_amdgcn_mfma_f32_16x16x32_bf16(aQ0, b1g0, zero, 0, 0, 0);
        f32x4 s01 = __builtin_amdgcn_mfma_f32_16x16x32_bf16(aQ0, b1g1, zero, 0, 0, 0);
        f32x4 s10 = __builtin_amdgcn_mfma_f32_16x16x32_bf16(aQ1, b1g0, zero, 0, 0, 0);
        f32x4 s11 = __builtin_amdgcn_mfma_f32_16x16x32_bf16(aQ1, b1g1, zero, 0, 0, 0);
        s00 = __builtin_amdgcn_mfma_f32_16x16x32_bf16(aQ0, b2g0, s00, 0, 0, 0);
        s01 = __builtin_amdgcn_mfma_f32_16x16x32_bf16(aQ0, b2g1, s01, 0, 0, 0);
        s10 = __builtin_amdgcn_mfma_f32_16x16x32_bf16(aQ1, b2g0, s10, 0, 0, 0);
        s11 = __builtin_amdgcn_mfma_f32_16x16x32_bf16(aQ1, b2g1, s11, 0, 0, 0);
        #pragma unroll
        for (int reg = 0; reg < 4; reg++) {
          Pl[hi4 * 4 + reg][lo4]           = fast_exp2(s00[reg]);
          Pl[hi4 * 4 + reg][16 + lo4]      = fast_exp2(s01[reg]);
          Pl[16 + hi4 * 4 + reg][lo4]      = fast_exp2(s10[reg]);
          Pl[16 + hi4 * 4 + reg][16 + lo4] = fast_exp2(s11[reg]);
        }
        __asm__ volatile("s_waitcnt lgkmcnt(0)" ::: "memory");
        const float4* p0 = (const float4*)&Pl[lo4][hi4 * 8];
        const float4* p1 = (const float4*)&Pl[16 + lo4][hi4 * 8];
        float4 a0 = p0[0], a1 = p0[1], c0 = p1[0], c1 = p1[1];
        float pv0[8] = {a0.x, a0.y, a0.z, a0.w, a1.x, a1.y, a1.z, a1.w};
        float pv1[8] = {c0.x, c0.y, c0.z, c0.w, c1.x, c1.y, c1.z, c1.w};
        bf16x8 ph0, pl0, ph1, pl1;
        split8(pv0, &ph0, &pl0);
        split8(pv1, &ph1, &pl1);
        acc0 = __builtin_amdgcn_mfma_f32_16x16x32_bf16(ph0, vh, acc0, 0, 0, 0);
        acc1 = __builtin_amdgcn_mfma_f32_16x16x32_bf16(ph1, vh, acc1, 0, 0, 0);
        acc0 = __builtin_amdgcn_mfma_f32_16x16x32_bf16(pl0, vh, acc0, 0, 0, 0);
        acc1 = __builtin_amdgcn_mfma_f32_16x16x32_bf16(pl1, vh, acc1, 0, 0, 0);
        acc0 = __builtin_amdgcn_mfma_f32_16x16x32_bf16(ph0, vl, acc0, 0, 0, 0);
        acc1 = __builtin_amdgcn_mfma_f32_16x16x32_bf16(ph1, vl, acc1, 0, 0, 0);
        __asm__ volatile("s_waitcnt lgkmcnt(0)" ::: "memory");
      }
      float* pbase = part + (size_t)(vb >> 6) * NN * 16;
      #pragma unroll
      for (int reg = 0; reg < 4; reg++) {
        int row0 = qbase + hi4 * 4 + reg;
        pbase[(size_t)row0 * 16 + lo4] = acc0[reg];
        pbase[(size_t)(row0 + 16) * 16 + lo4] = acc1[reg];
      }
    }
    grid.sync();

    // ---------------- attn combine + LN1 (32 thr/row) ----------------
    {
      const float* wol = p.wo + (size_t)l * 196;
      const float* bol = p.bo + (size_t)l * 14;
      const float* g1  = p.ln1g + (size_t)l * 14;
      const float* bl1 = p.ln1b + (size_t)l * 14;
      for (int vb = blockIdx.x; vb < 1024; vb += gridDim.x) {
        int t = vb * 256 + tid;
        int r = t >> 5, q = t & 31;
        float L = 0.f;
        float A[14];
        #pragma unroll
        for (int d = 0; d < 14; d++) A[d] = 0.f;
        if (q < 16) {
          float pp[16];
          LOAD16(pp, part + ((size_t)q * NN + r) * 16);
          L = pp[14];
          #pragma unroll
          for (int d = 0; d < 14; d++) A[d] = pp[d];
        }
        #pragma unroll
        for (int off = 1; off < 16; off <<= 1) {
          L += __shfl_xor(L, off, 64);
          #pragma unroll
          for (int d = 0; d < 14; d++) A[d] += __shfl_xor(A[d], off, 64);
        }
        if (q == 0) {
          float inv = 1.f / L;
          float a[14];
          #pragma unroll
          for (int d = 0; d < 14; d++) a[d] = A[d] * inv;
          float hr[16];
          LOAD16(hr, h + (size_t)r * DP);
          float xx[14];
          #pragma unroll
          for (int i = 0; i < 14; i++) {
            float s = bol[i];
            #pragma unroll
            for (int d = 0; d < 14; d++) s = fmaf(wol[i * 14 + d], a[d], s);
            xx[i] = hr[i] + s;
          }
          float mu = 0.f;
          #pragma unroll
          for (int i = 0; i < 14; i++) mu += xx[i];
          mu *= (1.f / 14.f);
          float var = 0.f;
          #pragma unroll
          for (int i = 0; i < 14; i++) { float tt = xx[i] - mu; var = fmaf(tt, tt, var); }
          var *= (1.f / 14.f);
          float rs = rsqrtf(var + LN_EPS);
          float o[16];
          #pragma unroll
          for (int i = 0; i < 14; i++) o[i] = fmaf((xx[i] - mu) * rs, g1[i], bl1[i]);
          o[14] = 0.f; o[15] = 0.f;
          STORE16(h + (size_t)r * DP, o);
          store_apack(Hpack + (size_t)r * 16, o);
        }
      }
    }
    grid.sync();

    // ---------------- ffn phase 1 (1024 vblocks, 16 neuron-chunks) ----------------
    {
      const bf16x8* Wb1 = (const bf16x8*)(W1B1 + (size_t)l * 2048 * 16);
      const bf16x8* Wb2 = (const bf16x8*)(W1B2 + (size_t)l * 2048 * 16);
      const bf16x8* Wvh = (const bf16x8*)(W2h + (size_t)l * 16 * FF);
      const bf16x8* Wvl = (const bf16x8*)(W2l + (size_t)l * 16 * FF);
      const float* fb1 = p.ffb1 + (size_t)l * FF;
      for (int vb = blockIdx.x; vb < 1024; vb += gridDim.x) {
        float (*Pl)[36] = reinterpret_cast<float(*)[36]>(smem + wave * 4608);
        const int qbase = (vb & 63) * 128 + wave * 32;
        const int jbase0 = (vb >> 6) * 128;
        bf16x8 aH0 = Hp[(size_t)(qbase + lo4) * 4 + hi4];
        bf16x8 aH1 = Hp[(size_t)(qbase + 16 + lo4) * 4 + hi4];
        f32x4 acc0 = zero, acc1 = zero;
        for (int c = 0; c < 4; c++) {
          const int jb = jbase0 + c * 32;
          bf16x8 b1g0 = Wb1[(size_t)(jb + lo4) * 4 + hi4];
          bf16x8 b2g0 = Wb2[(size_t)(jb + lo4) * 4 + hi4];
          bf16x8 b1g1 = Wb1[(size_t)(jb + 16 + lo4) * 4 + hi4];
          bf16x8 b2g1 = Wb2[(size_t)(jb + 16 + lo4) * 4 + hi4];
          bf16x8 vh = Wvh[(size_t)lo4 * 256 + (jb >> 3) + hi4];
          bf16x8 vl = Wvl[(size_t)lo4 * 256 + (jb >> 3) + hi4];
          float bb0 = fb1[jb + lo4];
          float bb1 = fb1[jb + 16 + lo4];

          f32x4 s00 = __builtin_amdgcn_mfma_f32_16x16x32_bf16(aH0, b1g0, zero, 0, 0, 0);
          f32x4 s01 = __builtin_amdgcn_mfma_f32_16x16x32_bf16(aH0, b1g1, zero, 0, 0, 0);
          f32x4 s10 = __builtin_amdgcn_mfma_f32_16x16x32_bf16(aH1, b1g0, zero, 0, 0, 0);
          f32x4 s11 = __builtin_amdgcn_mfma_f32_16x16x32_bf16(aH1, b1g1, zero, 0, 0, 0);
          s00 = __builtin_amdgcn_mfma_f32_16x16x32_bf16(aH0, b2g0, s00, 0, 0, 0);
          s01 = __builtin_amdgcn_mfma_f32_16x16x32_bf16(aH0, b2g1, s01, 0, 0, 0);
          s10 = __builtin_amdgcn_mfma_f32_16x16x32_bf16(aH1, b2g0, s10, 0, 0, 0);
          s11 = __builtin_amdgcn_mfma_f32_16x16x32_bf16(aH1, b2g1, s11, 0, 0, 0);
          #pragma unroll
          for (int reg = 0; reg < 4; reg++) {
            Pl[hi4 * 4 + reg][lo4]           = fmaxf(s00[reg] + bb0, 0.f);
            Pl[hi4 * 4 + reg][16 + lo4]      = fmaxf(s01[reg] + bb1, 0.f);
            Pl[16 + hi4 * 4 + reg][lo4]      = fmaxf(s10[reg] + bb0, 0.f);
            Pl[16 + hi4 * 4 + reg][16 + lo4] = fmaxf(s11[reg] + bb1, 0.f);
          }
          __asm__ volatile("s_waitcnt lgkmcnt(0)" ::: "memory");
          const float4* p0 = (const float4*)&Pl[lo4][hi4 * 8];
          const float4* p1 = (const float4*)&Pl[16 + lo4][hi4 * 8];
          float4 a0 = p0[0], a1 = p0[1], c0 = p1[0], c1 = p1[1];
          float pv0[8] = {a0.x, a0.y, a0.z, a0.w, a1.x, a1.y, a1.z, a1.w};
          float pv1[8] = {c0.x, c0.y, c0.z, c0.w, c1.x, c1.y, c1.z, c1.w};
          bf16x8 th0, tl0, th1, tl1;
          split8(pv0, &th0, &tl0);
          split8(pv1, &th1, &tl1);
          acc0 = __builtin_amdgcn_mfma_f32_16x16x32_bf16(th0, vh, acc0, 0, 0, 0);
          acc1 = __builtin_amdgcn_mfma_f32_16x16x32_bf16(th1, vh, acc1, 0, 0, 0);
          acc0 = __builtin_amdgcn_mfma_f32_16x16x32_bf16(tl0, vh, acc0, 0, 0, 0);
          acc1 = __builtin_amdgcn_mfma_f32_16x16x32_bf16(tl1, vh, acc1, 0, 0, 0);
          acc0 = __builtin_amdgcn_mfma_f32_16x16x32_bf16(th0, vl, acc0, 0, 0, 0);
          acc1 = __builtin_amdgcn_mfma_f32_16x16x32_bf16(th1, vl, acc1, 0, 0, 0);
          __asm__ volatile("s_waitcnt lgkmcnt(0)" ::: "memory");
        }
        float* pbase = part + (size_t)(vb >> 6) * NN * 16;
        #pragma unroll
        for (int reg = 0; reg < 4; reg++) {
          int row0 = qbase + hi4 * 4 + reg;
          pbase[(size_t)row0 * 16 + lo4] = acc0[reg];
          pbase[(size_t)(row0 + 16) * 16 + lo4] = acc1[reg];
        }
      }
    }
    grid.sync();

    if (l == 0) {
      // ---------- ffn combine + LN2 + next-layer qkv (32 thr/row) ----------
      for (int vb = blockIdx.x; vb < 1024; vb += gridDim.x) {
        int t = vb * 256 + tid;
        int r = t >> 5, q = t & 31;
        float f[14];
        #pragma unroll
        for (int d = 0; d < 14; d++) f[d] = 0.f;
        if (q < 16) {
          float pp[16];
          LOAD16(pp, part + ((size_t)q * NN + r) * 16);
          #pragma unroll
          for (int d = 0; d < 14; d++) f[d] = pp[d];
        }
        #pragma unroll
        for (int off = 1; off < 16; off <<= 1) {
          #pragma unroll
          for (int d = 0; d < 14; d++) f[d] += __shfl_xor(f[d], off, 64);
        }
        if (q == 0) {
          float hr[16];
          LOAD16(hr, h + (size_t)r * DP);
          float xx[14];
          #pragma unroll
          for (int i = 0; i < 14; i++) xx[i] = hr[i] + f[i] + p.ffb2[i];
          float mu = 0.f;
          #pragma unroll
          for (int i = 0; i < 14; i++) mu += xx[i];
          mu *= (1.f / 14.f);
          float var = 0.f;
          #pragma unroll
          for (int i = 0; i < 14; i++) { float tt = xx[i] - mu; var = fmaf(tt, tt, var); }
          var *= (1.f / 14.f);
          float rs = rsqrtf(var + LN_EPS);
          float o[16];
          #pragma unroll
          for (int i = 0; i < 14; i++) o[i] = fmaf((xx[i] - mu) * rs, p.ln2g[i], p.ln2b[i]);
          o[14] = 0.f; o[15] = 0.f;
          STORE16(h + (size_t)r * DP, o);
          qkv_compute_store(r, o, p.wqkv + 588, p.bqkv + 42, Qpack, KB1, KB2, VhiT, VloT);
        }
      }
      grid.sync();
    }
  }

  // ---------------- tail: combine + LN2 + size head + regression ----------------
  {
    unsigned short (*Ah)[72]  = (unsigned short(*)[72])(smem);
    unsigned short (*Al)[72]  = (unsigned short(*)[72])(smem + 2304);
    unsigned short (*R1h)[264] = (unsigned short(*)[264])(smem + 4608);
    unsigned short (*R1l)[264] = (unsigned short(*)[264])(smem + 13056);
    float (*sred)[16][16] = (float(*)[16][16])(smem + 21504);
    float* szf = (float*)(smem + 25600);
    const float* b2t = p.ffb2 + 14;
    const float* g2t = p.ln2g + 14;
    const float* bb2t = p.ln2b + 14;

    for (int vb = blockIdx.x; vb < 512; vb += gridDim.x) {
      const int rbase = vb * 16;
      {
        int m = tid >> 4, c = tid & 15;
        int r = rbase + m;
        float pp[16];
        LOAD16(pp, part + ((size_t)c * NN + r) * 16);
        float f[14];
        #pragma unroll
        for (int d = 0; d < 14; d++) f[d] = pp[d];
        #pragma unroll
        for (int off = 1; off < 16; off <<= 1) {
          #pragma unroll
          for (int d = 0; d < 14; d++) f[d] += __shfl_xor(f[d], off, 64);
        }
        if (c == 0) {
          float hr[16];
          LOAD16(hr, h + (size_t)r * DP);
          float xx[14];
          #pragma unroll
          for (int i = 0; i < 14; i++) xx[i] = hr[i] + f[i] + b2t[i];
          float mu = 0.f;
          #pragma unroll
          for (int i = 0; i < 14; i++) mu += xx[i];
          mu *= (1.f / 14.f);
          float var = 0.f;
          #pragma unroll
          for (int i = 0; i < 14; i++) { float tt = xx[i] - mu; var = fmaf(tt, tt, var); }
          var *= (1.f / 14.f);
          float rs = rsqrtf(var + LN_EPS);
          float o[14];
          #pragma unroll
          for (int i = 0; i < 14; i++) o[i] = fmaf((xx[i] - mu) * rs, g2t[i], bb2t[i]);
          float s = p.fc2b[0];
          #pragma unroll
          for (int i = 0; i < 14; i++) {
            float tt = p.fc1b[i];
            #pragma unroll
            for (int d = 0; d < 14; d++) tt = fmaf(p.fc1w[i * 14 + d], o[d], tt);
            s = fmaf(tt, p.fc2w[i], s);
          }
          out[r] = s;
          int si = (int)s;
          szf[m] = (float)si;
        }
      }
      __syncthreads();

      for (int idx = tid; idx < 16 * 64; idx += 256) {
        int m = idx >> 6, k = idx & 63;
        int r = rbase + m;
        float v = 0.f;
        if (k == 0)       v = szf[m];
        else if (k < 15)  v = p.x[(size_t)r * 14 + (k - 1)];
        else if (k < 51)  v = p.y[(size_t)r * 36 + (k - 15)];
        Ah[m][k] = bf_hi(v);
        Al[m][k] = bf_hi(v - bf_hi_f(v));
      }
      __syncthreads();

      f32x4 acc[4];
      #pragma unroll
      for (int nt = 0; nt < 4; nt++) acc[nt] = zero;
      #pragma unroll
      for (int ks = 0; ks < 2; ks++) {
        bf16x8 ah = *(const bf16x8*)&Ah[lo4][ks * 32 + hi4 * 8];
        bf16x8 al = *(const bf16x8*)&Al[lo4][ks * 32 + hi4 * 8];
        #pragma unroll
        for (int nt = 0; nt < 4; nt++) {
          int fi = ((wave * 4 + nt) * 2 + ks) * 64 + lane;
          bf16x8 bh = ((const bf16x8*)B3h)[fi];
          bf16x8 bl = ((const bf16x8*)B3l)[fi];
          acc[nt] = __builtin_amdgcn_mfma_f32_16x16x32_bf16(ah, bh, acc[nt], 0, 0, 0);
          acc[nt] = __builtin_amdgcn_mfma_f32_16x16x32_bf16(al, bh, acc[nt], 0, 0, 0);
          acc[nt] = __builtin_amdgcn_mfma_f32_16x16x32_bf16(ah, bl, acc[nt], 0, 0, 0);
        }
      }
      #pragma unroll
      for (int nt = 0; nt < 4; nt++) {
        int n = (wave * 4 + nt) * 16 + lo4;
        float bb = p.fc3b[n];
        #pragma unroll
        for (int reg = 0; reg < 4; reg++) {
          int m = hi4 * 4 + reg;
          float v = fmaxf(acc[nt][reg] + bb, 0.f);
          R1h[m][n] = bf_hi(v);
          R1l[m][n] = bf_hi(v - bf_hi_f(v));
        }
      }
      __syncthreads();

      #pragma unroll
      for (int nt = 0; nt < 4; nt++) acc[nt] = zero;
      #pragma unroll
      for (int ks = 0; ks < 8; ks++) {
        bf16x8 ah = *(const bf16x8*)&R1h[lo4][ks * 32 + hi4 * 8];
        bf16x8 al = *(const bf16x8*)&R1l[lo4][ks * 32 + hi4 * 8];
        #pragma unroll
        for (int nt = 0; nt < 4; nt++) {
          int fi = ((wave * 4 + nt) * 8 + ks) * 64 + lane;
          bf16x8 bh = ((const bf16x8*)B4h)[fi];
          bf16x8 bl = ((const bf16x8*)B4l)[fi];
          acc[nt] = __builtin_amdgcn_mfma_f32_16x16x32_bf16(ah, bh, acc[nt], 0, 0, 0);
          acc[nt] = __builtin_amdgcn_mfma_f32_16x16x32_bf16(al, bh, acc[nt], 0, 0, 0);
          acc[nt] = __builtin_amdgcn_mfma_f32_16x16x32_bf16(ah, bl, acc[nt], 0, 0, 0);
        }
      }
      float s4[4] = {0.f, 0.f, 0.f, 0.f};
      #pragma unroll
      for (int nt = 0; nt < 4; nt++) {
        int n = (wave * 4 + nt) * 16 + lo4;
        float bb = p.fc4b[n], ww = p.fc5w[n];
        #pragma unroll
        for (int reg = 0; reg < 4; reg++)
          s4[reg] = fmaf(fmaxf(acc[nt][reg] + bb, 0.f), ww, s4[reg]);
      }
      #pragma unroll
      for (int reg = 0; reg < 4; reg++) sred[wave][hi4 * 4 + reg][lo4] = s4[reg];
      __syncthreads();

      if (tid < 16) {
        float tsum = p.fc5b[0];
        #pragma unroll
        for (int w = 0; w < 4; w++) {
          const float4* pr = (const float4*)&sred[w][tid][0];
          float4 a0 = pr[0], a1 = pr[1], a2 = pr[2], a3 = pr[3];
          tsum += ((a0.x + a0.y) + (a0.z + a0.w)) + ((a1.x + a1.y) + (a1.z + a1.w)) +
                  ((a2.x + a2.y) + (a2.z + a2.w)) + ((a3.x + a3.y) + (a3.z + a3.w));
        }
        float sz = szf[tid];
        outr[rbase + tid] = (sz != 0.f) ? tsum : 0.f;
      }
      __syncthreads();   // szf/Ah reused next vb iteration
    }
  }
}

extern "C" void kernel_launch(void* const* d_in, const int* in_sizes, int n_in,
                              void* d_out, int out_size, void* d_ws, size_t ws_size,
                              hipStream_t stream) {
  const float* x    = (const float*)d_in[0];
  const float* y    = (const float*)d_in[1];
  const float* wqkv = (const float*)d_in[2];
  const float* bqkv = (const float*)d_in[3];
  const float* wo   = (const float*)d_in[4];
  const float* bo   = (const float*)d_in[5];
  const float* ln1g = (const float*)d_in[6];
  const float* ln1b = (const float*)d_in[7];
  const float* ffw1 = (const float*)d_in[8];
  const float* ffb1 = (const float*)d_in[9];
  const float* ffw2 = (const float*)d_in[10];
  const float* ffb2 = (const float*)d_in[11];
  const float* ln2g = (const float*)d_in[12];
  const float* ln2b = (const float*)d_in[13];
  const float* fc1w = (const float*)d_in[14];
  const float* fc1b = (const float*)d_in[15];
  const float* fc2w = (const float*)d_in[16];
  const float* fc2b = (const float*)d_in[17];
  const float* fc3w = (const float*)d_in[18];
  const float* fc3b = (const float*)d_in[19];
  const float* fc4w = (const float*)d_in[20];
  const float* fc4b = (const float*)d_in[21];
  const float* fc5w = (const float*)d_in[22];
  const float* fc5b = (const float*)d_in[23];

  float* ws = (float*)d_ws;
  float*          h     = ws;
  unsigned int*   Qpack = (unsigned int*)(ws + 131072);
  unsigned int*   KB1   = (unsigned int*)(ws + 262144);
  unsigned int*   KB2   = (unsigned int*)(ws + 393216);
  unsigned short* VhiT  = (unsigned short*)(ws + 524288);
  unsigned short* VloT  = (unsigned short*)(ws + 589824);
  unsigned int*   Hpack = (unsigned int*)(ws + 655360);
  float*          part  = ws + 786432;
  unsigned short* B3h   = (unsigned short*)(ws + 2891776);
  unsigned short* B3l   = (unsigned short*)(ws + 2899968);
  unsigned short* B4h   = (unsigned short*)(ws + 2908160);
  unsigned short* B4l   = (unsigned short*)(ws + 2940928);
  unsigned int*   W1B1  = (unsigned int*)(ws + 2973696);
  unsigned int*   W1B2  = (unsigned int*)(ws + 3039232);
  unsigned short* W2h   = (unsigned short*)(ws + 3104768);
  unsigned short* W2l   = (unsigned short*)(ws + 3137536);

  float* out = (float*)d_out;

  P26 hp;
  hp.x = x; hp.y = y; hp.wqkv = wqkv; hp.bqkv = bqkv; hp.wo = wo; hp.bo = bo;
  hp.ln1g = ln1g; hp.ln1b = ln1b; hp.ffw1 = ffw1; hp.ffb1 = ffb1;
  hp.ffw2 = ffw2; hp.ffb2 = ffb2; hp.ln2g = ln2g; hp.ln2b = ln2b;
  hp.fc1w = fc1w; hp.fc1b = fc1b; hp.fc2w = fc2w; hp.fc2b = fc2b;
  hp.fc3w = fc3w; hp.fc3b = fc3b; hp.fc4w = fc4w; hp.fc4b = fc4b;
  hp.fc5w = fc5w; hp.fc5b = fc5b;
  hp.ws = ws; hp.out = out;

  static int nblk = 0;
  if (nblk == 0) {
    int dev = 0, numCU = 0, perCU = 0;
    (void)hipGetDevice(&dev);
    (void)hipDeviceGetAttribute(&numCU, hipDeviceAttributeMultiprocessorCount, dev);
    (void)hipOccupancyMaxActiveBlocksPerMultiprocessor(&perCU, fused_pipeline, 256, 0);
    if (numCU <= 0) numCU = 256;
    if (perCU <= 0) perCU = 1;
    long cap = (long)perCU * (long)numCU;
    nblk = (int)(cap < 1024 ? cap : 1024);
  }

  void* kargs[] = { (void*)&hp };
  hipError_t err = hipLaunchCooperativeKernel(fused_pipeline, dim3(nblk), dim3(256),
                                              kargs, 0, stream);
  if (err != hipSuccess) {
    // Fallback: proven 9-kernel path.
    (void)hipGetLastError();
    pack_all<<<96, 256, 0, stream>>>(fc3w, fc4w, ffw1, ffw2, x, wqkv, bqkv, h,
                                     Qpack, KB1, KB2, VhiT, VloT,
                                     B3h, B3l, B4h, B4l, W1B1, W1B2, W2h, W2l);
    for (int l = 0; l < 2; l++) {
      attn_mfma<<<dim3(64, NCH), 256, 0, stream>>>(Qpack, KB1, KB2, VhiT, VloT, part);
      attn_comb_ln1<<<256, 128, 0, stream>>>(h, part, wo + (size_t)l * 196,
                                             bo + (size_t)l * 14, ln1g + (size_t)l * 14,
                                             ln1b + (size_t)l * 14, Hpack);
      ffn_mfma<<<dim3(64, NFCH), 256, 0, stream>>>(
          Hpack, W1B1 + (size_t)l * 2048 * 16, W1B2 + (size_t)l * 2048 * 16,
          W2h + (size_t)l * 16 * FF, W2l + (size_t)l * 16 * FF,
          ffb1 + (size_t)l * FF, part);
      if (l == 0) {
        ffn_ln2_qkv<<<256, 128, 0, stream>>>(h, part, ffb2, ln2g, ln2b,
                                             wqkv + 42 * 14, bqkv + 42,
                                             Qpack, KB1, KB2, VhiT, VloT);
      }
    }
    tail_fused<<<512, 256, 0, stream>>>(h, part, ffb2 + 14, ln2g + 14, ln2b + 14,
                                        fc1w, fc1b, fc2w, fc2b, x, y,
                                        B3h, B3l, fc3b, B4h, B4l, fc4b,
                                        fc5w, fc5b, out, out + NN);
  }
}

// Round 2
// 607.816 us; speedup vs baseline: 1.4448x; 1.4448x over previous
//
#include <hip/hip_runtime.h>
#include <hip/hip_cooperative_groups.h>
#include <math.h>

namespace cg = cooperative_groups;

#define NN 8192
#define DD 14
#define DP 16
#define FF 2048
#define HID 256
#define LN_EPS 1e-5f
#define NCH 16      // attention key chunks (512 keys each)
#define NFCH 8      // ffn neuron chunks in legacy path (256 each)
#define QSCALE (1.4426950408889634f / 3.7416573867739413f)  // log2(e)/sqrt(14)

typedef short bf16x8 __attribute__((ext_vector_type(8)));
typedef float f32x4 __attribute__((ext_vector_type(4)));

#define LOAD16(dst, srcp) { \
  const float4* _p = (const float4*)(srcp); \
  float4 _a = _p[0], _b = _p[1], _c = _p[2], _d = _p[3]; \
  dst[0]=_a.x; dst[1]=_a.y; dst[2]=_a.z; dst[3]=_a.w; \
  dst[4]=_b.x; dst[5]=_b.y; dst[6]=_b.z; dst[7]=_b.w; \
  dst[8]=_c.x; dst[9]=_c.y; dst[10]=_c.z; dst[11]=_c.w; \
  dst[12]=_d.x; dst[13]=_d.y; dst[14]=_d.z; dst[15]=_d.w; }

#define STORE16(dstp, src) { \
  float4* _p = (float4*)(dstp); \
  _p[0] = make_float4(src[0], src[1], src[2], src[3]); \
  _p[1] = make_float4(src[4], src[5], src[6], src[7]); \
  _p[2] = make_float4(src[8], src[9], src[10], src[11]); \
  _p[3] = make_float4(src[12], src[13], src[14], src[15]); }

static __device__ __forceinline__ float fast_exp2(float x) {
#if __has_builtin(__builtin_amdgcn_exp2f)
  return __builtin_amdgcn_exp2f(x);
#else
  return exp2f(x);
#endif
}

static __device__ __forceinline__ unsigned short bf_hi(float x) {
  return (unsigned short)(__float_as_uint(x) >> 16);
}
static __device__ __forceinline__ float bf_hi_f(float x) {
  return __uint_as_float(__float_as_uint(x) & 0xffff0000u);
}

// ---- repack 8 floats -> bf16 hi/lo fragments ----
static __device__ __forceinline__ void split8(const float* pv, bf16x8* ph, bf16x8* pl) {
  #pragma unroll
  for (int i = 0; i < 8; i++) {
    unsigned int u = __float_as_uint(pv[i]);
    (*ph)[i] = (short)(u >> 16);
    float rr = pv[i] - __uint_as_float(u & 0xffff0000u);
    (*pl)[i] = (short)(__float_as_uint(rr) >> 16);
  }
}

// ---- shared helper: compute qkv for row r from hr[16], store packed operands ----
static __device__ __forceinline__ void qkv_compute_store(
    int r, const float* hr, const float* __restrict__ wqkv,
    const float* __restrict__ bqkv, unsigned int* __restrict__ Qpack,
    unsigned int* __restrict__ KB1, unsigned int* __restrict__ KB2,
    unsigned short* __restrict__ VhiT, unsigned short* __restrict__ VloT) {
  float q[14], k[14], v[14];
  #pragma unroll 6
  for (int c = 0; c < 42; c++) {
    const float* w = wqkv + c * 14;
    float s = bqkv[c];
    #pragma unroll
    for (int d = 0; d < 14; d++) s = fmaf(hr[d], w[d], s);
    if (c < 14)       q[c] = s * QSCALE;
    else if (c < 28)  k[c - 14] = s;
    else              v[c - 28] = s;
  }
  unsigned int qp[16], k1[16], k2[16];
  unsigned short qh[14], ql[14], kh[14], kl[14];
  #pragma unroll
  for (int d = 0; d < 14; d++) {
    qh[d] = bf_hi(q[d]);
    ql[d] = bf_hi(q[d] - bf_hi_f(q[d]));
    kh[d] = bf_hi(k[d]);
    kl[d] = bf_hi(k[d] - bf_hi_f(k[d]));
  }
  #pragma unroll
  for (int i = 0; i < 7; i++) {
    qp[i]     = (unsigned int)qh[2*i] | ((unsigned int)qh[2*i+1] << 16);
    qp[8 + i] = (unsigned int)ql[2*i] | ((unsigned int)ql[2*i+1] << 16);
    k1[i]     = (unsigned int)kh[2*i] | ((unsigned int)kh[2*i+1] << 16);
    k1[8 + i] = k1[i];
    k2[i]     = (unsigned int)kl[2*i] | ((unsigned int)kl[2*i+1] << 16);
    k2[8 + i] = k2[i];
  }
  qp[7] = 0; qp[15] = 0; k1[7] = 0; k1[15] = 0; k2[7] = 0; k2[15] = 0;
  uint4* Qp4 = (uint4*)(Qpack + (size_t)r * 16);
  uint4* K14 = (uint4*)(KB1 + (size_t)r * 16);
  uint4* K24 = (uint4*)(KB2 + (size_t)r * 16);
  #pragma unroll
  for (int i = 0; i < 4; i++) {
    Qp4[i] = make_uint4(qp[4*i], qp[4*i+1], qp[4*i+2], qp[4*i+3]);
    K14[i] = make_uint4(k1[4*i], k1[4*i+1], k1[4*i+2], k1[4*i+3]);
    K24[i] = make_uint4(k2[4*i], k2[4*i+1], k2[4*i+2], k2[4*i+3]);
  }
  #pragma unroll
  for (int d = 0; d < 14; d++) {
    VhiT[(size_t)d * NN + r] = bf_hi(v[d]);
    VloT[(size_t)d * NN + r] = bf_hi(v[d] - bf_hi_f(v[d]));
  }
  VhiT[(size_t)14 * NN + r] = 0x3F80;  // ones column = softmax denom
  VhiT[(size_t)15 * NN + r] = 0;
  VloT[(size_t)14 * NN + r] = 0;
  VloT[(size_t)15 * NN + r] = 0;
}

// ---- shared helper: A-operand pack of 14-dim vector (hi|lo) ----
static __device__ __forceinline__ void store_apack(unsigned int* dst, const float* o) {
  unsigned int qp[16];
  unsigned short hh[14], ll[14];
  #pragma unroll
  for (int d = 0; d < 14; d++) {
    hh[d] = bf_hi(o[d]);
    ll[d] = bf_hi(o[d] - bf_hi_f(o[d]));
  }
  #pragma unroll
  for (int i = 0; i < 7; i++) {
    qp[i]     = (unsigned int)hh[2*i] | ((unsigned int)hh[2*i+1] << 16);
    qp[8 + i] = (unsigned int)ll[2*i] | ((unsigned int)ll[2*i+1] << 16);
  }
  qp[7] = 0; qp[15] = 0;
  uint4* d4 = (uint4*)dst;
  #pragma unroll
  for (int i = 0; i < 4; i++)
    d4[i] = make_uint4(qp[4*i], qp[4*i+1], qp[4*i+2], qp[4*i+3]);
}

// ======================================================================
// Legacy 9-kernel path (fallback if cooperative launch is unavailable)
// ======================================================================

__global__ void pack_all(const float* __restrict__ w3, const float* __restrict__ w4,
                         const float* __restrict__ ffw1, const float* __restrict__ ffw2,
                         const float* __restrict__ x, const float* __restrict__ wqkv,
                         const float* __restrict__ bqkv, float* __restrict__ h,
                         unsigned int* __restrict__ Qpack,
                         unsigned int* __restrict__ KB1, unsigned int* __restrict__ KB2,
                         unsigned short* __restrict__ VhiT, unsigned short* __restrict__ VloT,
                         unsigned short* __restrict__ B3h, unsigned short* __restrict__ B3l,
                         unsigned short* __restrict__ B4h, unsigned short* __restrict__ B4l,
                         unsigned int* __restrict__ W1B1, unsigned int* __restrict__ W1B2,
                         unsigned short* __restrict__ W2h, unsigned short* __restrict__ W2l) {
  const int blk = blockIdx.x, tid = threadIdx.x;
  if (blk < 32) {
    int t = blk * 256 + tid;
    int lane = t & 63, ks = (t >> 6) & 7, nt = t >> 9;
    int n = nt * 16 + (lane & 15);
    int k0 = ks * 32 + (lane >> 4) * 8;
    unsigned int h4[4], l4[4];
    #pragma unroll
    for (int jj = 0; jj < 4; jj++) {
      unsigned short h2[2], l2[2];
      #pragma unroll
      for (int e = 0; e < 2; e++) {
        float v = w4[(size_t)n * 256 + k0 + jj * 2 + e];
        h2[e] = bf_hi(v);
        l2[e] = bf_hi(v - bf_hi_f(v));
      }
      h4[jj] = (unsigned int)h2[0] | ((unsigned int)h2[1] << 16);
      l4[jj] = (unsigned int)l2[0] | ((unsigned int)l2[1] << 16);
    }
    ((uint4*)B4h)[t] = make_uint4(h4[0], h4[1], h4[2], h4[3]);
    ((uint4*)B4l)[t] = make_uint4(l4[0], l4[1], l4[2], l4[3]);
    if (ks < 2) {
      int fi = (nt * 2 + ks) * 64 + lane;
      #pragma unroll
      for (int jj = 0; jj < 4; jj++) {
        unsigned short h2[2], l2[2];
        #pragma unroll
        for (int e = 0; e < 2; e++) {
          int k = k0 + jj * 2 + e;
          float v = (k < 51) ? w3[(size_t)n * 51 + k] : 0.f;
          h2[e] = bf_hi(v);
          l2[e] = bf_hi(v - bf_hi_f(v));
        }
        h4[jj] = (unsigned int)h2[0] | ((unsigned int)h2[1] << 16);
        l4[jj] = (unsigned int)l2[0] | ((unsigned int)l2[1] << 16);
      }
      ((uint4*)B3h)[fi] = make_uint4(h4[0], h4[1], h4[2], h4[3]);
      ((uint4*)B3l)[fi] = make_uint4(l4[0], l4[1], l4[2], l4[3]);
    }
  } else if (blk < 48) {
    int t = (blk - 32) * 256 + tid;
    int l = t >> 11, j = t & 2047;
    const float* wrow = ffw1 + ((size_t)l * FF + j) * 14;
    unsigned int k1[16], k2[16];
    unsigned short kh[14], kl[14];
    #pragma unroll
    for (int d = 0; d < 14; d++) {
      float v = wrow[d];
      kh[d] = bf_hi(v);
      kl[d] = bf_hi(v - bf_hi_f(v));
    }
    #pragma unroll
    for (int i = 0; i < 7; i++) {
      k1[i] = (unsigned int)kh[2*i] | ((unsigned int)kh[2*i+1] << 16);
      k1[8 + i] = k1[i];
      k2[i] = (unsigned int)kl[2*i] | ((unsigned int)kl[2*i+1] << 16);
      k2[8 + i] = k2[i];
    }
    k1[7] = 0; k1[15] = 0; k2[7] = 0; k2[15] = 0;
    uint4* d1 = (uint4*)(W1B1 + (size_t)t * 16);
    uint4* d2 = (uint4*)(W1B2 + (size_t)t * 16);
    #pragma unroll
    for (int i = 0; i < 4; i++) {
      d1[i] = make_uint4(k1[4*i], k1[4*i+1], k1[4*i+2], k1[4*i+3]);
      d2[i] = make_uint4(k2[4*i], k2[4*i+1], k2[4*i+2], k2[4*i+3]);
    }
  } else if (blk < 64) {
    int t = (blk - 48) * 256 + tid;
    int l = t >> 11, j = t & 2047;
    #pragma unroll
    for (int d = 0; d < 16; d++) {
      float v = (d < 14) ? ffw2[((size_t)l * 14 + d) * FF + j] : 0.f;
      W2h[((size_t)l * 16 + d) * FF + j] = bf_hi(v);
      W2l[((size_t)l * 16 + d) * FF + j] = bf_hi(v - bf_hi_f(v));
    }
  } else {
    int r = (blk - 64) * 256 + tid;
    float hr[16];
    #pragma unroll
    for (int d = 0; d < 14; d++) hr[d] = x[(size_t)r * 14 + d];
    hr[14] = 0.f; hr[15] = 0.f;
    STORE16(h + (size_t)r * DP, hr);
    qkv_compute_store(r, hr, wqkv, bqkv, Qpack, KB1, KB2, VhiT, VloT);
  }
}

__global__ __launch_bounds__(256, 4) void attn_mfma(
    const unsigned int* __restrict__ Qpack, const unsigned int* __restrict__ KB1,
    const unsigned int* __restrict__ KB2, const unsigned short* __restrict__ VhiT,
    const unsigned short* __restrict__ VloT, float* __restrict__ part) {
  __shared__ float Plds[4][32][36];
  const int tid = threadIdx.x;
  const int wave = tid >> 6;
  const int lane = tid & 63;
  const int lo4 = lane & 15;
  const int hi4 = lane >> 4;
  const int qbase = blockIdx.x * 128 + wave * 32;
  const int kbase0 = blockIdx.y * 512;

  const bf16x8* Qp = (const bf16x8*)Qpack;
  const bf16x8* B1 = (const bf16x8*)KB1;
  const bf16x8* B2 = (const bf16x8*)KB2;
  const bf16x8* Vh = (const bf16x8*)VhiT;
  const bf16x8* Vl = (const bf16x8*)VloT;

  bf16x8 aQ0 = Qp[(size_t)(qbase + lo4) * 4 + hi4];
  bf16x8 aQ1 = Qp[(size_t)(qbase + 16 + lo4) * 4 + hi4];
  f32x4 acc0 = {0.f, 0.f, 0.f, 0.f};
  f32x4 acc1 = {0.f, 0.f, 0.f, 0.f};
  const f32x4 zero = {0.f, 0.f, 0.f, 0.f};

  for (int c = 0; c < 16; c++) {
    const int kb = kbase0 + c * 32;
    bf16x8 b1g0 = B1[(size_t)(kb + lo4) * 4 + hi4];
    bf16x8 b2g0 = B2[(size_t)(kb + lo4) * 4 + hi4];
    bf16x8 b1g1 = B1[(size_t)(kb + 16 + lo4) * 4 + hi4];
    bf16x8 b2g1 = B2[(size_t)(kb + 16 + lo4) * 4 + hi4];
    bf16x8 vh = Vh[(size_t)lo4 * 1024 + (kb >> 3) + hi4];
    bf16x8 vl = Vl[(size_t)lo4 * 1024 + (kb >> 3) + hi4];

    f32x4 s00 = __builtin_amdgcn_mfma_f32_16x16x32_bf16(aQ0, b1g0, zero, 0, 0, 0);
    f32x4 s01 = __builtin_amdgcn_mfma_f32_16x16x32_bf16(aQ0, b1g1, zero, 0, 0, 0);
    f32x4 s10 = __builtin_amdgcn_mfma_f32_16x16x32_bf16(aQ1, b1g0, zero, 0, 0, 0);
    f32x4 s11 = __builtin_amdgcn_mfma_f32_16x16x32_bf16(aQ1, b1g1, zero, 0, 0, 0);
    s00 = __builtin_amdgcn_mfma_f32_16x16x32_bf16(aQ0, b2g0, s00, 0, 0, 0);
    s01 = __builtin_amdgcn_mfma_f32_16x16x32_bf16(aQ0, b2g1, s01, 0, 0, 0);
    s10 = __builtin_amdgcn_mfma_f32_16x16x32_bf16(aQ1, b2g0, s10, 0, 0, 0);
    s11 = __builtin_amdgcn_mfma_f32_16x16x32_bf16(aQ1, b2g1, s11, 0, 0, 0);
    #pragma unroll
    for (int reg = 0; reg < 4; reg++) {
      Plds[wave][hi4 * 4 + reg][lo4]           = fast_exp2(s00[reg]);
      Plds[wave][hi4 * 4 + reg][16 + lo4]      = fast_exp2(s01[reg]);
      Plds[wave][16 + hi4 * 4 + reg][lo4]      = fast_exp2(s10[reg]);
      Plds[wave][16 + hi4 * 4 + reg][16 + lo4] = fast_exp2(s11[reg]);
    }
    __asm__ volatile("s_waitcnt lgkmcnt(0)" ::: "memory");
    const float4* p0 = (const float4*)&Plds[wave][lo4][hi4 * 8];
    const float4* p1 = (const float4*)&Plds[wave][16 + lo4][hi4 * 8];
    float4 a0 = p0[0], a1 = p0[1], c0 = p1[0], c1 = p1[1];
    float pv0[8] = {a0.x, a0.y, a0.z, a0.w, a1.x, a1.y, a1.z, a1.w};
    float pv1[8] = {c0.x, c0.y, c0.z, c0.w, c1.x, c1.y, c1.z, c1.w};
    bf16x8 ph0, pl0, ph1, pl1;
    split8(pv0, &ph0, &pl0);
    split8(pv1, &ph1, &pl1);
    acc0 = __builtin_amdgcn_mfma_f32_16x16x32_bf16(ph0, vh, acc0, 0, 0, 0);
    acc1 = __builtin_amdgcn_mfma_f32_16x16x32_bf16(ph1, vh, acc1, 0, 0, 0);
    acc0 = __builtin_amdgcn_mfma_f32_16x16x32_bf16(pl0, vh, acc0, 0, 0, 0);
    acc1 = __builtin_amdgcn_mfma_f32_16x16x32_bf16(pl1, vh, acc1, 0, 0, 0);
    acc0 = __builtin_amdgcn_mfma_f32_16x16x32_bf16(ph0, vl, acc0, 0, 0, 0);
    acc1 = __builtin_amdgcn_mfma_f32_16x16x32_bf16(ph1, vl, acc1, 0, 0, 0);
    __asm__ volatile("s_waitcnt lgkmcnt(0)" ::: "memory");
  }
  float* pbase = part + (size_t)blockIdx.y * NN * 16;
  #pragma unroll
  for (int reg = 0; reg < 4; reg++) {
    int row0 = qbase + hi4 * 4 + reg;
    pbase[(size_t)row0 * 16 + lo4] = acc0[reg];
    pbase[(size_t)(row0 + 16) * 16 + lo4] = acc1[reg];
  }
}

__global__ void attn_comb_ln1(float* __restrict__ h, const float* __restrict__ part,
                              const float* __restrict__ wo, const float* __restrict__ bo,
                              const float* __restrict__ g, const float* __restrict__ b,
                              unsigned int* __restrict__ Hpack) {
  int t = blockIdx.x * 128 + threadIdx.x;
  int r = t >> 2, q = t & 3;
  float L = 0.f;
  float A[14];
  #pragma unroll
  for (int d = 0; d < 14; d++) A[d] = 0.f;
  #pragma unroll
  for (int c = q; c < NCH; c += 4) {
    float p[16];
    LOAD16(p, part + ((size_t)c * NN + r) * 16);
    L += p[14];
    #pragma unroll
    for (int d = 0; d < 14; d++) A[d] += p[d];
  }
  #pragma unroll
  for (int off = 1; off < 4; off <<= 1) {
    L += __shfl_xor(L, off, 64);
    #pragma unroll
    for (int d = 0; d < 14; d++) A[d] += __shfl_xor(A[d], off, 64);
  }
  if (q == 0) {
    float inv = 1.f / L;
    float a[14];
    #pragma unroll
    for (int d = 0; d < 14; d++) a[d] = A[d] * inv;
    float hr[16];
    LOAD16(hr, h + (size_t)r * DP);
    float xx[14];
    #pragma unroll
    for (int i = 0; i < 14; i++) {
      float s = bo[i];
      #pragma unroll
      for (int d = 0; d < 14; d++) s = fmaf(wo[i * 14 + d], a[d], s);
      xx[i] = hr[i] + s;
    }
    float mu = 0.f;
    #pragma unroll
    for (int i = 0; i < 14; i++) mu += xx[i];
    mu *= (1.f / 14.f);
    float var = 0.f;
    #pragma unroll
    for (int i = 0; i < 14; i++) { float tt = xx[i] - mu; var = fmaf(tt, tt, var); }
    var *= (1.f / 14.f);
    float rs = rsqrtf(var + LN_EPS);
    float o[16];
    #pragma unroll
    for (int i = 0; i < 14; i++) o[i] = fmaf((xx[i] - mu) * rs, g[i], b[i]);
    o[14] = 0.f; o[15] = 0.f;
    STORE16(h + (size_t)r * DP, o);
    store_apack(Hpack + (size_t)r * 16, o);
  }
}

__global__ __launch_bounds__(256, 4) void ffn_mfma(
    const unsigned int* __restrict__ Hpack, const unsigned int* __restrict__ W1B1,
    const unsigned int* __restrict__ W1B2, const unsigned short* __restrict__ W2h,
    const unsigned short* __restrict__ W2l, const float* __restrict__ b1,
    float* __restrict__ part) {
  __shared__ float Plds[4][32][36];
  const int tid = threadIdx.x;
  const int wave = tid >> 6;
  const int lane = tid & 63;
  const int lo4 = lane & 15;
  const int hi4 = lane >> 4;
  const int qbase = blockIdx.x * 128 + wave * 32;
  const int jbase0 = blockIdx.y * 256;

  const bf16x8* Hp = (const bf16x8*)Hpack;
  const bf16x8* B1 = (const bf16x8*)W1B1;
  const bf16x8* B2 = (const bf16x8*)W1B2;
  const bf16x8* Vh = (const bf16x8*)W2h;
  const bf16x8* Vl = (const bf16x8*)W2l;

  bf16x8 aH0 = Hp[(size_t)(qbase + lo4) * 4 + hi4];
  bf16x8 aH1 = Hp[(size_t)(qbase + 16 + lo4) * 4 + hi4];
  f32x4 acc0 = {0.f, 0.f, 0.f, 0.f};
  f32x4 acc1 = {0.f, 0.f, 0.f, 0.f};
  const f32x4 zero = {0.f, 0.f, 0.f, 0.f};

  for (int c = 0; c < 8; c++) {
    const int jb = jbase0 + c * 32;
    bf16x8 b1g0 = B1[(size_t)(jb + lo4) * 4 + hi4];
    bf16x8 b2g0 = B2[(size_t)(jb + lo4) * 4 + hi4];
    bf16x8 b1g1 = B1[(size_t)(jb + 16 + lo4) * 4 + hi4];
    bf16x8 b2g1 = B2[(size_t)(jb + 16 + lo4) * 4 + hi4];
    bf16x8 vh = Vh[(size_t)lo4 * 256 + (jb >> 3) + hi4];
    bf16x8 vl = Vl[(size_t)lo4 * 256 + (jb >> 3) + hi4];
    float bb0 = b1[jb + lo4];
    float bb1 = b1[jb + 16 + lo4];

    f32x4 s00 = __builtin_amdgcn_mfma_f32_16x16x32_bf16(aH0, b1g0, zero, 0, 0, 0);
    f32x4 s01 = __builtin_amdgcn_mfma_f32_16x16x32_bf16(aH0, b1g1, zero, 0, 0, 0);
    f32x4 s10 = __builtin_amdgcn_mfma_f32_16x16x32_bf16(aH1, b1g0, zero, 0, 0, 0);
    f32x4 s11 = __builtin_amdgcn_mfma_f32_16x16x32_bf16(aH1, b1g1, zero, 0, 0, 0);
    s00 = __builtin_amdgcn_mfma_f32_16x16x32_bf16(aH0, b2g0, s00, 0, 0, 0);
    s01 = __builtin_amdgcn_mfma_f32_16x16x32_bf16(aH0, b2g1, s01, 0, 0, 0);
    s10 = __builtin_amdgcn_mfma_f32_16x16x32_bf16(aH1, b2g0, s10, 0, 0, 0);
    s11 = __builtin_amdgcn_mfma_f32_16x16x32_bf16(aH1, b2g1, s11, 0, 0, 0);
    #pragma unroll
    for (int reg = 0; reg < 4; reg++) {
      Plds[wave][hi4 * 4 + reg][lo4]           = fmaxf(s00[reg] + bb0, 0.f);
      Plds[wave][hi4 * 4 + reg][16 + lo4]      = fmaxf(s01[reg] + bb1, 0.f);
      Plds[wave][16 + hi4 * 4 + reg][lo4]      = fmaxf(s10[reg] + bb0, 0.f);
      Plds[wave][16 + hi4 * 4 + reg][16 + lo4] = fmaxf(s11[reg] + bb1, 0.f);
    }
    __asm__ volatile("s_waitcnt lgkmcnt(0)" ::: "memory");
    const float4* p0 = (const float4*)&Plds[wave][lo4][hi4 * 8];
    const float4* p1 = (const float4*)&Plds[wave][16 + lo4][hi4 * 8];
    float4 a0 = p0[0], a1 = p0[1], c0 = p1[0], c1 = p1[1];
    float pv0[8] = {a0.x, a0.y, a0.z, a0.w, a1.x, a1.y, a1.z, a1.w};
    float pv1[8] = {c0.x, c0.y, c0.z, c0.w, c1.x, c1.y, c1.z, c1.w};
    bf16x8 th0, tl0, th1, tl1;
    split8(pv0, &th0, &tl0);
    split8(pv1, &th1, &tl1);
    acc0 = __builtin_amdgcn_mfma_f32_16x16x32_bf16(th0, vh, acc0, 0, 0, 0);
    acc1 = __builtin_amdgcn_mfma_f32_16x16x32_bf16(th1, vh, acc1, 0, 0, 0);
    acc0 = __builtin_amdgcn_mfma_f32_16x16x32_bf16(tl0, vh, acc0, 0, 0, 0);
    acc1 = __builtin_amdgcn_mfma_f32_16x16x32_bf16(tl1, vh, acc1, 0, 0, 0);
    acc0 = __builtin_amdgcn_mfma_f32_16x16x32_bf16(th0, vl, acc0, 0, 0, 0);
    acc1 = __builtin_amdgcn_mfma_f32_16x16x32_bf16(th1, vl, acc1, 0, 0, 0);
    __asm__ volatile("s_waitcnt lgkmcnt(0)" ::: "memory");
  }
  float* pbase = part + (size_t)blockIdx.y * NN * 16;
  #pragma unroll
  for (int reg = 0; reg < 4; reg++) {
    int row0 = qbase + hi4 * 4 + reg;
    pbase[(size_t)row0 * 16 + lo4] = acc0[reg];
    pbase[(size_t)(row0 + 16) * 16 + lo4] = acc1[reg];
  }
}

__global__ void ffn_ln2_qkv(float* __restrict__ h, const float* __restrict__ part,
                            const float* __restrict__ b2, const float* __restrict__ g,
                            const float* __restrict__ b,
                            const float* __restrict__ wqkv, const float* __restrict__ bqkv,
                            unsigned int* __restrict__ Qpack,
                            unsigned int* __restrict__ KB1, unsigned int* __restrict__ KB2,
                            unsigned short* __restrict__ VhiT,
                            unsigned short* __restrict__ VloT) {
  int t = blockIdx.x * 128 + threadIdx.x;
  int r = t >> 2, q = t & 3;
  float f[14];
  #pragma unroll
  for (int d = 0; d < 14; d++) f[d] = 0.f;
  #pragma unroll
  for (int c = q; c < NFCH; c += 4) {
    float p[16];
    LOAD16(p, part + ((size_t)c * NN + r) * 16);
    #pragma unroll
    for (int d = 0; d < 14; d++) f[d] += p[d];
  }
  #pragma unroll
  for (int off = 1; off < 4; off <<= 1) {
    #pragma unroll
    for (int d = 0; d < 14; d++) f[d] += __shfl_xor(f[d], off, 64);
  }
  if (q == 0) {
    float hr[16];
    LOAD16(hr, h + (size_t)r * DP);
    float xx[14];
    #pragma unroll
    for (int i = 0; i < 14; i++) xx[i] = hr[i] + f[i] + b2[i];
    float mu = 0.f;
    #pragma unroll
    for (int i = 0; i < 14; i++) mu += xx[i];
    mu *= (1.f / 14.f);
    float var = 0.f;
    #pragma unroll
    for (int i = 0; i < 14; i++) { float tt = xx[i] - mu; var = fmaf(tt, tt, var); }
    var *= (1.f / 14.f);
    float rs = rsqrtf(var + LN_EPS);
    float o[16];
    #pragma unroll
    for (int i = 0; i < 14; i++) o[i] = fmaf((xx[i] - mu) * rs, g[i], b[i]);
    o[14] = 0.f; o[15] = 0.f;
    STORE16(h + (size_t)r * DP, o);
    qkv_compute_store(r, o, wqkv, bqkv, Qpack, KB1, KB2, VhiT, VloT);
  }
}

__global__ __launch_bounds__(256, 4) void tail_fused(
    const float* __restrict__ h, const float* __restrict__ part,
    const float* __restrict__ b2, const float* __restrict__ g, const float* __restrict__ b,
    const float* __restrict__ fc1w, const float* __restrict__ fc1b,
    const float* __restrict__ fc2w, const float* __restrict__ fc2b,
    const float* __restrict__ x, const float* __restrict__ y,
    const unsigned short* __restrict__ B3h, const unsigned short* __restrict__ B3l,
    const float* __restrict__ b3,
    const unsigned short* __restrict__ B4h, const unsigned short* __restrict__ B4l,
    const float* __restrict__ b4,
    const float* __restrict__ w5, const float* __restrict__ b5,
    float* __restrict__ out, float* __restrict__ outr) {
  __shared__ alignas(16) unsigned short Ah[16][72], Al[16][72];
  __shared__ alignas(16) unsigned short R1h[16][264], R1l[16][264];
  __shared__ float sred[4][16][16];
  __shared__ float szf[16];
  const int tid = threadIdx.x;
  const int wave = tid >> 6;
  const int lane = tid & 63;
  const int lo4 = lane & 15;
  const int hi4 = lane >> 4;
  const int rbase = blockIdx.x * 16;

  if (tid < 128) {
    int m = tid >> 3, c = tid & 7;
    int r = rbase + m;
    float p[16];
    LOAD16(p, part + ((size_t)c * NN + r) * 16);
    float f[14];
    #pragma unroll
    for (int d = 0; d < 14; d++) f[d] = p[d];
    #pragma unroll
    for (int off = 1; off < 8; off <<= 1) {
      #pragma unroll
      for (int d = 0; d < 14; d++) f[d] += __shfl_xor(f[d], off, 64);
    }
    if (c == 0) {
      float hr[16];
      LOAD16(hr, h + (size_t)r * DP);
      float xx[14];
      #pragma unroll
      for (int i = 0; i < 14; i++) xx[i] = hr[i] + f[i] + b2[i];
      float mu = 0.f;
      #pragma unroll
      for (int i = 0; i < 14; i++) mu += xx[i];
      mu *= (1.f / 14.f);
      float var = 0.f;
      #pragma unroll
      for (int i = 0; i < 14; i++) { float tt = xx[i] - mu; var = fmaf(tt, tt, var); }
      var *= (1.f / 14.f);
      float rs = rsqrtf(var + LN_EPS);
      float o[14];
      #pragma unroll
      for (int i = 0; i < 14; i++) o[i] = fmaf((xx[i] - mu) * rs, g[i], b[i]);
      float s = fc2b[0];
      #pragma unroll
      for (int i = 0; i < 14; i++) {
        float tt = fc1b[i];
        #pragma unroll
        for (int d = 0; d < 14; d++) tt = fmaf(fc1w[i * 14 + d], o[d], tt);
        s = fmaf(tt, fc2w[i], s);
      }
      out[r] = s;
      int si = (int)s;
      szf[m] = (float)si;
    }
  }
  __syncthreads();

  for (int idx = tid; idx < 16 * 64; idx += 256) {
    int m = idx >> 6, k = idx & 63;
    int r = rbase + m;
    float v = 0.f;
    if (k == 0)       v = szf[m];
    else if (k < 15)  v = x[(size_t)r * 14 + (k - 1)];
    else if (k < 51)  v = y[(size_t)r * 36 + (k - 15)];
    Ah[m][k] = bf_hi(v);
    Al[m][k] = bf_hi(v - bf_hi_f(v));
  }
  __syncthreads();

  const f32x4 zero = {0.f, 0.f, 0.f, 0.f};
  f32x4 acc[4];
  #pragma unroll
  for (int nt = 0; nt < 4; nt++) acc[nt] = zero;

  #pragma unroll
  for (int ks = 0; ks < 2; ks++) {
    bf16x8 ah = *(const bf16x8*)&Ah[lo4][ks * 32 + hi4 * 8];
    bf16x8 al = *(const bf16x8*)&Al[lo4][ks * 32 + hi4 * 8];
    #pragma unroll
    for (int nt = 0; nt < 4; nt++) {
      int fi = ((wave * 4 + nt) * 2 + ks) * 64 + lane;
      bf16x8 bh = ((const bf16x8*)B3h)[fi];
      bf16x8 bl = ((const bf16x8*)B3l)[fi];
      acc[nt] = __builtin_amdgcn_mfma_f32_16x16x32_bf16(ah, bh, acc[nt], 0, 0, 0);
      acc[nt] = __builtin_amdgcn_mfma_f32_16x16x32_bf16(al, bh, acc[nt], 0, 0, 0);
      acc[nt] = __builtin_amdgcn_mfma_f32_16x16x32_bf16(ah, bl, acc[nt], 0, 0, 0);
    }
  }
  #pragma unroll
  for (int nt = 0; nt < 4; nt++) {
    int n = (wave * 4 + nt) * 16 + lo4;
    float bb = b3[n];
    #pragma unroll
    for (int reg = 0; reg < 4; reg++) {
      int m = hi4 * 4 + reg;
      float v = fmaxf(acc[nt][reg] + bb, 0.f);
      R1h[m][n] = bf_hi(v);
      R1l[m][n] = bf_hi(v - bf_hi_f(v));
    }
  }
  __syncthreads();

  #pragma unroll
  for (int nt = 0; nt < 4; nt++) acc[nt] = zero;
  #pragma unroll
  for (int ks = 0; ks < 8; ks++) {
    bf16x8 ah = *(const bf16x8*)&R1h[lo4][ks * 32 + hi4 * 8];
    bf16x8 al = *(const bf16x8*)&R1l[lo4][ks * 32 + hi4 * 8];
    #pragma unroll
    for (int nt = 0; nt < 4; nt++) {
      int fi = ((wave * 4 + nt) * 8 + ks) * 64 + lane;
      bf16x8 bh = ((const bf16x8*)B4h)[fi];
      bf16x8 bl = ((const bf16x8*)B4l)[fi];
      acc[nt] = __builtin_amdgcn_mfma_f32_16x16x32_bf16(ah, bh, acc[nt], 0, 0, 0);
      acc[nt] = __builtin_amdgcn_mfma_f32_16x16x32_bf16(al, bh, acc[nt], 0, 0, 0);
      acc[nt] = __builtin_amdgcn_mfma_f32_16x16x32_bf16(ah, bl, acc[nt], 0, 0, 0);
    }
  }
  float s[4] = {0.f, 0.f, 0.f, 0.f};
  #pragma unroll
  for (int nt = 0; nt < 4; nt++) {
    int n = (wave * 4 + nt) * 16 + lo4;
    float bb = b4[n], ww = w5[n];
    #pragma unroll
    for (int reg = 0; reg < 4; reg++)
      s[reg] = fmaf(fmaxf(acc[nt][reg] + bb, 0.f), ww, s[reg]);
  }
  #pragma unroll
  for (int reg = 0; reg < 4; reg++) sred[wave][hi4 * 4 + reg][lo4] = s[reg];
  __syncthreads();

  if (tid < 16) {
    float t = b5[0];
    #pragma unroll
    for (int w = 0; w < 4; w++) {
      const float4* p = (const float4*)&sred[w][tid][0];
      float4 a0 = p[0], a1 = p[1], a2 = p[2], a3 = p[3];
      t += ((a0.x + a0.y) + (a0.z + a0.w)) + ((a1.x + a1.y) + (a1.z + a1.w)) +
           ((a2.x + a2.y) + (a2.z + a2.w)) + ((a3.x + a3.y) + (a3.z + a3.w));
    }
    float sz = szf[tid];
    outr[rbase + tid] = (sz != 0.f) ? t : 0.f;
  }
}

// ======================================================================
// Fused cooperative pipeline: one launch, 8 grid syncs instead of 8
// kernel-boundary drains.  Grid-stride virtual blocks; launch_bounds
// relaxed to (256,2) so the register allocator gets up to 256 VGPRs —
// round-1's (256,4) forced 64 VGPRs and ~375 MB of scratch spills.
// ======================================================================

struct P26 {
  const float *x, *y, *wqkv, *bqkv, *wo, *bo, *ln1g, *ln1b;
  const float *ffw1, *ffb1, *ffw2, *ffb2, *ln2g, *ln2b;
  const float *fc1w, *fc1b, *fc2w, *fc2b, *fc3w, *fc3b, *fc4w, *fc4b, *fc5w, *fc5b;
  float* ws;
  float* out;
};

__global__ __launch_bounds__(256, 2) void fused_pipeline(P26 p) {
  cg::grid_group grid = cg::this_grid();
  // LDS union: attn/ffn use [4][32][36] f32 (18432B); tail uses 25664B layout.
  __shared__ __attribute__((aligned(16))) char smem[25664];
  const int tid = threadIdx.x;
  const int wave = tid >> 6;
  const int lane = tid & 63;
  const int lo4 = lane & 15;
  const int hi4 = lane >> 4;

  float* ws = p.ws;
  float*          h     = ws;
  unsigned int*   Qpack = (unsigned int*)(ws + 131072);
  unsigned int*   KB1   = (unsigned int*)(ws + 262144);
  unsigned int*   KB2   = (unsigned int*)(ws + 393216);
  unsigned short* VhiT  = (unsigned short*)(ws + 524288);
  unsigned short* VloT  = (unsigned short*)(ws + 589824);
  unsigned int*   Hpack = (unsigned int*)(ws + 655360);
  float*          part  = ws + 786432;            // 16*8192*16 floats
  unsigned short* B3h   = (unsigned short*)(ws + 2891776);
  unsigned short* B3l   = (unsigned short*)(ws + 2899968);
  unsigned short* B4h   = (unsigned short*)(ws + 2908160);
  unsigned short* B4l   = (unsigned short*)(ws + 2940928);
  unsigned int*   W1B1  = (unsigned int*)(ws + 2973696);
  unsigned int*   W1B2  = (unsigned int*)(ws + 3039232);
  unsigned short* W2h   = (unsigned short*)(ws + 3104768);
  unsigned short* W2l   = (unsigned short*)(ws + 3137536);
  float* out  = p.out;
  float* outr = p.out + NN;

  // ---------------- P0: weight packs + layer-0 qkv ----------------
  for (int vb = blockIdx.x; vb < 96; vb += gridDim.x) {
    if (vb < 32) {
      int t = vb * 256 + tid;
      int ln = t & 63, ks = (t >> 6) & 7, nt = t >> 9;
      int n = nt * 16 + (ln & 15);
      int k0 = ks * 32 + (ln >> 4) * 8;
      unsigned int h4[4], l4[4];
      #pragma unroll
      for (int jj = 0; jj < 4; jj++) {
        unsigned short h2[2], l2[2];
        #pragma unroll
        for (int e = 0; e < 2; e++) {
          float v = p.fc4w[(size_t)n * 256 + k0 + jj * 2 + e];
          h2[e] = bf_hi(v);
          l2[e] = bf_hi(v - bf_hi_f(v));
        }
        h4[jj] = (unsigned int)h2[0] | ((unsigned int)h2[1] << 16);
        l4[jj] = (unsigned int)l2[0] | ((unsigned int)l2[1] << 16);
      }
      ((uint4*)B4h)[t] = make_uint4(h4[0], h4[1], h4[2], h4[3]);
      ((uint4*)B4l)[t] = make_uint4(l4[0], l4[1], l4[2], l4[3]);
      if (ks < 2) {
        int fi = (nt * 2 + ks) * 64 + ln;
        #pragma unroll
        for (int jj = 0; jj < 4; jj++) {
          unsigned short h2[2], l2[2];
          #pragma unroll
          for (int e = 0; e < 2; e++) {
            int k = k0 + jj * 2 + e;
            float v = (k < 51) ? p.fc3w[(size_t)n * 51 + k] : 0.f;
            h2[e] = bf_hi(v);
            l2[e] = bf_hi(v - bf_hi_f(v));
          }
          h4[jj] = (unsigned int)h2[0] | ((unsigned int)h2[1] << 16);
          l4[jj] = (unsigned int)l2[0] | ((unsigned int)l2[1] << 16);
        }
        ((uint4*)B3h)[fi] = make_uint4(h4[0], h4[1], h4[2], h4[3]);
        ((uint4*)B3l)[fi] = make_uint4(l4[0], l4[1], l4[2], l4[3]);
      }
    } else if (vb < 48) {
      int t = (vb - 32) * 256 + tid;
      int lw = t >> 11, j = t & 2047;
      const float* wrow = p.ffw1 + ((size_t)lw * FF + j) * 14;
      unsigned int k1[16], k2[16];
      unsigned short kh[14], kl[14];
      #pragma unroll
      for (int d = 0; d < 14; d++) {
        float v = wrow[d];
        kh[d] = bf_hi(v);
        kl[d] = bf_hi(v - bf_hi_f(v));
      }
      #pragma unroll
      for (int i = 0; i < 7; i++) {
        k1[i] = (unsigned int)kh[2*i] | ((unsigned int)kh[2*i+1] << 16);
        k1[8 + i] = k1[i];
        k2[i] = (unsigned int)kl[2*i] | ((unsigned int)kl[2*i+1] << 16);
        k2[8 + i] = k2[i];
      }
      k1[7] = 0; k1[15] = 0; k2[7] = 0; k2[15] = 0;
      uint4* d1 = (uint4*)(W1B1 + (size_t)t * 16);
      uint4* d2 = (uint4*)(W1B2 + (size_t)t * 16);
      #pragma unroll
      for (int i = 0; i < 4; i++) {
        d1[i] = make_uint4(k1[4*i], k1[4*i+1], k1[4*i+2], k1[4*i+3]);
        d2[i] = make_uint4(k2[4*i], k2[4*i+1], k2[4*i+2], k2[4*i+3]);
      }
    } else if (vb < 64) {
      int t = (vb - 48) * 256 + tid;
      int lw = t >> 11, j = t & 2047;
      #pragma unroll
      for (int d = 0; d < 16; d++) {
        float v = (d < 14) ? p.ffw2[((size_t)lw * 14 + d) * FF + j] : 0.f;
        W2h[((size_t)lw * 16 + d) * FF + j] = bf_hi(v);
        W2l[((size_t)lw * 16 + d) * FF + j] = bf_hi(v - bf_hi_f(v));
      }
    } else {
      int r = (vb - 64) * 256 + tid;
      float hr[16];
      #pragma unroll
      for (int d = 0; d < 14; d++) hr[d] = p.x[(size_t)r * 14 + d];
      hr[14] = 0.f; hr[15] = 0.f;
      STORE16(h + (size_t)r * DP, hr);
      qkv_compute_store(r, hr, p.wqkv, p.bqkv, Qpack, KB1, KB2, VhiT, VloT);
    }
  }
  grid.sync();

  const bf16x8* Qp  = (const bf16x8*)Qpack;
  const bf16x8* Kb1 = (const bf16x8*)KB1;
  const bf16x8* Kb2 = (const bf16x8*)KB2;
  const bf16x8* Vh  = (const bf16x8*)VhiT;
  const bf16x8* Vl  = (const bf16x8*)VloT;
  const bf16x8* Hp  = (const bf16x8*)Hpack;
  const f32x4 zero = {0.f, 0.f, 0.f, 0.f};

  for (int l = 0; l < 2; l++) {
    // ---------------- attention phase 1 (1024 vblocks) ----------------
    for (int vb = blockIdx.x; vb < 1024; vb += gridDim.x) {
      float (*Pl)[36] = reinterpret_cast<float(*)[36]>(smem + wave * 4608);
      const int qbase = (vb & 63) * 128 + wave * 32;
      const int kbase0 = (vb >> 6) * 512;
      bf16x8 aQ0 = Qp[(size_t)(qbase + lo4) * 4 + hi4];
      bf16x8 aQ1 = Qp[(size_t)(qbase + 16 + lo4) * 4 + hi4];
      f32x4 acc0 = zero, acc1 = zero;
      for (int c = 0; c < 16; c++) {
        const int kb = kbase0 + c * 32;
        bf16x8 b1g0 = Kb1[(size_t)(kb + lo4) * 4 + hi4];
        bf16x8 b2g0 = Kb2[(size_t)(kb + lo4) * 4 + hi4];
        bf16x8 b1g1 = Kb1[(size_t)(kb + 16 + lo4) * 4 + hi4];
        bf16x8 b2g1 = Kb2[(size_t)(kb + 16 + lo4) * 4 + hi4];
        bf16x8 vh = Vh[(size_t)lo4 * 1024 + (kb >> 3) + hi4];
        bf16x8 vl = Vl[(size_t)lo4 * 1024 + (kb >> 3) + hi4];

        f32x4 s00 = __builtin_amdgcn_mfma_f32_16x16x32_bf16(aQ0, b1g0, zero, 0, 0, 0);
        f32x4 s01 = __builtin_amdgcn_mfma_f32_16x16x32_bf16(aQ0, b1g1, zero, 0, 0, 0);
        f32x4 s10 = __builtin_amdgcn_mfma_f32_16x16x32_bf16(aQ1, b1g0, zero, 0, 0, 0);
        f32x4 s11 = __builtin_amdgcn_mfma_f32_16x16x32_bf16(aQ1, b1g1, zero, 0, 0, 0);
        s00 = __builtin_amdgcn_mfma_f32_16x16x32_bf16(aQ0, b2g0, s00, 0, 0, 0);
        s01 = __builtin_amdgcn_mfma_f32_16x16x32_bf16(aQ0, b2g1, s01, 0, 0, 0);
        s10 = __builtin_amdgcn_mfma_f32_16x16x32_bf16(aQ1, b2g0, s10, 0, 0, 0);
        s11 = __builtin_amdgcn_mfma_f32_16x16x32_bf16(aQ1, b2g1, s11, 0, 0, 0);
        #pragma unroll
        for (int reg = 0; reg < 4; reg++) {
          Pl[hi4 * 4 + reg][lo4]           = fast_exp2(s00[reg]);
          Pl[hi4 * 4 + reg][16 + lo4]      = fast_exp2(s01[reg]);
          Pl[16 + hi4 * 4 + reg][lo4]      = fast_exp2(s10[reg]);
          Pl[16 + hi4 * 4 + reg][16 + lo4] = fast_exp2(s11[reg]);
        }
        __asm__ volatile("s_waitcnt lgkmcnt(0)" ::: "memory");
        const float4* p0 = (const float4*)&Pl[lo4][hi4 * 8];
        const float4* p1 = (const float4*)&Pl[16 + lo4][hi4 * 8];
        float4 a0 = p0[0], a1 = p0[1], c0 = p1[0], c1 = p1[1];
        float pv0[8] = {a0.x, a0.y, a0.z, a0.w, a1.x, a1.y, a1.z, a1.w};
        float pv1[8] = {c0.x, c0.y, c0.z, c0.w, c1.x, c1.y, c1.z, c1.w};
        bf16x8 ph0, pl0, ph1, pl1;
        split8(pv0, &ph0, &pl0);
        split8(pv1, &ph1, &pl1);
        acc0 = __builtin_amdgcn_mfma_f32_16x16x32_bf16(ph0, vh, acc0, 0, 0, 0);
        acc1 = __builtin_amdgcn_mfma_f32_16x16x32_bf16(ph1, vh, acc1, 0, 0, 0);
        acc0 = __builtin_amdgcn_mfma_f32_16x16x32_bf16(pl0, vh, acc0, 0, 0, 0);
        acc1 = __builtin_amdgcn_mfma_f32_16x16x32_bf16(pl1, vh, acc1, 0, 0, 0);
        acc0 = __builtin_amdgcn_mfma_f32_16x16x32_bf16(ph0, vl, acc0, 0, 0, 0);
        acc1 = __builtin_amdgcn_mfma_f32_16x16x32_bf16(ph1, vl, acc1, 0, 0, 0);
        __asm__ volatile("s_waitcnt lgkmcnt(0)" ::: "memory");
      }
      float* pbase = part + (size_t)(vb >> 6) * NN * 16;
      #pragma unroll
      for (int reg = 0; reg < 4; reg++) {
        int row0 = qbase + hi4 * 4 + reg;
        pbase[(size_t)row0 * 16 + lo4] = acc0[reg];
        pbase[(size_t)(row0 + 16) * 16 + lo4] = acc1[reg];
      }
    }
    grid.sync();

    // ---------------- attn combine + LN1 (32 thr/row) ----------------
    {
      const float* wol = p.wo + (size_t)l * 196;
      const float* bol = p.bo + (size_t)l * 14;
      const float* g1  = p.ln1g + (size_t)l * 14;
      const float* bl1 = p.ln1b + (size_t)l * 14;
      for (int vb = blockIdx.x; vb < 1024; vb += gridDim.x) {
        int t = vb * 256 + tid;
        int r = t >> 5, q = t & 31;
        float L = 0.f;
        float A[14];
        #pragma unroll
        for (int d = 0; d < 14; d++) A[d] = 0.f;
        if (q < 16) {
          float pp[16];
          LOAD16(pp, part + ((size_t)q * NN + r) * 16);
          L = pp[14];
          #pragma unroll
          for (int d = 0; d < 14; d++) A[d] = pp[d];
        }
        #pragma unroll
        for (int off = 1; off < 16; off <<= 1) {
          L += __shfl_xor(L, off, 64);
          #pragma unroll
          for (int d = 0; d < 14; d++) A[d] += __shfl_xor(A[d], off, 64);
        }
        if (q == 0) {
          float inv = 1.f / L;
          float a[14];
          #pragma unroll
          for (int d = 0; d < 14; d++) a[d] = A[d] * inv;
          float hr[16];
          LOAD16(hr, h + (size_t)r * DP);
          float xx[14];
          #pragma unroll
          for (int i = 0; i < 14; i++) {
            float s = bol[i];
            #pragma unroll
            for (int d = 0; d < 14; d++) s = fmaf(wol[i * 14 + d], a[d], s);
            xx[i] = hr[i] + s;
          }
          float mu = 0.f;
          #pragma unroll
          for (int i = 0; i < 14; i++) mu += xx[i];
          mu *= (1.f / 14.f);
          float var = 0.f;
          #pragma unroll
          for (int i = 0; i < 14; i++) { float tt = xx[i] - mu; var = fmaf(tt, tt, var); }
          var *= (1.f / 14.f);
          float rs = rsqrtf(var + LN_EPS);
          float o[16];
          #pragma unroll
          for (int i = 0; i < 14; i++) o[i] = fmaf((xx[i] - mu) * rs, g1[i], bl1[i]);
          o[14] = 0.f; o[15] = 0.f;
          STORE16(h + (size_t)r * DP, o);
          store_apack(Hpack + (size_t)r * 16, o);
        }
      }
    }
    grid.sync();

    // ---------------- ffn phase 1 (1024 vblocks, 16 neuron-chunks) ----------------
    {
      const bf16x8* Wb1 = (const bf16x8*)(W1B1 + (size_t)l * 2048 * 16);
      const bf16x8* Wb2 = (const bf16x8*)(W1B2 + (size_t)l * 2048 * 16);
      const bf16x8* Wvh = (const bf16x8*)(W2h + (size_t)l * 16 * FF);
      const bf16x8* Wvl = (const bf16x8*)(W2l + (size_t)l * 16 * FF);
      const float* fb1 = p.ffb1 + (size_t)l * FF;
      for (int vb = blockIdx.x; vb < 1024; vb += gridDim.x) {
        float (*Pl)[36] = reinterpret_cast<float(*)[36]>(smem + wave * 4608);
        const int qbase = (vb & 63) * 128 + wave * 32;
        const int jbase0 = (vb >> 6) * 128;
        bf16x8 aH0 = Hp[(size_t)(qbase + lo4) * 4 + hi4];
        bf16x8 aH1 = Hp[(size_t)(qbase + 16 + lo4) * 4 + hi4];
        f32x4 acc0 = zero, acc1 = zero;
        for (int c = 0; c < 4; c++) {
          const int jb = jbase0 + c * 32;
          bf16x8 b1g0 = Wb1[(size_t)(jb + lo4) * 4 + hi4];
          bf16x8 b2g0 = Wb2[(size_t)(jb + lo4) * 4 + hi4];
          bf16x8 b1g1 = Wb1[(size_t)(jb + 16 + lo4) * 4 + hi4];
          bf16x8 b2g1 = Wb2[(size_t)(jb + 16 + lo4) * 4 + hi4];
          bf16x8 vh = Wvh[(size_t)lo4 * 256 + (jb >> 3) + hi4];
          bf16x8 vl = Wvl[(size_t)lo4 * 256 + (jb >> 3) + hi4];
          float bb0 = fb1[jb + lo4];
          float bb1 = fb1[jb + 16 + lo4];

          f32x4 s00 = __builtin_amdgcn_mfma_f32_16x16x32_bf16(aH0, b1g0, zero, 0, 0, 0);
          f32x4 s01 = __builtin_amdgcn_mfma_f32_16x16x32_bf16(aH0, b1g1, zero, 0, 0, 0);
          f32x4 s10 = __builtin_amdgcn_mfma_f32_16x16x32_bf16(aH1, b1g0, zero, 0, 0, 0);
          f32x4 s11 = __builtin_amdgcn_mfma_f32_16x16x32_bf16(aH1, b1g1, zero, 0, 0, 0);
          s00 = __builtin_amdgcn_mfma_f32_16x16x32_bf16(aH0, b2g0, s00, 0, 0, 0);
          s01 = __builtin_amdgcn_mfma_f32_16x16x32_bf16(aH0, b2g1, s01, 0, 0, 0);
          s10 = __builtin_amdgcn_mfma_f32_16x16x32_bf16(aH1, b2g0, s10, 0, 0, 0);
          s11 = __builtin_amdgcn_mfma_f32_16x16x32_bf16(aH1, b2g1, s11, 0, 0, 0);
          #pragma unroll
          for (int reg = 0; reg < 4; reg++) {
            Pl[hi4 * 4 + reg][lo4]           = fmaxf(s00[reg] + bb0, 0.f);
            Pl[hi4 * 4 + reg][16 + lo4]      = fmaxf(s01[reg] + bb1, 0.f);
            Pl[16 + hi4 * 4 + reg][lo4]      = fmaxf(s10[reg] + bb0, 0.f);
            Pl[16 + hi4 * 4 + reg][16 + lo4] = fmaxf(s11[reg] + bb1, 0.f);
          }
          __asm__ volatile("s_waitcnt lgkmcnt(0)" ::: "memory");
          const float4* p0 = (const float4*)&Pl[lo4][hi4 * 8];
          const float4* p1 = (const float4*)&Pl[16 + lo4][hi4 * 8];
          float4 a0 = p0[0], a1 = p0[1], c0 = p1[0], c1 = p1[1];
          float pv0[8] = {a0.x, a0.y, a0.z, a0.w, a1.x, a1.y, a1.z, a1.w};
          float pv1[8] = {c0.x, c0.y, c0.z, c0.w, c1.x, c1.y, c1.z, c1.w};
          bf16x8 th0, tl0, th1, tl1;
          split8(pv0, &th0, &tl0);
          split8(pv1, &th1, &tl1);
          acc0 = __builtin_amdgcn_mfma_f32_16x16x32_bf16(th0, vh, acc0, 0, 0, 0);
          acc1 = __builtin_amdgcn_mfma_f32_16x16x32_bf16(th1, vh, acc1, 0, 0, 0);
          acc0 = __builtin_amdgcn_mfma_f32_16x16x32_bf16(tl0, vh, acc0, 0, 0, 0);
          acc1 = __builtin_amdgcn_mfma_f32_16x16x32_bf16(tl1, vh, acc1, 0, 0, 0);
          acc0 = __builtin_amdgcn_mfma_f32_16x16x32_bf16(th0, vl, acc0, 0, 0, 0);
          acc1 = __builtin_amdgcn_mfma_f32_16x16x32_bf16(th1, vl, acc1, 0, 0, 0);
          __asm__ volatile("s_waitcnt lgkmcnt(0)" ::: "memory");
        }
        float* pbase = part + (size_t)(vb >> 6) * NN * 16;
        #pragma unroll
        for (int reg = 0; reg < 4; reg++) {
          int row0 = qbase + hi4 * 4 + reg;
          pbase[(size_t)row0 * 16 + lo4] = acc0[reg];
          pbase[(size_t)(row0 + 16) * 16 + lo4] = acc1[reg];
        }
      }
    }
    grid.sync();

    if (l == 0) {
      // ---------- ffn combine + LN2 + next-layer qkv (32 thr/row) ----------
      for (int vb = blockIdx.x; vb < 1024; vb += gridDim.x) {
        int t = vb * 256 + tid;
        int r = t >> 5, q = t & 31;
        float f[14];
        #pragma unroll
        for (int d = 0; d < 14; d++) f[d] = 0.f;
        if (q < 16) {
          float pp[16];
          LOAD16(pp, part + ((size_t)q * NN + r) * 16);
          #pragma unroll
          for (int d = 0; d < 14; d++) f[d] = pp[d];
        }
        #pragma unroll
        for (int off = 1; off < 16; off <<= 1) {
          #pragma unroll
          for (int d = 0; d < 14; d++) f[d] += __shfl_xor(f[d], off, 64);
        }
        if (q == 0) {
          float hr[16];
          LOAD16(hr, h + (size_t)r * DP);
          float xx[14];
          #pragma unroll
          for (int i = 0; i < 14; i++) xx[i] = hr[i] + f[i] + p.ffb2[i];
          float mu = 0.f;
          #pragma unroll
          for (int i = 0; i < 14; i++) mu += xx[i];
          mu *= (1.f / 14.f);
          float var = 0.f;
          #pragma unroll
          for (int i = 0; i < 14; i++) { float tt = xx[i] - mu; var = fmaf(tt, tt, var); }
          var *= (1.f / 14.f);
          float rs = rsqrtf(var + LN_EPS);
          float o[16];
          #pragma unroll
          for (int i = 0; i < 14; i++) o[i] = fmaf((xx[i] - mu) * rs, p.ln2g[i], p.ln2b[i]);
          o[14] = 0.f; o[15] = 0.f;
          STORE16(h + (size_t)r * DP, o);
          qkv_compute_store(r, o, p.wqkv + 588, p.bqkv + 42, Qpack, KB1, KB2, VhiT, VloT);
        }
      }
      grid.sync();
    }
  }

  // ---------------- tail: combine + LN2 + size head + regression ----------------
  {
    unsigned short (*Ah)[72]  = (unsigned short(*)[72])(smem);
    unsigned short (*Al)[72]  = (unsigned short(*)[72])(smem + 2304);
    unsigned short (*R1h)[264] = (unsigned short(*)[264])(smem + 4608);
    unsigned short (*R1l)[264] = (unsigned short(*)[264])(smem + 13056);
    float (*sred)[16][16] = (float(*)[16][16])(smem + 21504);
    float* szf = (float*)(smem + 25600);
    const float* b2t = p.ffb2 + 14;
    const float* g2t = p.ln2g + 14;
    const float* bb2t = p.ln2b + 14;

    for (int vb = blockIdx.x; vb < 512; vb += gridDim.x) {
      const int rbase = vb * 16;
      {
        int m = tid >> 4, c = tid & 15;
        int r = rbase + m;
        float pp[16];
        LOAD16(pp, part + ((size_t)c * NN + r) * 16);
        float f[14];
        #pragma unroll
        for (int d = 0; d < 14; d++) f[d] = pp[d];
        #pragma unroll
        for (int off = 1; off < 16; off <<= 1) {
          #pragma unroll
          for (int d = 0; d < 14; d++) f[d] += __shfl_xor(f[d], off, 64);
        }
        if (c == 0) {
          float hr[16];
          LOAD16(hr, h + (size_t)r * DP);
          float xx[14];
          #pragma unroll
          for (int i = 0; i < 14; i++) xx[i] = hr[i] + f[i] + b2t[i];
          float mu = 0.f;
          #pragma unroll
          for (int i = 0; i < 14; i++) mu += xx[i];
          mu *= (1.f / 14.f);
          float var = 0.f;
          #pragma unroll
          for (int i = 0; i < 14; i++) { float tt = xx[i] - mu; var = fmaf(tt, tt, var); }
          var *= (1.f / 14.f);
          float rs = rsqrtf(var + LN_EPS);
          float o[14];
          #pragma unroll
          for (int i = 0; i < 14; i++) o[i] = fmaf((xx[i] - mu) * rs, g2t[i], bb2t[i]);
          float s = p.fc2b[0];
          #pragma unroll
          for (int i = 0; i < 14; i++) {
            float tt = p.fc1b[i];
            #pragma unroll
            for (int d = 0; d < 14; d++) tt = fmaf(p.fc1w[i * 14 + d], o[d], tt);
            s = fmaf(tt, p.fc2w[i], s);
          }
          out[r] = s;
          int si = (int)s;
          szf[m] = (float)si;
        }
      }
      __syncthreads();

      for (int idx = tid; idx < 16 * 64; idx += 256) {
        int m = idx >> 6, k = idx & 63;
        int r = rbase + m;
        float v = 0.f;
        if (k == 0)       v = szf[m];
        else if (k < 15)  v = p.x[(size_t)r * 14 + (k - 1)];
        else if (k < 51)  v = p.y[(size_t)r * 36 + (k - 15)];
        Ah[m][k] = bf_hi(v);
        Al[m][k] = bf_hi(v - bf_hi_f(v));
      }
      __syncthreads();

      f32x4 acc[4];
      #pragma unroll
      for (int nt = 0; nt < 4; nt++) acc[nt] = zero;
      #pragma unroll
      for (int ks = 0; ks < 2; ks++) {
        bf16x8 ah = *(const bf16x8*)&Ah[lo4][ks * 32 + hi4 * 8];
        bf16x8 al = *(const bf16x8*)&Al[lo4][ks * 32 + hi4 * 8];
        #pragma unroll
        for (int nt = 0; nt < 4; nt++) {
          int fi = ((wave * 4 + nt) * 2 + ks) * 64 + lane;
          bf16x8 bh = ((const bf16x8*)B3h)[fi];
          bf16x8 bl = ((const bf16x8*)B3l)[fi];
          acc[nt] = __builtin_amdgcn_mfma_f32_16x16x32_bf16(ah, bh, acc[nt], 0, 0, 0);
          acc[nt] = __builtin_amdgcn_mfma_f32_16x16x32_bf16(al, bh, acc[nt], 0, 0, 0);
          acc[nt] = __builtin_amdgcn_mfma_f32_16x16x32_bf16(ah, bl, acc[nt], 0, 0, 0);
        }
      }
      #pragma unroll
      for (int nt = 0; nt < 4; nt++) {
        int n = (wave * 4 + nt) * 16 + lo4;
        float bb = p.fc3b[n];
        #pragma unroll
        for (int reg = 0; reg < 4; reg++) {
          int m = hi4 * 4 + reg;
          float v = fmaxf(acc[nt][reg] + bb, 0.f);
          R1h[m][n] = bf_hi(v);
          R1l[m][n] = bf_hi(v - bf_hi_f(v));
        }
      }
      __syncthreads();

      #pragma unroll
      for (int nt = 0; nt < 4; nt++) acc[nt] = zero;
      #pragma unroll
      for (int ks = 0; ks < 8; ks++) {
        bf16x8 ah = *(const bf16x8*)&R1h[lo4][ks * 32 + hi4 * 8];
        bf16x8 al = *(const bf16x8*)&R1l[lo4][ks * 32 + hi4 * 8];
        #pragma unroll
        for (int nt = 0; nt < 4; nt++) {
          int fi = ((wave * 4 + nt) * 8 + ks) * 64 + lane;
          bf16x8 bh = ((const bf16x8*)B4h)[fi];
          bf16x8 bl = ((const bf16x8*)B4l)[fi];
          acc[nt] = __builtin_amdgcn_mfma_f32_16x16x32_bf16(ah, bh, acc[nt], 0, 0, 0);
          acc[nt] = __builtin_amdgcn_mfma_f32_16x16x32_bf16(al, bh, acc[nt], 0, 0, 0);
          acc[nt] = __builtin_amdgcn_mfma_f32_16x16x32_bf16(ah, bl, acc[nt], 0, 0, 0);
        }
      }
      float s4[4] = {0.f, 0.f, 0.f, 0.f};
      #pragma unroll
      for (int nt = 0; nt < 4; nt++) {
        int n = (wave * 4 + nt) * 16 + lo4;
        float bb = p.fc4b[n], ww = p.fc5w[n];
        #pragma unroll
        for (int reg = 0; reg < 4; reg++)
          s4[reg] = fmaf(fmaxf(acc[nt][reg] + bb, 0.f), ww, s4[reg]);
      }
      #pragma unroll
      for (int reg = 0; reg < 4; reg++) sred[wave][hi4 * 4 + reg][lo4] = s4[reg];
      __syncthreads();

      if (tid < 16) {
        float tsum = p.fc5b[0];
        #pragma unroll
        for (int w = 0; w < 4; w++) {
          const float4* pr = (const float4*)&sred[w][tid][0];
          float4 a0 = pr[0], a1 = pr[1], a2 = pr[2], a3 = pr[3];
          tsum += ((a0.x + a0.y) + (a0.z + a0.w)) + ((a1.x + a1.y) + (a1.z + a1.w)) +
                  ((a2.x + a2.y) + (a2.z + a2.w)) + ((a3.x + a3.y) + (a3.z + a3.w));
        }
        float sz = szf[tid];
        outr[rbase + tid] = (sz != 0.f) ? tsum : 0.f;
      }
      __syncthreads();   // szf/Ah reused next vb iteration
    }
  }
}

extern "C" void kernel_launch(void* const* d_in, const int* in_sizes, int n_in,
                              void* d_out, int out_size, void* d_ws, size_t ws_size,
                              hipStream_t stream) {
  const float* x    = (const float*)d_in[0];
  const float* y    = (const float*)d_in[1];
  const float* wqkv = (const float*)d_in[2];
  const float* bqkv = (const float*)d_in[3];
  const float* wo   = (const float*)d_in[4];
  const float* bo   = (const float*)d_in[5];
  const float* ln1g = (const float*)d_in[6];
  const float* ln1b = (const float*)d_in[7];
  const float* ffw1 = (const float*)d_in[8];
  const float* ffb1 = (const float*)d_in[9];
  const float* ffw2 = (const float*)d_in[10];
  const float* ffb2 = (const float*)d_in[11];
  const float* ln2g = (const float*)d_in[12];
  const float* ln2b = (const float*)d_in[13];
  const float* fc1w = (const float*)d_in[14];
  const float* fc1b = (const float*)d_in[15];
  const float* fc2w = (const float*)d_in[16];
  const float* fc2b = (const float*)d_in[17];
  const float* fc3w = (const float*)d_in[18];
  const float* fc3b = (const float*)d_in[19];
  const float* fc4w = (const float*)d_in[20];
  const float* fc4b = (const float*)d_in[21];
  const float* fc5w = (const float*)d_in[22];
  const float* fc5b = (const float*)d_in[23];

  float* ws = (float*)d_ws;
  float*          h     = ws;
  unsigned int*   Qpack = (unsigned int*)(ws + 131072);
  unsigned int*   KB1   = (unsigned int*)(ws + 262144);
  unsigned int*   KB2   = (unsigned int*)(ws + 393216);
  unsigned short* VhiT  = (unsigned short*)(ws + 524288);
  unsigned short* VloT  = (unsigned short*)(ws + 589824);
  unsigned int*   Hpack = (unsigned int*)(ws + 655360);
  float*          part  = ws + 786432;
  unsigned short* B3h   = (unsigned short*)(ws + 2891776);
  unsigned short* B3l   = (unsigned short*)(ws + 2899968);
  unsigned short* B4h   = (unsigned short*)(ws + 2908160);
  unsigned short* B4l   = (unsigned short*)(ws + 2940928);
  unsigned int*   W1B1  = (unsigned int*)(ws + 2973696);
  unsigned int*   W1B2  = (unsigned int*)(ws + 3039232);
  unsigned short* W2h   = (unsigned short*)(ws + 3104768);
  unsigned short* W2l   = (unsigned short*)(ws + 3137536);

  float* out = (float*)d_out;

  P26 hp;
  hp.x = x; hp.y = y; hp.wqkv = wqkv; hp.bqkv = bqkv; hp.wo = wo; hp.bo = bo;
  hp.ln1g = ln1g; hp.ln1b = ln1b; hp.ffw1 = ffw1; hp.ffb1 = ffb1;
  hp.ffw2 = ffw2; hp.ffb2 = ffb2; hp.ln2g = ln2g; hp.ln2b = ln2b;
  hp.fc1w = fc1w; hp.fc1b = fc1b; hp.fc2w = fc2w; hp.fc2b = fc2b;
  hp.fc3w = fc3w; hp.fc3b = fc3b; hp.fc4w = fc4w; hp.fc4b = fc4b;
  hp.fc5w = fc5w; hp.fc5b = fc5b;
  hp.ws = ws; hp.out = out;

  static int nblk = 0;
  if (nblk == 0) {
    int dev = 0, numCU = 0, perCU = 0;
    (void)hipGetDevice(&dev);
    (void)hipDeviceGetAttribute(&numCU, hipDeviceAttributeMultiprocessorCount, dev);
    (void)hipOccupancyMaxActiveBlocksPerMultiprocessor(&perCU, fused_pipeline, 256, 0);
    if (numCU <= 0) numCU = 256;
    if (perCU <= 0) perCU = 1;
    long cap = (long)perCU * (long)numCU;
    nblk = (int)(cap < 1024 ? cap : 1024);
  }

  void* kargs[] = { (void*)&hp };
  hipError_t err = hipLaunchCooperativeKernel(fused_pipeline, dim3(nblk), dim3(256),
                                              kargs, 0, stream);
  if (err != hipSuccess) {
    // Fallback: proven 9-kernel path.
    (void)hipGetLastError();
    pack_all<<<96, 256, 0, stream>>>(fc3w, fc4w, ffw1, ffw2, x, wqkv, bqkv, h,
                                     Qpack, KB1, KB2, VhiT, VloT,
                                     B3h, B3l, B4h, B4l, W1B1, W1B2, W2h, W2l);
    for (int l = 0; l < 2; l++) {
      attn_mfma<<<dim3(64, NCH), 256, 0, stream>>>(Qpack, KB1, KB2, VhiT, VloT, part);
      attn_comb_ln1<<<256, 128, 0, stream>>>(h, part, wo + (size_t)l * 196,
                                             bo + (size_t)l * 14, ln1g + (size_t)l * 14,
                                             ln1b + (size_t)l * 14, Hpack);
      ffn_mfma<<<dim3(64, NFCH), 256, 0, stream>>>(
          Hpack, W1B1 + (size_t)l * 2048 * 16, W1B2 + (size_t)l * 2048 * 16,
          W2h + (size_t)l * 16 * FF, W2l + (size_t)l * 16 * FF,
          ffb1 + (size_t)l * FF, part);
      if (l == 0) {
        ffn_ln2_qkv<<<256, 128, 0, stream>>>(h, part, ffb2, ln2g, ln2b,
                                             wqkv + 42 * 14, bqkv + 42,
                                             Qpack, KB1, KB2, VhiT, VloT);
      }
    }
    tail_fused<<<512, 256, 0, stream>>>(h, part, ffb2 + 14, ln2g + 14, ln2b + 14,
                                        fc1w, fc1b, fc2w, fc2b, x, y,
                                        B3h, B3l, fc3b, B4h, B4l, fc4b,
                                        fc5w, fc5b, out, out + NN);
  }
}

// Round 3
// 244.945 us; speedup vs baseline: 3.5853x; 2.4814x over previous
//
#include <hip/hip_runtime.h>
#include <math.h>

#define NN 8192
#define DD 14
#define DP 16
#define FF 2048
#define HID 256
#define LN_EPS 1e-5f
#define QSCALE (1.4426950408889634f / 3.7416573867739413f)  // log2(e)/sqrt(14)

typedef short bf16x8 __attribute__((ext_vector_type(8)));
typedef float f32x4 __attribute__((ext_vector_type(4)));

#define LOAD16(dst, srcp) { \
  const float4* _p = (const float4*)(srcp); \
  float4 _a = _p[0], _b = _p[1], _c = _p[2], _d = _p[3]; \
  dst[0]=_a.x; dst[1]=_a.y; dst[2]=_a.z; dst[3]=_a.w; \
  dst[4]=_b.x; dst[5]=_b.y; dst[6]=_b.z; dst[7]=_b.w; \
  dst[8]=_c.x; dst[9]=_c.y; dst[10]=_c.z; dst[11]=_c.w; \
  dst[12]=_d.x; dst[13]=_d.y; dst[14]=_d.z; dst[15]=_d.w; }

#define STORE16(dstp, src) { \
  float4* _p = (float4*)(dstp); \
  _p[0] = make_float4(src[0], src[1], src[2], src[3]); \
  _p[1] = make_float4(src[4], src[5], src[6], src[7]); \
  _p[2] = make_float4(src[8], src[9], src[10], src[11]); \
  _p[3] = make_float4(src[12], src[13], src[14], src[15]); }

static __device__ __forceinline__ float fast_exp2(float x) {
#if __has_builtin(__builtin_amdgcn_exp2f)
  return __builtin_amdgcn_exp2f(x);
#else
  return exp2f(x);
#endif
}

static __device__ __forceinline__ unsigned short bf_hi(float x) {
  return (unsigned short)(__float_as_uint(x) >> 16);
}
static __device__ __forceinline__ float bf_hi_f(float x) {
  return __uint_as_float(__float_as_uint(x) & 0xffff0000u);
}

// ---- repack 8 floats -> bf16 hi/lo fragments ----
static __device__ __forceinline__ void split8(const float* pv, bf16x8* ph, bf16x8* pl) {
  #pragma unroll
  for (int i = 0; i < 8; i++) {
    unsigned int u = __float_as_uint(pv[i]);
    (*ph)[i] = (short)(u >> 16);
    float rr = pv[i] - __uint_as_float(u & 0xffff0000u);
    (*pl)[i] = (short)(__float_as_uint(rr) >> 16);
  }
}

// ---- shared helper: compute qkv for row r from hr[16], store packed operands ----
static __device__ __forceinline__ void qkv_compute_store(
    int r, const float* hr, const float* __restrict__ wqkv,
    const float* __restrict__ bqkv, unsigned int* __restrict__ Qpack,
    unsigned int* __restrict__ KB1, unsigned int* __restrict__ KB2,
    unsigned short* __restrict__ VhiT, unsigned short* __restrict__ VloT) {
  float q[14], k[14], v[14];
  #pragma unroll 6
  for (int c = 0; c < 42; c++) {
    const float* w = wqkv + c * 14;
    float s = bqkv[c];
    #pragma unroll
    for (int d = 0; d < 14; d++) s = fmaf(hr[d], w[d], s);
    if (c < 14)       q[c] = s * QSCALE;
    else if (c < 28)  k[c - 14] = s;
    else              v[c - 28] = s;
  }
  unsigned int qp[16], k1[16], k2[16];
  unsigned short qh[14], ql[14], kh[14], kl[14];
  #pragma unroll
  for (int d = 0; d < 14; d++) {
    qh[d] = bf_hi(q[d]);
    ql[d] = bf_hi(q[d] - bf_hi_f(q[d]));
    kh[d] = bf_hi(k[d]);
    kl[d] = bf_hi(k[d] - bf_hi_f(k[d]));
  }
  #pragma unroll
  for (int i = 0; i < 7; i++) {
    qp[i]     = (unsigned int)qh[2*i] | ((unsigned int)qh[2*i+1] << 16);
    qp[8 + i] = (unsigned int)ql[2*i] | ((unsigned int)ql[2*i+1] << 16);
    k1[i]     = (unsigned int)kh[2*i] | ((unsigned int)kh[2*i+1] << 16);
    k1[8 + i] = k1[i];
    k2[i]     = (unsigned int)kl[2*i] | ((unsigned int)kl[2*i+1] << 16);
    k2[8 + i] = k2[i];
  }
  qp[7] = 0; qp[15] = 0; k1[7] = 0; k1[15] = 0; k2[7] = 0; k2[15] = 0;
  uint4* Qp4 = (uint4*)(Qpack + (size_t)r * 16);
  uint4* K14 = (uint4*)(KB1 + (size_t)r * 16);
  uint4* K24 = (uint4*)(KB2 + (size_t)r * 16);
  #pragma unroll
  for (int i = 0; i < 4; i++) {
    Qp4[i] = make_uint4(qp[4*i], qp[4*i+1], qp[4*i+2], qp[4*i+3]);
    K14[i] = make_uint4(k1[4*i], k1[4*i+1], k1[4*i+2], k1[4*i+3]);
    K24[i] = make_uint4(k2[4*i], k2[4*i+1], k2[4*i+2], k2[4*i+3]);
  }
  #pragma unroll
  for (int d = 0; d < 14; d++) {
    VhiT[(size_t)d * NN + r] = bf_hi(v[d]);
    VloT[(size_t)d * NN + r] = bf_hi(v[d] - bf_hi_f(v[d]));
  }
  VhiT[(size_t)14 * NN + r] = 0x3F80;  // ones column = softmax denom
  VhiT[(size_t)15 * NN + r] = 0;
  VloT[(size_t)14 * NN + r] = 0;
  VloT[(size_t)15 * NN + r] = 0;
}

// ---- shared helper: A-operand pack of 14-dim vector (hi|lo) ----
static __device__ __forceinline__ void store_apack(unsigned int* dst, const float* o) {
  unsigned int qp[16];
  unsigned short hh[14], ll[14];
  #pragma unroll
  for (int d = 0; d < 14; d++) {
    hh[d] = bf_hi(o[d]);
    ll[d] = bf_hi(o[d] - bf_hi_f(o[d]));
  }
  #pragma unroll
  for (int i = 0; i < 7; i++) {
    qp[i]     = (unsigned int)hh[2*i] | ((unsigned int)hh[2*i+1] << 16);
    qp[8 + i] = (unsigned int)ll[2*i] | ((unsigned int)ll[2*i+1] << 16);
  }
  qp[7] = 0; qp[15] = 0;
  uint4* d4 = (uint4*)dst;
  #pragma unroll
  for (int i = 0; i < 4; i++)
    d4[i] = make_uint4(qp[4*i], qp[4*i+1], qp[4*i+2], qp[4*i+3]);
}

// ======================================================================
// K1: weight packs (fc3/fc4/ffn) + layer-0 qkv from x  (unchanged, proven)
// ======================================================================
__global__ void pack_all(const float* __restrict__ w3, const float* __restrict__ w4,
                         const float* __restrict__ ffw1, const float* __restrict__ ffw2,
                         const float* __restrict__ x, const float* __restrict__ wqkv,
                         const float* __restrict__ bqkv, float* __restrict__ h,
                         unsigned int* __restrict__ Qpack,
                         unsigned int* __restrict__ KB1, unsigned int* __restrict__ KB2,
                         unsigned short* __restrict__ VhiT, unsigned short* __restrict__ VloT,
                         unsigned short* __restrict__ B3h, unsigned short* __restrict__ B3l,
                         unsigned short* __restrict__ B4h, unsigned short* __restrict__ B4l,
                         unsigned int* __restrict__ W1B1, unsigned int* __restrict__ W1B2,
                         unsigned short* __restrict__ W2h, unsigned short* __restrict__ W2l) {
  const int blk = blockIdx.x, tid = threadIdx.x;
  if (blk < 32) {
    int t = blk * 256 + tid;
    int lane = t & 63, ks = (t >> 6) & 7, nt = t >> 9;
    int n = nt * 16 + (lane & 15);
    int k0 = ks * 32 + (lane >> 4) * 8;
    unsigned int h4[4], l4[4];
    #pragma unroll
    for (int jj = 0; jj < 4; jj++) {
      unsigned short h2[2], l2[2];
      #pragma unroll
      for (int e = 0; e < 2; e++) {
        float v = w4[(size_t)n * 256 + k0 + jj * 2 + e];
        h2[e] = bf_hi(v);
        l2[e] = bf_hi(v - bf_hi_f(v));
      }
      h4[jj] = (unsigned int)h2[0] | ((unsigned int)h2[1] << 16);
      l4[jj] = (unsigned int)l2[0] | ((unsigned int)l2[1] << 16);
    }
    ((uint4*)B4h)[t] = make_uint4(h4[0], h4[1], h4[2], h4[3]);
    ((uint4*)B4l)[t] = make_uint4(l4[0], l4[1], l4[2], l4[3]);
    if (ks < 2) {
      int fi = (nt * 2 + ks) * 64 + lane;
      #pragma unroll
      for (int jj = 0; jj < 4; jj++) {
        unsigned short h2[2], l2[2];
        #pragma unroll
        for (int e = 0; e < 2; e++) {
          int k = k0 + jj * 2 + e;
          float v = (k < 51) ? w3[(size_t)n * 51 + k] : 0.f;
          h2[e] = bf_hi(v);
          l2[e] = bf_hi(v - bf_hi_f(v));
        }
        h4[jj] = (unsigned int)h2[0] | ((unsigned int)h2[1] << 16);
        l4[jj] = (unsigned int)l2[0] | ((unsigned int)l2[1] << 16);
      }
      ((uint4*)B3h)[fi] = make_uint4(h4[0], h4[1], h4[2], h4[3]);
      ((uint4*)B3l)[fi] = make_uint4(l4[0], l4[1], l4[2], l4[3]);
    }
  } else if (blk < 48) {
    int t = (blk - 32) * 256 + tid;
    int l = t >> 11, j = t & 2047;
    const float* wrow = ffw1 + ((size_t)l * FF + j) * 14;
    unsigned int k1[16], k2[16];
    unsigned short kh[14], kl[14];
    #pragma unroll
    for (int d = 0; d < 14; d++) {
      float v = wrow[d];
      kh[d] = bf_hi(v);
      kl[d] = bf_hi(v - bf_hi_f(v));
    }
    #pragma unroll
    for (int i = 0; i < 7; i++) {
      k1[i] = (unsigned int)kh[2*i] | ((unsigned int)kh[2*i+1] << 16);
      k1[8 + i] = k1[i];
      k2[i] = (unsigned int)kl[2*i] | ((unsigned int)kl[2*i+1] << 16);
      k2[8 + i] = k2[i];
    }
    k1[7] = 0; k1[15] = 0; k2[7] = 0; k2[15] = 0;
    uint4* d1 = (uint4*)(W1B1 + (size_t)t * 16);
    uint4* d2 = (uint4*)(W1B2 + (size_t)t * 16);
    #pragma unroll
    for (int i = 0; i < 4; i++) {
      d1[i] = make_uint4(k1[4*i], k1[4*i+1], k1[4*i+2], k1[4*i+3]);
      d2[i] = make_uint4(k2[4*i], k2[4*i+1], k2[4*i+2], k2[4*i+3]);
    }
  } else if (blk < 64) {
    int t = (blk - 48) * 256 + tid;
    int l = t >> 11, j = t & 2047;
    #pragma unroll
    for (int d = 0; d < 16; d++) {
      float v = (d < 14) ? ffw2[((size_t)l * 14 + d) * FF + j] : 0.f;
      W2h[((size_t)l * 16 + d) * FF + j] = bf_hi(v);
      W2l[((size_t)l * 16 + d) * FF + j] = bf_hi(v - bf_hi_f(v));
    }
  } else {
    int r = (blk - 64) * 256 + tid;
    float hr[16];
    #pragma unroll
    for (int d = 0; d < 14; d++) hr[d] = x[(size_t)r * 14 + d];
    hr[14] = 0.f; hr[15] = 0.f;
    STORE16(h + (size_t)r * DP, hr);
    qkv_compute_store(r, hr, wqkv, bqkv, Qpack, KB1, KB2, VhiT, VloT);
  }
}

// ======================================================================
// K2/K4: flash attention — block owns 32 q rows end-to-end.
// 8 waves; wave w covers keys [w*1024, (w+1)*1024) in 32-key chunks,
// accumulating A-partial (incl. softmax denom via ones-row of V) in regs.
// Block-local LDS reduction replaces the part buffer + combine kernel,
// then out-proj + residual + LN1 + Hpack for the 32 rows.
// ======================================================================
__global__ __launch_bounds__(512, 2) void attn_flash(
    const unsigned int* __restrict__ Qpack, const unsigned int* __restrict__ KB1,
    const unsigned int* __restrict__ KB2, const unsigned short* __restrict__ VhiT,
    const unsigned short* __restrict__ VloT, float* __restrict__ h,
    const float* __restrict__ wo, const float* __restrict__ bo,
    const float* __restrict__ g, const float* __restrict__ b,
    unsigned int* __restrict__ Hpack) {
  __shared__ float Plds[8][32][36];
  __shared__ float sacc[8][32][16];
  const int tid = threadIdx.x;
  const int wave = tid >> 6;
  const int lane = tid & 63;
  const int lo4 = lane & 15;
  const int hi4 = lane >> 4;
  const int qbase = blockIdx.x * 32;

  const bf16x8* Qp = (const bf16x8*)Qpack;
  const bf16x8* B1 = (const bf16x8*)KB1;
  const bf16x8* B2 = (const bf16x8*)KB2;
  const bf16x8* Vh = (const bf16x8*)VhiT;
  const bf16x8* Vl = (const bf16x8*)VloT;

  bf16x8 aQ0 = Qp[(size_t)(qbase + lo4) * 4 + hi4];
  bf16x8 aQ1 = Qp[(size_t)(qbase + 16 + lo4) * 4 + hi4];
  f32x4 acc0 = {0.f, 0.f, 0.f, 0.f};
  f32x4 acc1 = {0.f, 0.f, 0.f, 0.f};
  const f32x4 zero = {0.f, 0.f, 0.f, 0.f};

  const int kstart = wave * 1024;
  for (int c = 0; c < 32; c++) {
    const int kb = kstart + c * 32;
    bf16x8 b1g0 = B1[(size_t)(kb + lo4) * 4 + hi4];
    bf16x8 b2g0 = B2[(size_t)(kb + lo4) * 4 + hi4];
    bf16x8 b1g1 = B1[(size_t)(kb + 16 + lo4) * 4 + hi4];
    bf16x8 b2g1 = B2[(size_t)(kb + 16 + lo4) * 4 + hi4];
    bf16x8 vh = Vh[(size_t)lo4 * 1024 + (kb >> 3) + hi4];
    bf16x8 vl = Vl[(size_t)lo4 * 1024 + (kb >> 3) + hi4];

    f32x4 s00 = __builtin_amdgcn_mfma_f32_16x16x32_bf16(aQ0, b1g0, zero, 0, 0, 0);
    f32x4 s01 = __builtin_amdgcn_mfma_f32_16x16x32_bf16(aQ0, b1g1, zero, 0, 0, 0);
    f32x4 s10 = __builtin_amdgcn_mfma_f32_16x16x32_bf16(aQ1, b1g0, zero, 0, 0, 0);
    f32x4 s11 = __builtin_amdgcn_mfma_f32_16x16x32_bf16(aQ1, b1g1, zero, 0, 0, 0);
    s00 = __builtin_amdgcn_mfma_f32_16x16x32_bf16(aQ0, b2g0, s00, 0, 0, 0);
    s01 = __builtin_amdgcn_mfma_f32_16x16x32_bf16(aQ0, b2g1, s01, 0, 0, 0);
    s10 = __builtin_amdgcn_mfma_f32_16x16x32_bf16(aQ1, b2g0, s10, 0, 0, 0);
    s11 = __builtin_amdgcn_mfma_f32_16x16x32_bf16(aQ1, b2g1, s11, 0, 0, 0);
    #pragma unroll
    for (int reg = 0; reg < 4; reg++) {
      Plds[wave][hi4 * 4 + reg][lo4]           = fast_exp2(s00[reg]);
      Plds[wave][hi4 * 4 + reg][16 + lo4]      = fast_exp2(s01[reg]);
      Plds[wave][16 + hi4 * 4 + reg][lo4]      = fast_exp2(s10[reg]);
      Plds[wave][16 + hi4 * 4 + reg][16 + lo4] = fast_exp2(s11[reg]);
    }
    __asm__ volatile("s_waitcnt lgkmcnt(0)" ::: "memory");
    const float4* p0 = (const float4*)&Plds[wave][lo4][hi4 * 8];
    const float4* p1 = (const float4*)&Plds[wave][16 + lo4][hi4 * 8];
    float4 a0 = p0[0], a1 = p0[1], c0 = p1[0], c1 = p1[1];
    float pv0[8] = {a0.x, a0.y, a0.z, a0.w, a1.x, a1.y, a1.z, a1.w};
    float pv1[8] = {c0.x, c0.y, c0.z, c0.w, c1.x, c1.y, c1.z, c1.w};
    bf16x8 ph0, pl0, ph1, pl1;
    split8(pv0, &ph0, &pl0);
    split8(pv1, &ph1, &pl1);
    acc0 = __builtin_amdgcn_mfma_f32_16x16x32_bf16(ph0, vh, acc0, 0, 0, 0);
    acc1 = __builtin_amdgcn_mfma_f32_16x16x32_bf16(ph1, vh, acc1, 0, 0, 0);
    acc0 = __builtin_amdgcn_mfma_f32_16x16x32_bf16(pl0, vh, acc0, 0, 0, 0);
    acc1 = __builtin_amdgcn_mfma_f32_16x16x32_bf16(pl1, vh, acc1, 0, 0, 0);
    acc0 = __builtin_amdgcn_mfma_f32_16x16x32_bf16(ph0, vl, acc0, 0, 0, 0);
    acc1 = __builtin_amdgcn_mfma_f32_16x16x32_bf16(ph1, vl, acc1, 0, 0, 0);
    __asm__ volatile("s_waitcnt lgkmcnt(0)" ::: "memory");
  }

  // block-local reduction of the 8 per-wave partials
  #pragma unroll
  for (int reg = 0; reg < 4; reg++) {
    sacc[wave][hi4 * 4 + reg][lo4] = acc0[reg];
    sacc[wave][16 + hi4 * 4 + reg][lo4] = acc1[reg];
  }
  __syncthreads();
  {
    int qq = tid >> 4, col = tid & 15;   // 512 threads = 32 rows x 16 cols
    float v = 0.f;
    #pragma unroll
    for (int w = 0; w < 8; w++) v += sacc[w][qq][col];
    sacc[0][qq][col] = v;                // each thread owns its slot
  }
  __syncthreads();

  // out-proj + residual + LN1 + Hpack (one thread per row)
  if (tid < 32) {
    int r = qbase + tid;
    float L = sacc[0][tid][14];
    float inv = 1.f / L;
    float a[14];
    #pragma unroll
    for (int d = 0; d < 14; d++) a[d] = sacc[0][tid][d] * inv;
    float hr[16];
    LOAD16(hr, h + (size_t)r * DP);
    float xx[14];
    #pragma unroll
    for (int i = 0; i < 14; i++) {
      float s = bo[i];
      #pragma unroll
      for (int d = 0; d < 14; d++) s = fmaf(wo[i * 14 + d], a[d], s);
      xx[i] = hr[i] + s;
    }
    float mu = 0.f;
    #pragma unroll
    for (int i = 0; i < 14; i++) mu += xx[i];
    mu *= (1.f / 14.f);
    float var = 0.f;
    #pragma unroll
    for (int i = 0; i < 14; i++) { float tt = xx[i] - mu; var = fmaf(tt, tt, var); }
    var *= (1.f / 14.f);
    float rs = rsqrtf(var + LN_EPS);
    float o[16];
    #pragma unroll
    for (int i = 0; i < 14; i++) o[i] = fmaf((xx[i] - mu) * rs, g[i], b[i]);
    o[14] = 0.f; o[15] = 0.f;
    STORE16(h + (size_t)r * DP, o);
    store_apack(Hpack + (size_t)r * 16, o);
  }
}

// ======================================================================
// K3: flash FFN (layer 0) — block owns 32 rows; wave w covers neurons
// [w*256, (w+1)*256).  Block-local reduce + residual + LN2 + next-layer
// qkv pack, all in one kernel.
// ======================================================================
__global__ __launch_bounds__(512, 2) void ffn_flash_qkv(
    float* __restrict__ h, const unsigned int* __restrict__ Hpack,
    const unsigned int* __restrict__ W1B1, const unsigned int* __restrict__ W1B2,
    const unsigned short* __restrict__ W2h, const unsigned short* __restrict__ W2l,
    const float* __restrict__ b1, const float* __restrict__ b2,
    const float* __restrict__ g, const float* __restrict__ bb,
    const float* __restrict__ wqkv, const float* __restrict__ bqkv,
    unsigned int* __restrict__ Qpack, unsigned int* __restrict__ KB1,
    unsigned int* __restrict__ KB2, unsigned short* __restrict__ VhiT,
    unsigned short* __restrict__ VloT) {
  __shared__ float Plds[8][32][36];
  __shared__ float sacc[8][32][16];
  const int tid = threadIdx.x;
  const int wave = tid >> 6;
  const int lane = tid & 63;
  const int lo4 = lane & 15;
  const int hi4 = lane >> 4;
  const int qbase = blockIdx.x * 32;

  const bf16x8* Hp = (const bf16x8*)Hpack;
  const bf16x8* B1 = (const bf16x8*)W1B1;
  const bf16x8* B2 = (const bf16x8*)W1B2;
  const bf16x8* Vh = (const bf16x8*)W2h;
  const bf16x8* Vl = (const bf16x8*)W2l;

  bf16x8 aH0 = Hp[(size_t)(qbase + lo4) * 4 + hi4];
  bf16x8 aH1 = Hp[(size_t)(qbase + 16 + lo4) * 4 + hi4];
  f32x4 acc0 = {0.f, 0.f, 0.f, 0.f};
  f32x4 acc1 = {0.f, 0.f, 0.f, 0.f};
  const f32x4 zero = {0.f, 0.f, 0.f, 0.f};

  const int jstart = wave * 256;
  for (int c = 0; c < 8; c++) {
    const int jb = jstart + c * 32;
    bf16x8 b1g0 = B1[(size_t)(jb + lo4) * 4 + hi4];
    bf16x8 b2g0 = B2[(size_t)(jb + lo4) * 4 + hi4];
    bf16x8 b1g1 = B1[(size_t)(jb + 16 + lo4) * 4 + hi4];
    bf16x8 b2g1 = B2[(size_t)(jb + 16 + lo4) * 4 + hi4];
    bf16x8 vh = Vh[(size_t)lo4 * 256 + (jb >> 3) + hi4];
    bf16x8 vl = Vl[(size_t)lo4 * 256 + (jb >> 3) + hi4];
    float bb0 = b1[jb + lo4];
    float bb1 = b1[jb + 16 + lo4];

    f32x4 s00 = __builtin_amdgcn_mfma_f32_16x16x32_bf16(aH0, b1g0, zero, 0, 0, 0);
    f32x4 s01 = __builtin_amdgcn_mfma_f32_16x16x32_bf16(aH0, b1g1, zero, 0, 0, 0);
    f32x4 s10 = __builtin_amdgcn_mfma_f32_16x16x32_bf16(aH1, b1g0, zero, 0, 0, 0);
    f32x4 s11 = __builtin_amdgcn_mfma_f32_16x16x32_bf16(aH1, b1g1, zero, 0, 0, 0);
    s00 = __builtin_amdgcn_mfma_f32_16x16x32_bf16(aH0, b2g0, s00, 0, 0, 0);
    s01 = __builtin_amdgcn_mfma_f32_16x16x32_bf16(aH0, b2g1, s01, 0, 0, 0);
    s10 = __builtin_amdgcn_mfma_f32_16x16x32_bf16(aH1, b2g0, s10, 0, 0, 0);
    s11 = __builtin_amdgcn_mfma_f32_16x16x32_bf16(aH1, b2g1, s11, 0, 0, 0);
    #pragma unroll
    for (int reg = 0; reg < 4; reg++) {
      Plds[wave][hi4 * 4 + reg][lo4]           = fmaxf(s00[reg] + bb0, 0.f);
      Plds[wave][hi4 * 4 + reg][16 + lo4]      = fmaxf(s01[reg] + bb1, 0.f);
      Plds[wave][16 + hi4 * 4 + reg][lo4]      = fmaxf(s10[reg] + bb0, 0.f);
      Plds[wave][16 + hi4 * 4 + reg][16 + lo4] = fmaxf(s11[reg] + bb1, 0.f);
    }
    __asm__ volatile("s_waitcnt lgkmcnt(0)" ::: "memory");
    const float4* p0 = (const float4*)&Plds[wave][lo4][hi4 * 8];
    const float4* p1 = (const float4*)&Plds[wave][16 + lo4][hi4 * 8];
    float4 a0 = p0[0], a1 = p0[1], c0 = p1[0], c1 = p1[1];
    float pv0[8] = {a0.x, a0.y, a0.z, a0.w, a1.x, a1.y, a1.z, a1.w};
    float pv1[8] = {c0.x, c0.y, c0.z, c0.w, c1.x, c1.y, c1.z, c1.w};
    bf16x8 th0, tl0, th1, tl1;
    split8(pv0, &th0, &tl0);
    split8(pv1, &th1, &tl1);
    acc0 = __builtin_amdgcn_mfma_f32_16x16x32_bf16(th0, vh, acc0, 0, 0, 0);
    acc1 = __builtin_amdgcn_mfma_f32_16x16x32_bf16(th1, vh, acc1, 0, 0, 0);
    acc0 = __builtin_amdgcn_mfma_f32_16x16x32_bf16(tl0, vh, acc0, 0, 0, 0);
    acc1 = __builtin_amdgcn_mfma_f32_16x16x32_bf16(tl1, vh, acc1, 0, 0, 0);
    acc0 = __builtin_amdgcn_mfma_f32_16x16x32_bf16(th0, vl, acc0, 0, 0, 0);
    acc1 = __builtin_amdgcn_mfma_f32_16x16x32_bf16(th1, vl, acc1, 0, 0, 0);
    __asm__ volatile("s_waitcnt lgkmcnt(0)" ::: "memory");
  }

  #pragma unroll
  for (int reg = 0; reg < 4; reg++) {
    sacc[wave][hi4 * 4 + reg][lo4] = acc0[reg];
    sacc[wave][16 + hi4 * 4 + reg][lo4] = acc1[reg];
  }
  __syncthreads();
  {
    int qq = tid >> 4, col = tid & 15;
    float v = 0.f;
    #pragma unroll
    for (int w = 0; w < 8; w++) v += sacc[w][qq][col];
    sacc[0][qq][col] = v;
  }
  __syncthreads();

  if (tid < 32) {
    int r = qbase + tid;
    float hr[16];
    LOAD16(hr, h + (size_t)r * DP);
    float xx[14];
    #pragma unroll
    for (int i = 0; i < 14; i++) xx[i] = hr[i] + sacc[0][tid][i] + b2[i];
    float mu = 0.f;
    #pragma unroll
    for (int i = 0; i < 14; i++) mu += xx[i];
    mu *= (1.f / 14.f);
    float var = 0.f;
    #pragma unroll
    for (int i = 0; i < 14; i++) { float tt = xx[i] - mu; var = fmaf(tt, tt, var); }
    var *= (1.f / 14.f);
    float rs = rsqrtf(var + LN_EPS);
    float o[16];
    #pragma unroll
    for (int i = 0; i < 14; i++) o[i] = fmaf((xx[i] - mu) * rs, g[i], bb[i]);
    o[14] = 0.f; o[15] = 0.f;
    STORE16(h + (size_t)r * DP, o);
    qkv_compute_store(r, o, wqkv, bqkv, Qpack, KB1, KB2, VhiT, VloT);
  }
}

// ======================================================================
// K5: flash FFN (layer 1) + LN2 + size head + regression tail.
// 512 blocks x 256 thr; block owns 16 rows.  Wave w covers neurons
// [w*512, (w+1)*512) in 16 chunks; then the proven tail_fused body.
// ======================================================================
__global__ __launch_bounds__(256, 4) void ffn_tail(
    const float* __restrict__ h, const unsigned int* __restrict__ Hpack,
    const unsigned int* __restrict__ W1B1, const unsigned int* __restrict__ W1B2,
    const unsigned short* __restrict__ W2h, const unsigned short* __restrict__ W2l,
    const float* __restrict__ b1,
    const float* __restrict__ b2, const float* __restrict__ g, const float* __restrict__ b,
    const float* __restrict__ fc1w, const float* __restrict__ fc1b,
    const float* __restrict__ fc2w, const float* __restrict__ fc2b,
    const float* __restrict__ x, const float* __restrict__ y,
    const unsigned short* __restrict__ B3h, const unsigned short* __restrict__ B3l,
    const float* __restrict__ b3,
    const unsigned short* __restrict__ B4h, const unsigned short* __restrict__ B4l,
    const float* __restrict__ b4,
    const float* __restrict__ w5, const float* __restrict__ b5,
    float* __restrict__ out, float* __restrict__ outr) {
  __shared__ float PldsT[4][16][36];
  __shared__ float saccT[4][16][16];
  __shared__ alignas(16) unsigned short Ah[16][72], Al[16][72];
  __shared__ alignas(16) unsigned short R1h[16][264], R1l[16][264];
  __shared__ float sred[4][16][16];
  __shared__ float szf[16];
  const int tid = threadIdx.x;
  const int wave = tid >> 6;
  const int lane = tid & 63;
  const int lo4 = lane & 15;
  const int hi4 = lane >> 4;
  const int rbase = blockIdx.x * 16;
  const f32x4 zero = {0.f, 0.f, 0.f, 0.f};

  // ---- FFN layer 1 for this block's 16 rows ----
  {
    const bf16x8* Hp = (const bf16x8*)Hpack;
    const bf16x8* B1 = (const bf16x8*)W1B1;
    const bf16x8* B2 = (const bf16x8*)W1B2;
    const bf16x8* Vh = (const bf16x8*)W2h;
    const bf16x8* Vl = (const bf16x8*)W2l;
    bf16x8 aH0 = Hp[(size_t)(rbase + lo4) * 4 + hi4];
    f32x4 acc0 = zero;
    const int jstart = wave * 512;
    for (int c = 0; c < 16; c++) {
      const int jb = jstart + c * 32;
      bf16x8 b1g0 = B1[(size_t)(jb + lo4) * 4 + hi4];
      bf16x8 b2g0 = B2[(size_t)(jb + lo4) * 4 + hi4];
      bf16x8 b1g1 = B1[(size_t)(jb + 16 + lo4) * 4 + hi4];
      bf16x8 b2g1 = B2[(size_t)(jb + 16 + lo4) * 4 + hi4];
      bf16x8 vh = Vh[(size_t)lo4 * 256 + (jb >> 3) + hi4];
      bf16x8 vl = Vl[(size_t)lo4 * 256 + (jb >> 3) + hi4];
      float bb0 = b1[jb + lo4];
      float bb1 = b1[jb + 16 + lo4];

      f32x4 s00 = __builtin_amdgcn_mfma_f32_16x16x32_bf16(aH0, b1g0, zero, 0, 0, 0);
      f32x4 s01 = __builtin_amdgcn_mfma_f32_16x16x32_bf16(aH0, b1g1, zero, 0, 0, 0);
      s00 = __builtin_amdgcn_mfma_f32_16x16x32_bf16(aH0, b2g0, s00, 0, 0, 0);
      s01 = __builtin_amdgcn_mfma_f32_16x16x32_bf16(aH0, b2g1, s01, 0, 0, 0);
      #pragma unroll
      for (int reg = 0; reg < 4; reg++) {
        PldsT[wave][hi4 * 4 + reg][lo4]      = fmaxf(s00[reg] + bb0, 0.f);
        PldsT[wave][hi4 * 4 + reg][16 + lo4] = fmaxf(s01[reg] + bb1, 0.f);
      }
      __asm__ volatile("s_waitcnt lgkmcnt(0)" ::: "memory");
      const float4* p0 = (const float4*)&PldsT[wave][lo4][hi4 * 8];
      float4 a0 = p0[0], a1 = p0[1];
      float pv0[8] = {a0.x, a0.y, a0.z, a0.w, a1.x, a1.y, a1.z, a1.w};
      bf16x8 th0, tl0;
      split8(pv0, &th0, &tl0);
      acc0 = __builtin_amdgcn_mfma_f32_16x16x32_bf16(th0, vh, acc0, 0, 0, 0);
      acc0 = __builtin_amdgcn_mfma_f32_16x16x32_bf16(tl0, vh, acc0, 0, 0, 0);
      acc0 = __builtin_amdgcn_mfma_f32_16x16x32_bf16(th0, vl, acc0, 0, 0, 0);
      __asm__ volatile("s_waitcnt lgkmcnt(0)" ::: "memory");
    }
    #pragma unroll
    for (int reg = 0; reg < 4; reg++)
      saccT[wave][hi4 * 4 + reg][lo4] = acc0[reg];
  }
  __syncthreads();
  {
    int qq = tid >> 4, col = tid & 15;   // 256 threads = 16 rows x 16 cols
    float v = saccT[0][qq][col] + saccT[1][qq][col] + saccT[2][qq][col] + saccT[3][qq][col];
    saccT[0][qq][col] = v;
  }
  __syncthreads();

  // ---- LN2 + size head for the 16 rows ----
  if (tid < 16) {
    int r = rbase + tid;
    float hr[16];
    LOAD16(hr, h + (size_t)r * DP);
    float xx[14];
    #pragma unroll
    for (int i = 0; i < 14; i++) xx[i] = hr[i] + saccT[0][tid][i] + b2[i];
    float mu = 0.f;
    #pragma unroll
    for (int i = 0; i < 14; i++) mu += xx[i];
    mu *= (1.f / 14.f);
    float var = 0.f;
    #pragma unroll
    for (int i = 0; i < 14; i++) { float tt = xx[i] - mu; var = fmaf(tt, tt, var); }
    var *= (1.f / 14.f);
    float rs = rsqrtf(var + LN_EPS);
    float o[14];
    #pragma unroll
    for (int i = 0; i < 14; i++) o[i] = fmaf((xx[i] - mu) * rs, g[i], b[i]);
    float s = fc2b[0];
    #pragma unroll
    for (int i = 0; i < 14; i++) {
      float tt = fc1b[i];
      #pragma unroll
      for (int d = 0; d < 14; d++) tt = fmaf(fc1w[i * 14 + d], o[d], tt);
      s = fmaf(tt, fc2w[i], s);
    }
    out[r] = s;
    int si = (int)s;  // trunc toward zero, matches astype(int32)
    szf[tid] = (float)si;
  }
  __syncthreads();

  // ---- regression head (verbatim proven tail) ----
  for (int idx = tid; idx < 16 * 64; idx += 256) {
    int m = idx >> 6, k = idx & 63;
    int r = rbase + m;
    float v = 0.f;
    if (k == 0)       v = szf[m];
    else if (k < 15)  v = x[(size_t)r * 14 + (k - 1)];
    else if (k < 51)  v = y[(size_t)r * 36 + (k - 15)];
    Ah[m][k] = bf_hi(v);
    Al[m][k] = bf_hi(v - bf_hi_f(v));
  }
  __syncthreads();

  f32x4 acc[4];
  #pragma unroll
  for (int nt = 0; nt < 4; nt++) acc[nt] = zero;
  #pragma unroll
  for (int ks = 0; ks < 2; ks++) {
    bf16x8 ah = *(const bf16x8*)&Ah[lo4][ks * 32 + hi4 * 8];
    bf16x8 al = *(const bf16x8*)&Al[lo4][ks * 32 + hi4 * 8];
    #pragma unroll
    for (int nt = 0; nt < 4; nt++) {
      int fi = ((wave * 4 + nt) * 2 + ks) * 64 + lane;
      bf16x8 bh = ((const bf16x8*)B3h)[fi];
      bf16x8 bl = ((const bf16x8*)B3l)[fi];
      acc[nt] = __builtin_amdgcn_mfma_f32_16x16x32_bf16(ah, bh, acc[nt], 0, 0, 0);
      acc[nt] = __builtin_amdgcn_mfma_f32_16x16x32_bf16(al, bh, acc[nt], 0, 0, 0);
      acc[nt] = __builtin_amdgcn_mfma_f32_16x16x32_bf16(ah, bl, acc[nt], 0, 0, 0);
    }
  }
  #pragma unroll
  for (int nt = 0; nt < 4; nt++) {
    int n = (wave * 4 + nt) * 16 + lo4;
    float bbv = b3[n];
    #pragma unroll
    for (int reg = 0; reg < 4; reg++) {
      int m = hi4 * 4 + reg;
      float v = fmaxf(acc[nt][reg] + bbv, 0.f);
      R1h[m][n] = bf_hi(v);
      R1l[m][n] = bf_hi(v - bf_hi_f(v));
    }
  }
  __syncthreads();

  #pragma unroll
  for (int nt = 0; nt < 4; nt++) acc[nt] = zero;
  #pragma unroll
  for (int ks = 0; ks < 8; ks++) {
    bf16x8 ah = *(const bf16x8*)&R1h[lo4][ks * 32 + hi4 * 8];
    bf16x8 al = *(const bf16x8*)&R1l[lo4][ks * 32 + hi4 * 8];
    #pragma unroll
    for (int nt = 0; nt < 4; nt++) {
      int fi = ((wave * 4 + nt) * 8 + ks) * 64 + lane;
      bf16x8 bh = ((const bf16x8*)B4h)[fi];
      bf16x8 bl = ((const bf16x8*)B4l)[fi];
      acc[nt] = __builtin_amdgcn_mfma_f32_16x16x32_bf16(ah, bh, acc[nt], 0, 0, 0);
      acc[nt] = __builtin_amdgcn_mfma_f32_16x16x32_bf16(al, bh, acc[nt], 0, 0, 0);
      acc[nt] = __builtin_amdgcn_mfma_f32_16x16x32_bf16(ah, bl, acc[nt], 0, 0, 0);
    }
  }
  float s4[4] = {0.f, 0.f, 0.f, 0.f};
  #pragma unroll
  for (int nt = 0; nt < 4; nt++) {
    int n = (wave * 4 + nt) * 16 + lo4;
    float bbv = b4[n], ww = w5[n];
    #pragma unroll
    for (int reg = 0; reg < 4; reg++)
      s4[reg] = fmaf(fmaxf(acc[nt][reg] + bbv, 0.f), ww, s4[reg]);
  }
  #pragma unroll
  for (int reg = 0; reg < 4; reg++) sred[wave][hi4 * 4 + reg][lo4] = s4[reg];
  __syncthreads();

  if (tid < 16) {
    float t = b5[0];
    #pragma unroll
    for (int w = 0; w < 4; w++) {
      const float4* p = (const float4*)&sred[w][tid][0];
      float4 a0 = p[0], a1 = p[1], a2 = p[2], a3 = p[3];
      t += ((a0.x + a0.y) + (a0.z + a0.w)) + ((a1.x + a1.y) + (a1.z + a1.w)) +
           ((a2.x + a2.y) + (a2.z + a2.w)) + ((a3.x + a3.y) + (a3.z + a3.w));
    }
    float sz = szf[tid];
    outr[rbase + tid] = (sz != 0.f) ? t : 0.f;
  }
}

extern "C" void kernel_launch(void* const* d_in, const int* in_sizes, int n_in,
                              void* d_out, int out_size, void* d_ws, size_t ws_size,
                              hipStream_t stream) {
  const float* x    = (const float*)d_in[0];
  const float* y    = (const float*)d_in[1];
  const float* wqkv = (const float*)d_in[2];
  const float* bqkv = (const float*)d_in[3];
  const float* wo   = (const float*)d_in[4];
  const float* bo   = (const float*)d_in[5];
  const float* ln1g = (const float*)d_in[6];
  const float* ln1b = (const float*)d_in[7];
  const float* ffw1 = (const float*)d_in[8];
  const float* ffb1 = (const float*)d_in[9];
  const float* ffw2 = (const float*)d_in[10];
  const float* ffb2 = (const float*)d_in[11];
  const float* ln2g = (const float*)d_in[12];
  const float* ln2b = (const float*)d_in[13];
  const float* fc1w = (const float*)d_in[14];
  const float* fc1b = (const float*)d_in[15];
  const float* fc2w = (const float*)d_in[16];
  const float* fc2b = (const float*)d_in[17];
  const float* fc3w = (const float*)d_in[18];
  const float* fc3b = (const float*)d_in[19];
  const float* fc4w = (const float*)d_in[20];
  const float* fc4b = (const float*)d_in[21];
  const float* fc5w = (const float*)d_in[22];
  const float* fc5b = (const float*)d_in[23];

  float* ws = (float*)d_ws;
  float*          h     = ws;                               // 131072
  unsigned int*   Qpack = (unsigned int*)(ws + 131072);     // 131072
  unsigned int*   KB1   = (unsigned int*)(ws + 262144);     // 131072
  unsigned int*   KB2   = (unsigned int*)(ws + 393216);     // 131072
  unsigned short* VhiT  = (unsigned short*)(ws + 524288);   // 65536 f
  unsigned short* VloT  = (unsigned short*)(ws + 589824);   // 65536 f
  unsigned int*   Hpack = (unsigned int*)(ws + 655360);     // 131072
  unsigned short* B3h   = (unsigned short*)(ws + 2891776);  // 8192 f
  unsigned short* B3l   = (unsigned short*)(ws + 2899968);
  unsigned short* B4h   = (unsigned short*)(ws + 2908160);  // 32768 f
  unsigned short* B4l   = (unsigned short*)(ws + 2940928);
  unsigned int*   W1B1  = (unsigned int*)(ws + 2973696);    // 65536
  unsigned int*   W1B2  = (unsigned int*)(ws + 3039232);
  unsigned short* W2h   = (unsigned short*)(ws + 3104768);  // 32768 f
  unsigned short* W2l   = (unsigned short*)(ws + 3137536);

  float* out = (float*)d_out;

  pack_all<<<96, 256, 0, stream>>>(fc3w, fc4w, ffw1, ffw2, x, wqkv, bqkv, h,
                                   Qpack, KB1, KB2, VhiT, VloT,
                                   B3h, B3l, B4h, B4l, W1B1, W1B2, W2h, W2l);

  // layer 0
  attn_flash<<<256, 512, 0, stream>>>(Qpack, KB1, KB2, VhiT, VloT, h,
                                      wo, bo, ln1g, ln1b, Hpack);
  ffn_flash_qkv<<<256, 512, 0, stream>>>(h, Hpack, W1B1, W1B2, W2h, W2l,
                                         ffb1, ffb2, ln2g, ln2b,
                                         wqkv + 42 * 14, bqkv + 42,
                                         Qpack, KB1, KB2, VhiT, VloT);
  // layer 1
  attn_flash<<<256, 512, 0, stream>>>(Qpack, KB1, KB2, VhiT, VloT, h,
                                      wo + 196, bo + 14, ln1g + 14, ln1b + 14, Hpack);
  ffn_tail<<<512, 256, 0, stream>>>(h, Hpack,
                                    W1B1 + (size_t)2048 * 16, W1B2 + (size_t)2048 * 16,
                                    W2h + (size_t)16 * FF, W2l + (size_t)16 * FF,
                                    ffb1 + FF, ffb2 + 14, ln2g + 14, ln2b + 14,
                                    fc1w, fc1b, fc2w, fc2b, x, y,
                                    B3h, B3l, fc3b, B4h, B4l, fc4b,
                                    fc5w, fc5b, out, out + NN);
}

// Round 4
// 230.921 us; speedup vs baseline: 3.8030x; 1.0607x over previous
//
#include <hip/hip_runtime.h>
#include <math.h>

#define NN 8192
#define DD 14
#define DP 16
#define FF 2048
#define HID 256
#define LN_EPS 1e-5f
#define QSCALE (1.4426950408889634f / 3.7416573867739413f)  // log2(e)/sqrt(14)

typedef short bf16x8 __attribute__((ext_vector_type(8)));
typedef float f32x4 __attribute__((ext_vector_type(4)));

#define LOAD16(dst, srcp) { \
  const float4* _p = (const float4*)(srcp); \
  float4 _a = _p[0], _b = _p[1], _c = _p[2], _d = _p[3]; \
  dst[0]=_a.x; dst[1]=_a.y; dst[2]=_a.z; dst[3]=_a.w; \
  dst[4]=_b.x; dst[5]=_b.y; dst[6]=_b.z; dst[7]=_b.w; \
  dst[8]=_c.x; dst[9]=_c.y; dst[10]=_c.z; dst[11]=_c.w; \
  dst[12]=_d.x; dst[13]=_d.y; dst[14]=_d.z; dst[15]=_d.w; }

#define STORE16(dstp, src) { \
  float4* _p = (float4*)(dstp); \
  _p[0] = make_float4(src[0], src[1], src[2], src[3]); \
  _p[1] = make_float4(src[4], src[5], src[6], src[7]); \
  _p[2] = make_float4(src[8], src[9], src[10], src[11]); \
  _p[3] = make_float4(src[12], src[13], src[14], src[15]); }

static __device__ __forceinline__ float fast_exp2(float x) {
#if __has_builtin(__builtin_amdgcn_exp2f)
  return __builtin_amdgcn_exp2f(x);
#else
  return exp2f(x);
#endif
}

static __device__ __forceinline__ unsigned short bf_hi(float x) {
  return (unsigned short)(__float_as_uint(x) >> 16);
}
static __device__ __forceinline__ float bf_hi_f(float x) {
  return __uint_as_float(__float_as_uint(x) & 0xffff0000u);
}

// ---- repack 8 floats -> bf16 hi/lo fragments ----
static __device__ __forceinline__ void split8(const float* pv, bf16x8* ph, bf16x8* pl) {
  #pragma unroll
  for (int i = 0; i < 8; i++) {
    unsigned int u = __float_as_uint(pv[i]);
    (*ph)[i] = (short)(u >> 16);
    float rr = pv[i] - __uint_as_float(u & 0xffff0000u);
    (*pl)[i] = (short)(__float_as_uint(rr) >> 16);
  }
}

// ---- shared helper: compute qkv for row r from hr[16], store packed operands ----
static __device__ __forceinline__ void qkv_compute_store(
    int r, const float* hr, const float* __restrict__ wqkv,
    const float* __restrict__ bqkv, unsigned int* __restrict__ Qpack,
    unsigned int* __restrict__ KB1, unsigned int* __restrict__ KB2,
    unsigned short* __restrict__ VhiT, unsigned short* __restrict__ VloT) {
  float q[14], k[14], v[14];
  #pragma unroll 6
  for (int c = 0; c < 42; c++) {
    const float* w = wqkv + c * 14;
    float s = bqkv[c];
    #pragma unroll
    for (int d = 0; d < 14; d++) s = fmaf(hr[d], w[d], s);
    if (c < 14)       q[c] = s * QSCALE;
    else if (c < 28)  k[c - 14] = s;
    else              v[c - 28] = s;
  }
  unsigned int qp[16], k1[16], k2[16];
  unsigned short qh[14], ql[14], kh[14], kl[14];
  #pragma unroll
  for (int d = 0; d < 14; d++) {
    qh[d] = bf_hi(q[d]);
    ql[d] = bf_hi(q[d] - bf_hi_f(q[d]));
    kh[d] = bf_hi(k[d]);
    kl[d] = bf_hi(k[d] - bf_hi_f(k[d]));
  }
  #pragma unroll
  for (int i = 0; i < 7; i++) {
    qp[i]     = (unsigned int)qh[2*i] | ((unsigned int)qh[2*i+1] << 16);
    qp[8 + i] = (unsigned int)ql[2*i] | ((unsigned int)ql[2*i+1] << 16);
    k1[i]     = (unsigned int)kh[2*i] | ((unsigned int)kh[2*i+1] << 16);
    k1[8 + i] = k1[i];
    k2[i]     = (unsigned int)kl[2*i] | ((unsigned int)kl[2*i+1] << 16);
    k2[8 + i] = k2[i];
  }
  qp[7] = 0; qp[15] = 0; k1[7] = 0; k1[15] = 0; k2[7] = 0; k2[15] = 0;
  uint4* Qp4 = (uint4*)(Qpack + (size_t)r * 16);
  uint4* K14 = (uint4*)(KB1 + (size_t)r * 16);
  uint4* K24 = (uint4*)(KB2 + (size_t)r * 16);
  #pragma unroll
  for (int i = 0; i < 4; i++) {
    Qp4[i] = make_uint4(qp[4*i], qp[4*i+1], qp[4*i+2], qp[4*i+3]);
    K14[i] = make_uint4(k1[4*i], k1[4*i+1], k1[4*i+2], k1[4*i+3]);
    K24[i] = make_uint4(k2[4*i], k2[4*i+1], k2[4*i+2], k2[4*i+3]);
  }
  #pragma unroll
  for (int d = 0; d < 14; d++) {
    VhiT[(size_t)d * NN + r] = bf_hi(v[d]);
    VloT[(size_t)d * NN + r] = bf_hi(v[d] - bf_hi_f(v[d]));
  }
  VhiT[(size_t)14 * NN + r] = 0x3F80;  // ones column = softmax denom
  VhiT[(size_t)15 * NN + r] = 0;
  VloT[(size_t)14 * NN + r] = 0;
  VloT[(size_t)15 * NN + r] = 0;
}

// ---- shared helper: A-operand pack of 14-dim vector (hi|lo) ----
static __device__ __forceinline__ void store_apack(unsigned int* dst, const float* o) {
  unsigned int qp[16];
  unsigned short hh[14], ll[14];
  #pragma unroll
  for (int d = 0; d < 14; d++) {
    hh[d] = bf_hi(o[d]);
    ll[d] = bf_hi(o[d] - bf_hi_f(o[d]));
  }
  #pragma unroll
  for (int i = 0; i < 7; i++) {
    qp[i]     = (unsigned int)hh[2*i] | ((unsigned int)hh[2*i+1] << 16);
    qp[8 + i] = (unsigned int)ll[2*i] | ((unsigned int)ll[2*i+1] << 16);
  }
  qp[7] = 0; qp[15] = 0;
  uint4* d4 = (uint4*)dst;
  #pragma unroll
  for (int i = 0; i < 4; i++)
    d4[i] = make_uint4(qp[4*i], qp[4*i+1], qp[4*i+2], qp[4*i+3]);
}

// ---- combine + LN (out-proj variant) ----
static __device__ __forceinline__ void combine_ln1(
    const float* srow, const float* hr, const float* __restrict__ wo,
    const float* __restrict__ bo, const float* __restrict__ g,
    const float* __restrict__ b, float* o) {
  float L = srow[14];
  float inv = 1.f / L;
  float a[14];
  #pragma unroll
  for (int d = 0; d < 14; d++) a[d] = srow[d] * inv;
  float xx[14];
  #pragma unroll
  for (int i = 0; i < 14; i++) {
    float s = bo[i];
    #pragma unroll
    for (int d = 0; d < 14; d++) s = fmaf(wo[i * 14 + d], a[d], s);
    xx[i] = hr[i] + s;
  }
  float mu = 0.f;
  #pragma unroll
  for (int i = 0; i < 14; i++) mu += xx[i];
  mu *= (1.f / 14.f);
  float var = 0.f;
  #pragma unroll
  for (int i = 0; i < 14; i++) { float tt = xx[i] - mu; var = fmaf(tt, tt, var); }
  var *= (1.f / 14.f);
  float rs = rsqrtf(var + LN_EPS);
  #pragma unroll
  for (int i = 0; i < 14; i++) o[i] = fmaf((xx[i] - mu) * rs, g[i], b[i]);
  o[14] = 0.f; o[15] = 0.f;
}

// ======================================================================
// K1: weight packs (fc3/fc4/ffn) + layer-0 qkv from x  (unchanged, proven)
// ======================================================================
__global__ void pack_all(const float* __restrict__ w3, const float* __restrict__ w4,
                         const float* __restrict__ ffw1, const float* __restrict__ ffw2,
                         const float* __restrict__ x, const float* __restrict__ wqkv,
                         const float* __restrict__ bqkv, float* __restrict__ h,
                         unsigned int* __restrict__ Qpack,
                         unsigned int* __restrict__ KB1, unsigned int* __restrict__ KB2,
                         unsigned short* __restrict__ VhiT, unsigned short* __restrict__ VloT,
                         unsigned short* __restrict__ B3h, unsigned short* __restrict__ B3l,
                         unsigned short* __restrict__ B4h, unsigned short* __restrict__ B4l,
                         unsigned int* __restrict__ W1B1, unsigned int* __restrict__ W1B2,
                         unsigned short* __restrict__ W2h, unsigned short* __restrict__ W2l) {
  const int blk = blockIdx.x, tid = threadIdx.x;
  if (blk < 32) {
    int t = blk * 256 + tid;
    int lane = t & 63, ks = (t >> 6) & 7, nt = t >> 9;
    int n = nt * 16 + (lane & 15);
    int k0 = ks * 32 + (lane >> 4) * 8;
    unsigned int h4[4], l4[4];
    #pragma unroll
    for (int jj = 0; jj < 4; jj++) {
      unsigned short h2[2], l2[2];
      #pragma unroll
      for (int e = 0; e < 2; e++) {
        float v = w4[(size_t)n * 256 + k0 + jj * 2 + e];
        h2[e] = bf_hi(v);
        l2[e] = bf_hi(v - bf_hi_f(v));
      }
      h4[jj] = (unsigned int)h2[0] | ((unsigned int)h2[1] << 16);
      l4[jj] = (unsigned int)l2[0] | ((unsigned int)l2[1] << 16);
    }
    ((uint4*)B4h)[t] = make_uint4(h4[0], h4[1], h4[2], h4[3]);
    ((uint4*)B4l)[t] = make_uint4(l4[0], l4[1], l4[2], l4[3]);
    if (ks < 2) {
      int fi = (nt * 2 + ks) * 64 + lane;
      #pragma unroll
      for (int jj = 0; jj < 4; jj++) {
        unsigned short h2[2], l2[2];
        #pragma unroll
        for (int e = 0; e < 2; e++) {
          int k = k0 + jj * 2 + e;
          float v = (k < 51) ? w3[(size_t)n * 51 + k] : 0.f;
          h2[e] = bf_hi(v);
          l2[e] = bf_hi(v - bf_hi_f(v));
        }
        h4[jj] = (unsigned int)h2[0] | ((unsigned int)h2[1] << 16);
        l4[jj] = (unsigned int)l2[0] | ((unsigned int)l2[1] << 16);
      }
      ((uint4*)B3h)[fi] = make_uint4(h4[0], h4[1], h4[2], h4[3]);
      ((uint4*)B3l)[fi] = make_uint4(l4[0], l4[1], l4[2], l4[3]);
    }
  } else if (blk < 48) {
    int t = (blk - 32) * 256 + tid;
    int l = t >> 11, j = t & 2047;
    const float* wrow = ffw1 + ((size_t)l * FF + j) * 14;
    unsigned int k1[16], k2[16];
    unsigned short kh[14], kl[14];
    #pragma unroll
    for (int d = 0; d < 14; d++) {
      float v = wrow[d];
      kh[d] = bf_hi(v);
      kl[d] = bf_hi(v - bf_hi_f(v));
    }
    #pragma unroll
    for (int i = 0; i < 7; i++) {
      k1[i] = (unsigned int)kh[2*i] | ((unsigned int)kh[2*i+1] << 16);
      k1[8 + i] = k1[i];
      k2[i] = (unsigned int)kl[2*i] | ((unsigned int)kl[2*i+1] << 16);
      k2[8 + i] = k2[i];
    }
    k1[7] = 0; k1[15] = 0; k2[7] = 0; k2[15] = 0;
    uint4* d1 = (uint4*)(W1B1 + (size_t)t * 16);
    uint4* d2 = (uint4*)(W1B2 + (size_t)t * 16);
    #pragma unroll
    for (int i = 0; i < 4; i++) {
      d1[i] = make_uint4(k1[4*i], k1[4*i+1], k1[4*i+2], k1[4*i+3]);
      d2[i] = make_uint4(k2[4*i], k2[4*i+1], k2[4*i+2], k2[4*i+3]);
    }
  } else if (blk < 64) {
    int t = (blk - 48) * 256 + tid;
    int l = t >> 11, j = t & 2047;
    #pragma unroll
    for (int d = 0; d < 16; d++) {
      float v = (d < 14) ? ffw2[((size_t)l * 14 + d) * FF + j] : 0.f;
      W2h[((size_t)l * 16 + d) * FF + j] = bf_hi(v);
      W2l[((size_t)l * 16 + d) * FF + j] = bf_hi(v - bf_hi_f(v));
    }
  } else {
    int r = (blk - 64) * 256 + tid;
    float hr[16];
    #pragma unroll
    for (int d = 0; d < 14; d++) hr[d] = x[(size_t)r * 14 + d];
    hr[14] = 0.f; hr[15] = 0.f;
    STORE16(h + (size_t)r * DP, hr);
    qkv_compute_store(r, hr, wqkv, bqkv, Qpack, KB1, KB2, VhiT, VloT);
  }
}

// ======================================================================
// Pipelined attention core: 32-key chunks; LDS reads of P(c-1) issued at
// the top of iter c so S-MFMA+exp hide the latency (single buffer is
// safe: per-wave DS ops execute in order).
// ======================================================================
static __device__ __forceinline__ void attn_core(
    const bf16x8* __restrict__ Qp, const bf16x8* __restrict__ B1,
    const bf16x8* __restrict__ B2, const bf16x8* __restrict__ Vh,
    const bf16x8* __restrict__ Vl, int qbase, int wave, int lo4, int hi4,
    float (*Pl)[36], f32x4* o0, f32x4* o1) {
  const f32x4 zero = {0.f, 0.f, 0.f, 0.f};
  bf16x8 aQ0 = Qp[(size_t)(qbase + lo4) * 4 + hi4];
  bf16x8 aQ1 = Qp[(size_t)(qbase + 16 + lo4) * 4 + hi4];
  f32x4 acc0 = zero, acc1 = zero;
  const int kstart = wave * 1024;
  float4 ra0, ra1, rc0, rc1;
  const float4* p0 = (const float4*)&Pl[lo4][hi4 * 8];
  const float4* p1 = (const float4*)&Pl[16 + lo4][hi4 * 8];

  for (int c = 0; c < 32; c++) {
    const int kb = kstart + c * 32;
    if (c > 0) {            // issue reads of P(c-1) early
      ra0 = p0[0]; ra1 = p0[1]; rc0 = p1[0]; rc1 = p1[1];
      __asm__ volatile("" ::: "memory");   // keep reads above the writes below
    }
    bf16x8 b1g0 = B1[(size_t)(kb + lo4) * 4 + hi4];
    bf16x8 b2g0 = B2[(size_t)(kb + lo4) * 4 + hi4];
    bf16x8 b1g1 = B1[(size_t)(kb + 16 + lo4) * 4 + hi4];
    bf16x8 b2g1 = B2[(size_t)(kb + 16 + lo4) * 4 + hi4];
    bf16x8 vh = Vh[(size_t)lo4 * 1024 + (kb >> 3) + hi4];
    bf16x8 vl = Vl[(size_t)lo4 * 1024 + (kb >> 3) + hi4];

    f32x4 s00 = __builtin_amdgcn_mfma_f32_16x16x32_bf16(aQ0, b1g0, zero, 0, 0, 0);
    f32x4 s01 = __builtin_amdgcn_mfma_f32_16x16x32_bf16(aQ0, b1g1, zero, 0, 0, 0);
    f32x4 s10 = __builtin_amdgcn_mfma_f32_16x16x32_bf16(aQ1, b1g0, zero, 0, 0, 0);
    f32x4 s11 = __builtin_amdgcn_mfma_f32_16x16x32_bf16(aQ1, b1g1, zero, 0, 0, 0);
    s00 = __builtin_amdgcn_mfma_f32_16x16x32_bf16(aQ0, b2g0, s00, 0, 0, 0);
    s01 = __builtin_amdgcn_mfma_f32_16x16x32_bf16(aQ0, b2g1, s01, 0, 0, 0);
    s10 = __builtin_amdgcn_mfma_f32_16x16x32_bf16(aQ1, b2g0, s10, 0, 0, 0);
    s11 = __builtin_amdgcn_mfma_f32_16x16x32_bf16(aQ1, b2g1, s11, 0, 0, 0);
    // write P(c) (queued after the reads -> reads return old data)
    #pragma unroll
    for (int reg = 0; reg < 4; reg++) {
      Pl[hi4 * 4 + reg][lo4]           = fast_exp2(s00[reg]);
      Pl[hi4 * 4 + reg][16 + lo4]      = fast_exp2(s01[reg]);
      Pl[16 + hi4 * 4 + reg][lo4]      = fast_exp2(s10[reg]);
      Pl[16 + hi4 * 4 + reg][16 + lo4] = fast_exp2(s11[reg]);
    }
    if (c > 0) {            // PV of chunk c-1 (V frags of c-1 kept below)
      const int kbp = kb - 32;
      bf16x8 vhp = Vh[(size_t)lo4 * 1024 + (kbp >> 3) + hi4];
      bf16x8 vlp = Vl[(size_t)lo4 * 1024 + (kbp >> 3) + hi4];
      float pv0[8] = {ra0.x, ra0.y, ra0.z, ra0.w, ra1.x, ra1.y, ra1.z, ra1.w};
      float pv1[8] = {rc0.x, rc0.y, rc0.z, rc0.w, rc1.x, rc1.y, rc1.z, rc1.w};
      bf16x8 ph0, pl0, ph1, pl1;
      split8(pv0, &ph0, &pl0);
      split8(pv1, &ph1, &pl1);
      acc0 = __builtin_amdgcn_mfma_f32_16x16x32_bf16(ph0, vhp, acc0, 0, 0, 0);
      acc1 = __builtin_amdgcn_mfma_f32_16x16x32_bf16(ph1, vhp, acc1, 0, 0, 0);
      acc0 = __builtin_amdgcn_mfma_f32_16x16x32_bf16(pl0, vhp, acc0, 0, 0, 0);
      acc1 = __builtin_amdgcn_mfma_f32_16x16x32_bf16(pl1, vhp, acc1, 0, 0, 0);
      acc0 = __builtin_amdgcn_mfma_f32_16x16x32_bf16(ph0, vlp, acc0, 0, 0, 0);
      acc1 = __builtin_amdgcn_mfma_f32_16x16x32_bf16(ph1, vlp, acc1, 0, 0, 0);
    }
  }
  // epilogue: PV of chunk 31
  {
    const int kbp = kstart + 31 * 32;
    bf16x8 vhp = Vh[(size_t)lo4 * 1024 + (kbp >> 3) + hi4];
    bf16x8 vlp = Vl[(size_t)lo4 * 1024 + (kbp >> 3) + hi4];
    float4 a0 = p0[0], a1 = p0[1], c0 = p1[0], c1 = p1[1];
    float pv0[8] = {a0.x, a0.y, a0.z, a0.w, a1.x, a1.y, a1.z, a1.w};
    float pv1[8] = {c0.x, c0.y, c0.z, c0.w, c1.x, c1.y, c1.z, c1.w};
    bf16x8 ph0, pl0, ph1, pl1;
    split8(pv0, &ph0, &pl0);
    split8(pv1, &ph1, &pl1);
    acc0 = __builtin_amdgcn_mfma_f32_16x16x32_bf16(ph0, vhp, acc0, 0, 0, 0);
    acc1 = __builtin_amdgcn_mfma_f32_16x16x32_bf16(ph1, vhp, acc1, 0, 0, 0);
    acc0 = __builtin_amdgcn_mfma_f32_16x16x32_bf16(pl0, vhp, acc0, 0, 0, 0);
    acc1 = __builtin_amdgcn_mfma_f32_16x16x32_bf16(pl1, vhp, acc1, 0, 0, 0);
    acc0 = __builtin_amdgcn_mfma_f32_16x16x32_bf16(ph0, vlp, acc0, 0, 0, 0);
    acc1 = __builtin_amdgcn_mfma_f32_16x16x32_bf16(ph1, vlp, acc1, 0, 0, 0);
  }
  *o0 = acc0; *o1 = acc1;
}

// ======================================================================
// Pipelined FFN core: 8 neuron chunks of 32, same pipeline structure.
// ======================================================================
static __device__ __forceinline__ void ffn_core(
    bf16x8 aH0, bf16x8 aH1, const bf16x8* __restrict__ B1,
    const bf16x8* __restrict__ B2, const bf16x8* __restrict__ Vh,
    const bf16x8* __restrict__ Vl, const float* __restrict__ b1,
    int jstart, int lo4, int hi4, float (*Pl)[36], f32x4* o0, f32x4* o1) {
  const f32x4 zero = {0.f, 0.f, 0.f, 0.f};
  f32x4 acc0 = zero, acc1 = zero;
  float4 ra0, ra1, rc0, rc1;
  const float4* p0 = (const float4*)&Pl[lo4][hi4 * 8];
  const float4* p1 = (const float4*)&Pl[16 + lo4][hi4 * 8];

  for (int c = 0; c < 8; c++) {
    const int jb = jstart + c * 32;
    if (c > 0) {
      ra0 = p0[0]; ra1 = p0[1]; rc0 = p1[0]; rc1 = p1[1];
      __asm__ volatile("" ::: "memory");
    }
    bf16x8 b1g0 = B1[(size_t)(jb + lo4) * 4 + hi4];
    bf16x8 b2g0 = B2[(size_t)(jb + lo4) * 4 + hi4];
    bf16x8 b1g1 = B1[(size_t)(jb + 16 + lo4) * 4 + hi4];
    bf16x8 b2g1 = B2[(size_t)(jb + 16 + lo4) * 4 + hi4];
    float bb0 = b1[jb + lo4];
    float bb1 = b1[jb + 16 + lo4];

    f32x4 s00 = __builtin_amdgcn_mfma_f32_16x16x32_bf16(aH0, b1g0, zero, 0, 0, 0);
    f32x4 s01 = __builtin_amdgcn_mfma_f32_16x16x32_bf16(aH0, b1g1, zero, 0, 0, 0);
    f32x4 s10 = __builtin_amdgcn_mfma_f32_16x16x32_bf16(aH1, b1g0, zero, 0, 0, 0);
    f32x4 s11 = __builtin_amdgcn_mfma_f32_16x16x32_bf16(aH1, b1g1, zero, 0, 0, 0);
    s00 = __builtin_amdgcn_mfma_f32_16x16x32_bf16(aH0, b2g0, s00, 0, 0, 0);
    s01 = __builtin_amdgcn_mfma_f32_16x16x32_bf16(aH0, b2g1, s01, 0, 0, 0);
    s10 = __builtin_amdgcn_mfma_f32_16x16x32_bf16(aH1, b2g0, s10, 0, 0, 0);
    s11 = __builtin_amdgcn_mfma_f32_16x16x32_bf16(aH1, b2g1, s11, 0, 0, 0);
    #pragma unroll
    for (int reg = 0; reg < 4; reg++) {
      Pl[hi4 * 4 + reg][lo4]           = fmaxf(s00[reg] + bb0, 0.f);
      Pl[hi4 * 4 + reg][16 + lo4]      = fmaxf(s01[reg] + bb1, 0.f);
      Pl[16 + hi4 * 4 + reg][lo4]      = fmaxf(s10[reg] + bb0, 0.f);
      Pl[16 + hi4 * 4 + reg][16 + lo4] = fmaxf(s11[reg] + bb1, 0.f);
    }
    if (c > 0) {
      const int jbp = jb - 32;
      bf16x8 vhp = Vh[(size_t)lo4 * 256 + (jbp >> 3) + hi4];
      bf16x8 vlp = Vl[(size_t)lo4 * 256 + (jbp >> 3) + hi4];
      float pv0[8] = {ra0.x, ra0.y, ra0.z, ra0.w, ra1.x, ra1.y, ra1.z, ra1.w};
      float pv1[8] = {rc0.x, rc0.y, rc0.z, rc0.w, rc1.x, rc1.y, rc1.z, rc1.w};
      bf16x8 th0, tl0, th1, tl1;
      split8(pv0, &th0, &tl0);
      split8(pv1, &th1, &tl1);
      acc0 = __builtin_amdgcn_mfma_f32_16x16x32_bf16(th0, vhp, acc0, 0, 0, 0);
      acc1 = __builtin_amdgcn_mfma_f32_16x16x32_bf16(th1, vhp, acc1, 0, 0, 0);
      acc0 = __builtin_amdgcn_mfma_f32_16x16x32_bf16(tl0, vhp, acc0, 0, 0, 0);
      acc1 = __builtin_amdgcn_mfma_f32_16x16x32_bf16(tl1, vhp, acc1, 0, 0, 0);
      acc0 = __builtin_amdgcn_mfma_f32_16x16x32_bf16(th0, vlp, acc0, 0, 0, 0);
      acc1 = __builtin_amdgcn_mfma_f32_16x16x32_bf16(th1, vlp, acc1, 0, 0, 0);
    }
  }
  {
    const int jbp = jstart + 7 * 32;
    bf16x8 vhp = Vh[(size_t)lo4 * 256 + (jbp >> 3) + hi4];
    bf16x8 vlp = Vl[(size_t)lo4 * 256 + (jbp >> 3) + hi4];
    float4 a0 = p0[0], a1 = p0[1], c0 = p1[0], c1 = p1[1];
    float pv0[8] = {a0.x, a0.y, a0.z, a0.w, a1.x, a1.y, a1.z, a1.w};
    float pv1[8] = {c0.x, c0.y, c0.z, c0.w, c1.x, c1.y, c1.z, c1.w};
    bf16x8 th0, tl0, th1, tl1;
    split8(pv0, &th0, &tl0);
    split8(pv1, &th1, &tl1);
    acc0 = __builtin_amdgcn_mfma_f32_16x16x32_bf16(th0, vhp, acc0, 0, 0, 0);
    acc1 = __builtin_amdgcn_mfma_f32_16x16x32_bf16(th1, vhp, acc1, 0, 0, 0);
    acc0 = __builtin_amdgcn_mfma_f32_16x16x32_bf16(tl0, vhp, acc0, 0, 0, 0);
    acc1 = __builtin_amdgcn_mfma_f32_16x16x32_bf16(tl1, vhp, acc1, 0, 0, 0);
    acc0 = __builtin_amdgcn_mfma_f32_16x16x32_bf16(th0, vlp, acc0, 0, 0, 0);
    acc1 = __builtin_amdgcn_mfma_f32_16x16x32_bf16(th1, vlp, acc1, 0, 0, 0);
  }
  *o0 = acc0; *o1 = acc1;
}

// LDS layout (bytes):
//   0      : Plds  8 x [32][36] f32   (36864)      } tail phase reuses 0..51200
//   36864  : sacc  [8][32][16] f32    (16384)
//   53248  : hrow  [32][16] f32       (2048)
//   55296  : Hl    [32][16] u32       (2048)
//   57344  : szf   [32] f32           (128)   -> total 57472
#define SMEM_BYTES 57472

// ======================================================================
// K2: layer 0 = attn + combine/LN1 (LDS) + ffn + LN2 + layer-1 qkv pack.
// Layer-1 packs go to a SEPARATE buffer set (no race with other blocks
// still reading layer-0 packs).
// ======================================================================
__global__ __launch_bounds__(512, 4) void layer0_fused(
    const unsigned int* __restrict__ Qpack, const unsigned int* __restrict__ KB1,
    const unsigned int* __restrict__ KB2, const unsigned short* __restrict__ VhiT,
    const unsigned short* __restrict__ VloT, float* __restrict__ h,
    const float* __restrict__ wo, const float* __restrict__ bo,
    const float* __restrict__ g1, const float* __restrict__ b1n,
    const unsigned int* __restrict__ W1B1, const unsigned int* __restrict__ W1B2,
    const unsigned short* __restrict__ W2h, const unsigned short* __restrict__ W2l,
    const float* __restrict__ fb1, const float* __restrict__ fb2,
    const float* __restrict__ g2, const float* __restrict__ b2n,
    const float* __restrict__ wqkv1, const float* __restrict__ bqkv1,
    unsigned int* __restrict__ Qpack1, unsigned int* __restrict__ KB1_1,
    unsigned int* __restrict__ KB2_1, unsigned short* __restrict__ VhiT1,
    unsigned short* __restrict__ VloT1) {
  __shared__ alignas(16) char smem[SMEM_BYTES];
  const int tid = threadIdx.x;
  const int wave = tid >> 6;
  const int lane = tid & 63;
  const int lo4 = lane & 15;
  const int hi4 = lane >> 4;
  const int qbase = blockIdx.x * 32;

  float (*Pl)[36] = (float(*)[36])(smem + wave * 4608);
  float (*sacc)[32][16] = (float(*)[32][16])(smem + 36864);
  float (*hrow)[16] = (float(*)[16])(smem + 53248);
  unsigned int (*Hl)[16] = (unsigned int(*)[16])(smem + 55296);

  // ---- phase A: attention ----
  f32x4 a0, a1;
  attn_core((const bf16x8*)Qpack, (const bf16x8*)KB1, (const bf16x8*)KB2,
            (const bf16x8*)VhiT, (const bf16x8*)VloT, qbase, wave, lo4, hi4,
            Pl, &a0, &a1);
  #pragma unroll
  for (int reg = 0; reg < 4; reg++) {
    sacc[wave][hi4 * 4 + reg][lo4] = a0[reg];
    sacc[wave][16 + hi4 * 4 + reg][lo4] = a1[reg];
  }
  __syncthreads();
  {
    int qq = tid >> 4, col = tid & 15;
    float v = 0.f;
    #pragma unroll
    for (int w = 0; w < 8; w++) v += sacc[w][qq][col];
    sacc[0][qq][col] = v;
  }
  __syncthreads();
  if (tid < 32) {
    int r = qbase + tid;
    float hr[16];
    LOAD16(hr, h + (size_t)r * DP);
    float o[16];
    combine_ln1(&sacc[0][tid][0], hr, wo, bo, g1, b1n, o);
    #pragma unroll
    for (int i = 0; i < 16; i++) hrow[tid][i] = o[i];
    store_apack(&Hl[tid][0], o);
  }
  __syncthreads();

  // ---- phase B: FFN ----
  bf16x8 aH0 = *(const bf16x8*)&Hl[lo4][hi4 * 4];
  bf16x8 aH1 = *(const bf16x8*)&Hl[16 + lo4][hi4 * 4];
  f32x4 f0, f1;
  ffn_core(aH0, aH1, (const bf16x8*)W1B1, (const bf16x8*)W1B2,
           (const bf16x8*)W2h, (const bf16x8*)W2l, fb1, wave * 256,
           lo4, hi4, Pl, &f0, &f1);
  __syncthreads();   // sacc[0] still being read? no: consumed above; reuse safely
  #pragma unroll
  for (int reg = 0; reg < 4; reg++) {
    sacc[wave][hi4 * 4 + reg][lo4] = f0[reg];
    sacc[wave][16 + hi4 * 4 + reg][lo4] = f1[reg];
  }
  __syncthreads();
  {
    int qq = tid >> 4, col = tid & 15;
    float v = 0.f;
    #pragma unroll
    for (int w = 0; w < 8; w++) v += sacc[w][qq][col];
    sacc[0][qq][col] = v;
  }
  __syncthreads();
  if (tid < 32) {
    int r = qbase + tid;
    float xx[14];
    #pragma unroll
    for (int i = 0; i < 14; i++) xx[i] = hrow[tid][i] + sacc[0][tid][i] + fb2[i];
    float mu = 0.f;
    #pragma unroll
    for (int i = 0; i < 14; i++) mu += xx[i];
    mu *= (1.f / 14.f);
    float var = 0.f;
    #pragma unroll
    for (int i = 0; i < 14; i++) { float tt = xx[i] - mu; var = fmaf(tt, tt, var); }
    var *= (1.f / 14.f);
    float rs = rsqrtf(var + LN_EPS);
    float o[16];
    #pragma unroll
    for (int i = 0; i < 14; i++) o[i] = fmaf((xx[i] - mu) * rs, g2[i], b2n[i]);
    o[14] = 0.f; o[15] = 0.f;
    STORE16(h + (size_t)r * DP, o);
    qkv_compute_store(r, o, wqkv1, bqkv1, Qpack1, KB1_1, KB2_1, VhiT1, VloT1);
  }
}

// ======================================================================
// K3: layer 1 = attn + LN1 + ffn + LN2 + size head + regression tail.
// 32 rows/block; tail runs as two 16-row groups (waves 0-3 / 4-7).
// ======================================================================
__global__ __launch_bounds__(512, 4) void layer1_tail(
    const unsigned int* __restrict__ Qpack, const unsigned int* __restrict__ KB1,
    const unsigned int* __restrict__ KB2, const unsigned short* __restrict__ VhiT,
    const unsigned short* __restrict__ VloT, const float* __restrict__ h,
    const float* __restrict__ wo, const float* __restrict__ bo,
    const float* __restrict__ g1, const float* __restrict__ b1n,
    const unsigned int* __restrict__ W1B1, const unsigned int* __restrict__ W1B2,
    const unsigned short* __restrict__ W2h, const unsigned short* __restrict__ W2l,
    const float* __restrict__ fb1, const float* __restrict__ fb2,
    const float* __restrict__ g2, const float* __restrict__ b2n,
    const float* __restrict__ fc1w, const float* __restrict__ fc1b,
    const float* __restrict__ fc2w, const float* __restrict__ fc2b,
    const float* __restrict__ x, const float* __restrict__ y,
    const unsigned short* __restrict__ B3h, const unsigned short* __restrict__ B3l,
    const float* __restrict__ b3,
    const unsigned short* __restrict__ B4h, const unsigned short* __restrict__ B4l,
    const float* __restrict__ b4,
    const float* __restrict__ w5, const float* __restrict__ b5,
    float* __restrict__ out, float* __restrict__ outr) {
  __shared__ alignas(16) char smem[SMEM_BYTES];
  const int tid = threadIdx.x;
  const int wave = tid >> 6;
  const int lane = tid & 63;
  const int lo4 = lane & 15;
  const int hi4 = lane >> 4;
  const int qbase = blockIdx.x * 32;
  const f32x4 zero = {0.f, 0.f, 0.f, 0.f};

  float (*Pl)[36] = (float(*)[36])(smem + wave * 4608);
  float (*sacc)[32][16] = (float(*)[32][16])(smem + 36864);
  float (*hrow)[16] = (float(*)[16])(smem + 53248);
  unsigned int (*Hl)[16] = (unsigned int(*)[16])(smem + 55296);
  float* szf = (float*)(smem + 57344);

  // ---- phase A: attention (layer 1) ----
  f32x4 a0, a1;
  attn_core((const bf16x8*)Qpack, (const bf16x8*)KB1, (const bf16x8*)KB2,
            (const bf16x8*)VhiT, (const bf16x8*)VloT, qbase, wave, lo4, hi4,
            Pl, &a0, &a1);
  #pragma unroll
  for (int reg = 0; reg < 4; reg++) {
    sacc[wave][hi4 * 4 + reg][lo4] = a0[reg];
    sacc[wave][16 + hi4 * 4 + reg][lo4] = a1[reg];
  }
  __syncthreads();
  {
    int qq = tid >> 4, col = tid & 15;
    float v = 0.f;
    #pragma unroll
    for (int w = 0; w < 8; w++) v += sacc[w][qq][col];
    sacc[0][qq][col] = v;
  }
  __syncthreads();
  if (tid < 32) {
    int r = qbase + tid;
    float hr[16];
    LOAD16(hr, h + (size_t)r * DP);
    float o[16];
    combine_ln1(&sacc[0][tid][0], hr, wo, bo, g1, b1n, o);
    #pragma unroll
    for (int i = 0; i < 16; i++) hrow[tid][i] = o[i];
    store_apack(&Hl[tid][0], o);
  }
  __syncthreads();

  // ---- phase B: FFN (layer 1) + LN2 + size head ----
  bf16x8 aH0 = *(const bf16x8*)&Hl[lo4][hi4 * 4];
  bf16x8 aH1 = *(const bf16x8*)&Hl[16 + lo4][hi4 * 4];
  f32x4 f0, f1;
  ffn_core(aH0, aH1, (const bf16x8*)W1B1, (const bf16x8*)W1B2,
           (const bf16x8*)W2h, (const bf16x8*)W2l, fb1, wave * 256,
           lo4, hi4, Pl, &f0, &f1);
  __syncthreads();
  #pragma unroll
  for (int reg = 0; reg < 4; reg++) {
    sacc[wave][hi4 * 4 + reg][lo4] = f0[reg];
    sacc[wave][16 + hi4 * 4 + reg][lo4] = f1[reg];
  }
  __syncthreads();
  {
    int qq = tid >> 4, col = tid & 15;
    float v = 0.f;
    #pragma unroll
    for (int w = 0; w < 8; w++) v += sacc[w][qq][col];
    sacc[0][qq][col] = v;
  }
  __syncthreads();
  if (tid < 32) {
    int r = qbase + tid;
    float xx[14];
    #pragma unroll
    for (int i = 0; i < 14; i++) xx[i] = hrow[tid][i] + sacc[0][tid][i] + fb2[i];
    float mu = 0.f;
    #pragma unroll
    for (int i = 0; i < 14; i++) mu += xx[i];
    mu *= (1.f / 14.f);
    float var = 0.f;
    #pragma unroll
    for (int i = 0; i < 14; i++) { float tt = xx[i] - mu; var = fmaf(tt, tt, var); }
    var *= (1.f / 14.f);
    float rs = rsqrtf(var + LN_EPS);
    float o[14];
    #pragma unroll
    for (int i = 0; i < 14; i++) o[i] = fmaf((xx[i] - mu) * rs, g2[i], b2n[i]);
    float s = fc2b[0];
    #pragma unroll
    for (int i = 0; i < 14; i++) {
      float tt = fc1b[i];
      #pragma unroll
      for (int d = 0; d < 14; d++) tt = fmaf(fc1w[i * 14 + d], o[d], tt);
      s = fmaf(tt, fc2w[i], s);
    }
    out[r] = s;
    int si = (int)s;  // trunc toward zero, matches astype(int32)
    szf[tid] = (float)si;
  }
  __syncthreads();

  // ---- phase C: regression head, two 16-row groups ----
  // tail arrays reuse smem[0..51200) (Plds/sacc regions are dead now)
  const int grp = wave >> 2;   // 0 or 1: rows [qbase+grp*16, +16)
  const int wg  = wave & 3;    // wave-in-group

  // stage reg_in -> bf16 hi/lo
  for (int idx = tid; idx < 2 * 16 * 64; idx += 512) {
    int g = idx >> 10, m = (idx >> 6) & 15, k = idx & 63;
    int r = qbase + g * 16 + m;
    float v = 0.f;
    if (k == 0)       v = szf[g * 16 + m];
    else if (k < 15)  v = x[(size_t)r * 14 + (k - 1)];
    else if (k < 51)  v = y[(size_t)r * 36 + (k - 15)];
    ((unsigned short(*)[72])(smem + g * 2304))[m][k] = bf_hi(v);
    ((unsigned short(*)[72])(smem + 4608 + g * 2304))[m][k] = bf_hi(v - bf_hi_f(v));
  }
  __syncthreads();

  unsigned short (*Ah)[72]  = (unsigned short(*)[72])(smem + grp * 2304);
  unsigned short (*Al)[72]  = (unsigned short(*)[72])(smem + 4608 + grp * 2304);
  unsigned short (*R1h)[264] = (unsigned short(*)[264])(smem + 9216 + grp * 8448);
  unsigned short (*R1l)[264] = (unsigned short(*)[264])(smem + 26112 + grp * 8448);
  float (*sred)[16][16] = (float(*)[16][16])(smem + 43008 + (size_t)grp * 4096);

  f32x4 acc[4];
  #pragma unroll
  for (int nt = 0; nt < 4; nt++) acc[nt] = zero;
  #pragma unroll
  for (int ks = 0; ks < 2; ks++) {
    bf16x8 ah = *(const bf16x8*)&Ah[lo4][ks * 32 + hi4 * 8];
    bf16x8 al = *(const bf16x8*)&Al[lo4][ks * 32 + hi4 * 8];
    #pragma unroll
    for (int nt = 0; nt < 4; nt++) {
      int fi = ((wg * 4 + nt) * 2 + ks) * 64 + lane;
      bf16x8 bh = ((const bf16x8*)B3h)[fi];
      bf16x8 bl = ((const bf16x8*)B3l)[fi];
      acc[nt] = __builtin_amdgcn_mfma_f32_16x16x32_bf16(ah, bh, acc[nt], 0, 0, 0);
      acc[nt] = __builtin_amdgcn_mfma_f32_16x16x32_bf16(al, bh, acc[nt], 0, 0, 0);
      acc[nt] = __builtin_amdgcn_mfma_f32_16x16x32_bf16(ah, bl, acc[nt], 0, 0, 0);
    }
  }
  #pragma unroll
  for (int nt = 0; nt < 4; nt++) {
    int n = (wg * 4 + nt) * 16 + lo4;
    float bbv = b3[n];
    #pragma unroll
    for (int reg = 0; reg < 4; reg++) {
      int m = hi4 * 4 + reg;
      float v = fmaxf(acc[nt][reg] + bbv, 0.f);
      R1h[m][n] = bf_hi(v);
      R1l[m][n] = bf_hi(v - bf_hi_f(v));
    }
  }
  __syncthreads();

  #pragma unroll
  for (int nt = 0; nt < 4; nt++) acc[nt] = zero;
  #pragma unroll
  for (int ks = 0; ks < 8; ks++) {
    bf16x8 ah = *(const bf16x8*)&R1h[lo4][ks * 32 + hi4 * 8];
    bf16x8 al = *(const bf16x8*)&R1l[lo4][ks * 32 + hi4 * 8];
    #pragma unroll
    for (int nt = 0; nt < 4; nt++) {
      int fi = ((wg * 4 + nt) * 8 + ks) * 64 + lane;
      bf16x8 bh = ((const bf16x8*)B4h)[fi];
      bf16x8 bl = ((const bf16x8*)B4l)[fi];
      acc[nt] = __builtin_amdgcn_mfma_f32_16x16x32_bf16(ah, bh, acc[nt], 0, 0, 0);
      acc[nt] = __builtin_amdgcn_mfma_f32_16x16x32_bf16(al, bh, acc[nt], 0, 0, 0);
      acc[nt] = __builtin_amdgcn_mfma_f32_16x16x32_bf16(ah, bl, acc[nt], 0, 0, 0);
    }
  }
  float s4[4] = {0.f, 0.f, 0.f, 0.f};
  #pragma unroll
  for (int nt = 0; nt < 4; nt++) {
    int n = (wg * 4 + nt) * 16 + lo4;
    float bbv = b4[n], ww = w5[n];
    #pragma unroll
    for (int reg = 0; reg < 4; reg++)
      s4[reg] = fmaf(fmaxf(acc[nt][reg] + bbv, 0.f), ww, s4[reg]);
  }
  #pragma unroll
  for (int reg = 0; reg < 4; reg++) sred[wg][hi4 * 4 + reg][lo4] = s4[reg];
  __syncthreads();

  if (tid < 32) {
    int g = tid >> 4, m = tid & 15;
    float (*sredG)[16][16] = (float(*)[16][16])(smem + 43008 + (size_t)g * 4096);
    float t = b5[0];
    #pragma unroll
    for (int w = 0; w < 4; w++) {
      const float4* p = (const float4*)&sredG[w][m][0];
      float4 q0 = p[0], q1 = p[1], q2 = p[2], q3 = p[3];
      t += ((q0.x + q0.y) + (q0.z + q0.w)) + ((q1.x + q1.y) + (q1.z + q1.w)) +
           ((q2.x + q2.y) + (q2.z + q2.w)) + ((q3.x + q3.y) + (q3.z + q3.w));
    }
    float sz = szf[tid];
    outr[qbase + tid] = (sz != 0.f) ? t : 0.f;
  }
}

extern "C" void kernel_launch(void* const* d_in, const int* in_sizes, int n_in,
                              void* d_out, int out_size, void* d_ws, size_t ws_size,
                              hipStream_t stream) {
  const float* x    = (const float*)d_in[0];
  const float* y    = (const float*)d_in[1];
  const float* wqkv = (const float*)d_in[2];
  const float* bqkv = (const float*)d_in[3];
  const float* wo   = (const float*)d_in[4];
  const float* bo   = (const float*)d_in[5];
  const float* ln1g = (const float*)d_in[6];
  const float* ln1b = (const float*)d_in[7];
  const float* ffw1 = (const float*)d_in[8];
  const float* ffb1 = (const float*)d_in[9];
  const float* ffw2 = (const float*)d_in[10];
  const float* ffb2 = (const float*)d_in[11];
  const float* ln2g = (const float*)d_in[12];
  const float* ln2b = (const float*)d_in[13];
  const float* fc1w = (const float*)d_in[14];
  const float* fc1b = (const float*)d_in[15];
  const float* fc2w = (const float*)d_in[16];
  const float* fc2b = (const float*)d_in[17];
  const float* fc3w = (const float*)d_in[18];
  const float* fc3b = (const float*)d_in[19];
  const float* fc4w = (const float*)d_in[20];
  const float* fc4b = (const float*)d_in[21];
  const float* fc5w = (const float*)d_in[22];
  const float* fc5b = (const float*)d_in[23];

  float* ws = (float*)d_ws;
  float*          h      = ws;                               // 131072 f
  unsigned int*   Qpack0 = (unsigned int*)(ws + 131072);
  unsigned int*   KB1_0  = (unsigned int*)(ws + 262144);
  unsigned int*   KB2_0  = (unsigned int*)(ws + 393216);
  unsigned short* VhiT0  = (unsigned short*)(ws + 524288);
  unsigned short* VloT0  = (unsigned short*)(ws + 589824);
  // layer-1 packs in the old 'part' region (no longer used)
  unsigned int*   Qpack1 = (unsigned int*)(ws + 786432);
  unsigned int*   KB1_1  = (unsigned int*)(ws + 917504);
  unsigned int*   KB2_1  = (unsigned int*)(ws + 1048576);
  unsigned short* VhiT1  = (unsigned short*)(ws + 1179648);
  unsigned short* VloT1  = (unsigned short*)(ws + 1245184);
  unsigned short* B3h    = (unsigned short*)(ws + 2891776);
  unsigned short* B3l    = (unsigned short*)(ws + 2899968);
  unsigned short* B4h    = (unsigned short*)(ws + 2908160);
  unsigned short* B4l    = (unsigned short*)(ws + 2940928);
  unsigned int*   W1B1   = (unsigned int*)(ws + 2973696);
  unsigned int*   W1B2   = (unsigned int*)(ws + 3039232);
  unsigned short* W2h    = (unsigned short*)(ws + 3104768);
  unsigned short* W2l    = (unsigned short*)(ws + 3137536);

  float* out = (float*)d_out;

  pack_all<<<96, 256, 0, stream>>>(fc3w, fc4w, ffw1, ffw2, x, wqkv, bqkv, h,
                                   Qpack0, KB1_0, KB2_0, VhiT0, VloT0,
                                   B3h, B3l, B4h, B4l, W1B1, W1B2, W2h, W2l);

  layer0_fused<<<256, 512, 0, stream>>>(
      Qpack0, KB1_0, KB2_0, VhiT0, VloT0, h,
      wo, bo, ln1g, ln1b,
      W1B1, W1B2, W2h, W2l, ffb1, ffb2, ln2g, ln2b,
      wqkv + 42 * 14, bqkv + 42,
      Qpack1, KB1_1, KB2_1, VhiT1, VloT1);

  layer1_tail<<<256, 512, 0, stream>>>(
      Qpack1, KB1_1, KB2_1, VhiT1, VloT1, h,
      wo + 196, bo + 14, ln1g + 14, ln1b + 14,
      W1B1 + (size_t)2048 * 16, W1B2 + (size_t)2048 * 16,
      W2h + (size_t)16 * FF, W2l + (size_t)16 * FF,
      ffb1 + FF, ffb2 + 14, ln2g + 14, ln2b + 14,
      fc1w, fc1b, fc2w, fc2b, x, y,
      B3h, B3l, fc3b, B4h, B4l, fc4b,
      fc5w, fc5b, out, out + NN);
}